// Round 1
// baseline (448.519 us; speedup 1.0000x reference)
//
#include <hip/hip_runtime.h>

// Problem: B=4, S=2048, E=1024, H=16, DH=64
// out[b][s][h*64+d] = softmax_causal(Q K^T / 8) V, with Q/K/V = X @ W{q,k,v}[h]
//
// Pipeline:
//   1) conv_x:  embedded f32 -> bf16 (row-major [8192][1024])
//   2) conv_w:  W[p][h][e][d] f32 -> bf16 transposed Wt[p][h*64+d][e]  (k-contiguous for MFMA)
//   3) qkv_gemm: 128x128 tile, BK=32, 4 waves, global_load_lds(16B), mfma_f32_16x16x32_bf16
//        p=0 -> Q [b][h][s][d], p=1 -> K [b][h][s][d], p=2 -> V^T [b][h][d][s] (swapped-operand MFMA)
//   4) attn: flash, 128 q-rows/block (4 waves x 32), 64-key tiles, online softmax, f32 out

typedef short bf16x8 __attribute__((ext_vector_type(8)));
typedef float f32x4 __attribute__((ext_vector_type(4)));
typedef unsigned short u16x4 __attribute__((ext_vector_type(4)));
typedef unsigned short u16x8 __attribute__((ext_vector_type(8)));

#define LOG2E 1.4426950408889634f

static __device__ __forceinline__ unsigned short f2bf(float f) {
  unsigned int u = __builtin_bit_cast(unsigned int, f);
  u += 0x7fffu + ((u >> 16) & 1u);   // RNE
  return (unsigned short)(u >> 16);
}

static __device__ __forceinline__ void gload16(const void* g, void* l) {
  __builtin_amdgcn_global_load_lds((__attribute__((address_space(1))) void*)g,
                                   (__attribute__((address_space(3))) void*)l, 16, 0, 0);
}

// ---------------- 1) X f32 -> bf16 ----------------
__global__ __launch_bounds__(256) void conv_x(const float* __restrict__ x,
                                              unsigned short* __restrict__ y, int n4) {
  int i0 = blockIdx.x * 256 + threadIdx.x;
  int stride = gridDim.x * 256;
  for (int c = i0; c < n4; c += stride) {
    float4 v = ((const float4*)x)[c];
    u16x4 o;
    o[0] = f2bf(v.x); o[1] = f2bf(v.y); o[2] = f2bf(v.z); o[3] = f2bf(v.w);
    ((u16x4*)y)[c] = o;
  }
}

// ---------------- 2) W transpose+convert: [p][h][e][d] -> Wt[(p*1024 + h*64 + d)][e] bf16 ----
__global__ __launch_bounds__(256) void conv_w(const float* __restrict__ Wq,
                                              const float* __restrict__ Wk,
                                              const float* __restrict__ Wv,
                                              unsigned short* __restrict__ Wt) {
  const int p = blockIdx.y;
  const float* Wsrc = (p == 0) ? Wq : ((p == 1) ? Wk : Wv);
  const int h = blockIdx.x >> 4, et = blockIdx.x & 15;   // 64-wide e tile
  const int t = threadIdx.x;
  __shared__ __align__(16) unsigned short tile[64][72];  // [e][d], padded

  const float* src = Wsrc + (h * 1024 + et * 64) * 64;   // rows e (64), cols d (64)
#pragma unroll
  for (int i = 0; i < 4; ++i) {                          // 1024 float4 chunks / 256 thr
    int c = i * 256 + t;
    int r = c >> 4, cc = (c & 15) * 4;
    float4 v = *(const float4*)(src + r * 64 + cc);
    tile[r][cc + 0] = f2bf(v.x); tile[r][cc + 1] = f2bf(v.y);
    tile[r][cc + 2] = f2bf(v.z); tile[r][cc + 3] = f2bf(v.w);
  }
  __syncthreads();
#pragma unroll
  for (int i = 0; i < 2; ++i) {                          // 512 x 16B out chunks
    int c = i * 256 + t;
    int d = c >> 3, ec = (c & 7) * 8;
    u16x8 o;
#pragma unroll
    for (int j = 0; j < 8; ++j) o[j] = tile[ec + j][d];
    *(u16x8*)(Wt + (p * 1024 + h * 64 + d) * 1024 + et * 64 + ec) = o;
  }
}

// ---------------- 3) QKV projection GEMM ----------------
// A = Xb [8192][1024] bf16 row-major. B(eff) = Wt [3*1024][1024] bf16 (row n, col k).
__global__ __launch_bounds__(256) void qkv_gemm(const unsigned short* __restrict__ Xb,
                                                const unsigned short* __restrict__ Wt,
                                                unsigned short* __restrict__ Qb,
                                                unsigned short* __restrict__ Kb,
                                                unsigned short* __restrict__ Vtb) {
  __shared__ __align__(16) unsigned short As[128 * 32];  // [m][k] rows 64B
  __shared__ __align__(16) unsigned short Bs[128 * 32];  // [n][k] rows 64B
  const int t = threadIdx.x, lane = t & 63, w = t >> 6;
  const int wr = w >> 1, wc = w & 1;
  const int m0 = blockIdx.x * 128;
  const int pt = blockIdx.y;
  const int p = pt >> 3, n0 = (pt & 7) * 128;

  f32x4 acc[4][4] = {};

  // staging addresses: chunk i covers 16 rows; lane -> (row = lane>>2, colchunk = lane&3)
  const unsigned short* Ag = Xb + (m0 + w * 32 + (lane >> 2)) * 1024 + (lane & 3) * 8;
  const unsigned short* Bg = Wt + (p * 1024 + n0 + w * 32 + (lane >> 2)) * 1024 + (lane & 3) * 8;
  unsigned short* AsW = &As[w * 1024];  // wave-uniform LDS dest (bytes w*2048)
  unsigned short* BsW = &Bs[w * 1024];

  for (int kt = 0; kt < 32; ++kt) {
    __syncthreads();
    gload16(Ag + kt * 32,             AsW);
    gload16(Ag + kt * 32 + 16 * 1024, AsW + 512);
    gload16(Bg + kt * 32,             BsW);
    gload16(Bg + kt * 32 + 16 * 1024, BsW + 512);
    asm volatile("s_waitcnt vmcnt(0)" ::: "memory");
    __syncthreads();

    bf16x8 a[4], bfr[4];
#pragma unroll
    for (int mi = 0; mi < 4; ++mi)
      a[mi] = *(const bf16x8*)&As[(wr * 64 + mi * 16 + (lane & 15)) * 32 + (lane >> 4) * 8];
#pragma unroll
    for (int ni = 0; ni < 4; ++ni)
      bfr[ni] = *(const bf16x8*)&Bs[(wc * 64 + ni * 16 + (lane & 15)) * 32 + (lane >> 4) * 8];

    if (p != 2) {
#pragma unroll
      for (int mi = 0; mi < 4; ++mi)
#pragma unroll
        for (int ni = 0; ni < 4; ++ni)
          acc[mi][ni] = __builtin_amdgcn_mfma_f32_16x16x32_bf16(a[mi], bfr[ni], acc[mi][ni], 0, 0, 0);
    } else {  // compute C^T so V stores coalesce in the [d][s] layout
#pragma unroll
      for (int mi = 0; mi < 4; ++mi)
#pragma unroll
        for (int ni = 0; ni < 4; ++ni)
          acc[mi][ni] = __builtin_amdgcn_mfma_f32_16x16x32_bf16(bfr[ni], a[mi], acc[mi][ni], 0, 0, 0);
    }
  }

  if (p != 2) {
    unsigned short* dst = (p == 0) ? Qb : Kb;
#pragma unroll
    for (int mi = 0; mi < 4; ++mi)
#pragma unroll
      for (int ni = 0; ni < 4; ++ni)
#pragma unroll
        for (int r = 0; r < 4; ++r) {
          int m_g = m0 + wr * 64 + mi * 16 + (lane >> 4) * 4 + r;
          int n_g = n0 + wc * 64 + ni * 16 + (lane & 15);
          int b = m_g >> 11, s = m_g & 2047;
          dst[((b * 16 + (n_g >> 6)) * 2048 + s) * 64 + (n_g & 63)] = f2bf(acc[mi][ni][r]);
        }
  } else {
#pragma unroll
    for (int mi = 0; mi < 4; ++mi)
#pragma unroll
      for (int ni = 0; ni < 4; ++ni)
#pragma unroll
        for (int r = 0; r < 4; ++r) {
          int n_g = n0 + wc * 64 + ni * 16 + (lane >> 4) * 4 + r;  // d-dim
          int m_g = m0 + wr * 64 + mi * 16 + (lane & 15);          // s-dim
          int b = m_g >> 11, s = m_g & 2047;
          Vtb[((b * 16 + (n_g >> 6)) * 64 + (n_g & 63)) * 2048 + s] = f2bf(acc[mi][ni][r]);
        }
  }
}

// ---------------- 4) Flash attention (causal) ----------------
// grid (16 qtiles, 64 bh). 4 waves x 32 q-rows. KV tiles of 64 keys.
__global__ __launch_bounds__(256) void attn(const unsigned short* __restrict__ Qb,
                                            const unsigned short* __restrict__ Kb,
                                            const unsigned short* __restrict__ Vtb,
                                            float* __restrict__ out) {
  const int bh = blockIdx.y;
  const int qt = (gridDim.x - 1) - blockIdx.x;  // heavy q-tiles first
  const int q0 = qt * 128;
  const int t = threadIdx.x, lane = t & 63, w = t >> 6;

  __shared__ __align__(16) unsigned short Ks[64][72];      // [key][d] padded (144B rows)
  __shared__ __align__(16) unsigned short Vs[64][72];      // [d][key] padded
  __shared__ __align__(16) unsigned short Ps[4][32][72];   // per-wave P [qrow][key]

  // Q fragments in registers (A-operand layout)
  bf16x8 qf[2][2];
#pragma unroll
  for (int mi = 0; mi < 2; ++mi)
#pragma unroll
    for (int kc = 0; kc < 2; ++kc)
      qf[mi][kc] = *(const bf16x8*)(Qb + ((bh * 2048 + q0 + w * 32 + mi * 16 + (lane & 15)) << 6)
                                       + kc * 32 + ((lane >> 4) << 3));

  f32x4 o_acc[2][4] = {};
  float m_s[2][4], l_s[2][4];
#pragma unroll
  for (int mi = 0; mi < 2; ++mi)
#pragma unroll
    for (int r = 0; r < 4; ++r) { m_s[mi][r] = -INFINITY; l_s[mi][r] = 0.f; }

  const int ktiles = 2 * qt + 2;
  for (int kt = 0; kt < ktiles; ++kt) {
    const int kv0 = kt * 64;
    // stage K (64x64) and V^T (64x64) into padded LDS
#pragma unroll
    for (int i = 0; i < 2; ++i) {
      int c = i * 256 + t;
      int r = c >> 3, cc = (c & 7) * 8;
      *(uint4*)&Ks[r][cc] = *(const uint4*)(Kb + ((bh * 2048 + kv0 + r) << 6) + cc);
      *(uint4*)&Vs[r][cc] = *(const uint4*)(Vtb + ((bh * 64 + r) << 11) + kv0 + cc);
    }
    __syncthreads();

    // QK^T: sc[mi][sub] = 16x16 scores (rows q, cols key)
    f32x4 sc[2][4];
#pragma unroll
    for (int sub = 0; sub < 4; ++sub) {
      bf16x8 kf0 = *(const bf16x8*)&Ks[sub * 16 + (lane & 15)][(lane >> 4) * 8];
      bf16x8 kf1 = *(const bf16x8*)&Ks[sub * 16 + (lane & 15)][32 + (lane >> 4) * 8];
#pragma unroll
      for (int mi = 0; mi < 2; ++mi) {
        f32x4 z = {};
        z = __builtin_amdgcn_mfma_f32_16x16x32_bf16(qf[mi][0], kf0, z, 0, 0, 0);
        z = __builtin_amdgcn_mfma_f32_16x16x32_bf16(qf[mi][1], kf1, z, 0, 0, 0);
        sc[mi][sub] = z;
      }
    }

    const bool maskt = (kv0 + 64 > q0);  // only diagonal-adjacent tiles need masking
#pragma unroll
    for (int mi = 0; mi < 2; ++mi) {
      float pvv[4][4];  // [sub][r]
      float rm[4];
#pragma unroll
      for (int r = 0; r < 4; ++r) {
        const int q_g = q0 + w * 32 + mi * 16 + ((lane >> 4) << 2) + r;
        float best = -INFINITY;
#pragma unroll
        for (int sub = 0; sub < 4; ++sub) {
          float v = sc[mi][sub][r] * 0.125f;
          if (maskt && (kv0 + sub * 16 + (lane & 15)) > q_g) v = -INFINITY;
          pvv[sub][r] = v;
          best = fmaxf(best, v);
        }
        rm[r] = best;
      }
#pragma unroll
      for (int r = 0; r < 4; ++r) {
        rm[r] = fmaxf(rm[r], __shfl_xor(rm[r], 1));
        rm[r] = fmaxf(rm[r], __shfl_xor(rm[r], 2));
        rm[r] = fmaxf(rm[r], __shfl_xor(rm[r], 4));
        rm[r] = fmaxf(rm[r], __shfl_xor(rm[r], 8));
        float mnew = fmaxf(m_s[mi][r], rm[r]);
        float corr = exp2f((m_s[mi][r] - mnew) * LOG2E);
        float rsum = 0.f;
#pragma unroll
        for (int sub = 0; sub < 4; ++sub) {
          float e = exp2f((pvv[sub][r] - mnew) * LOG2E);
          pvv[sub][r] = e;
          rsum += e;
        }
        rsum += __shfl_xor(rsum, 1);
        rsum += __shfl_xor(rsum, 2);
        rsum += __shfl_xor(rsum, 4);
        rsum += __shfl_xor(rsum, 8);
        l_s[mi][r] = l_s[mi][r] * corr + rsum;
        m_s[mi][r] = mnew;
#pragma unroll
        for (int ni = 0; ni < 4; ++ni) o_acc[mi][ni][r] *= corr;
        const int prow = mi * 16 + ((lane >> 4) << 2) + r;
#pragma unroll
        for (int sub = 0; sub < 4; ++sub)
          Ps[w][prow][sub * 16 + (lane & 15)] = f2bf(pvv[sub][r]);
      }
    }

    // PV: O += P(16x64) x V(64x64), per wave
    bf16x8 pf[2][2];
#pragma unroll
    for (int mi = 0; mi < 2; ++mi)
#pragma unroll
      for (int kc = 0; kc < 2; ++kc)
        pf[mi][kc] = *(const bf16x8*)&Ps[w][mi * 16 + (lane & 15)][kc * 32 + (lane >> 4) * 8];
#pragma unroll
    for (int ni = 0; ni < 4; ++ni) {
      bf16x8 vf0 = *(const bf16x8*)&Vs[ni * 16 + (lane & 15)][(lane >> 4) * 8];
      bf16x8 vf1 = *(const bf16x8*)&Vs[ni * 16 + (lane & 15)][32 + (lane >> 4) * 8];
#pragma unroll
      for (int mi = 0; mi < 2; ++mi) {
        o_acc[mi][ni] = __builtin_amdgcn_mfma_f32_16x16x32_bf16(pf[mi][0], vf0, o_acc[mi][ni], 0, 0, 0);
        o_acc[mi][ni] = __builtin_amdgcn_mfma_f32_16x16x32_bf16(pf[mi][1], vf1, o_acc[mi][ni], 0, 0, 0);
      }
    }
    __syncthreads();
  }

  // epilogue: out[b][s][h*64+d] = O / l
  const int b = bh >> 4, h = bh & 15;
#pragma unroll
  for (int mi = 0; mi < 2; ++mi)
#pragma unroll
    for (int r = 0; r < 4; ++r) {
      float inv = 1.f / l_s[mi][r];
      int q_g = q0 + w * 32 + mi * 16 + ((lane >> 4) << 2) + r;
#pragma unroll
      for (int ni = 0; ni < 4; ++ni)
        out[(b * 2048 + q_g) * 1024 + h * 64 + ni * 16 + (lane & 15)] = o_acc[mi][ni][r] * inv;
    }
}

// ---------------- launch ----------------
extern "C" void kernel_launch(void* const* d_in, const int* in_sizes, int n_in,
                              void* d_out, int out_size, void* d_ws, size_t ws_size,
                              hipStream_t stream) {
  const float* emb = (const float*)d_in[0];
  const float* Wq  = (const float*)d_in[1];
  const float* Wk  = (const float*)d_in[2];
  const float* Wv  = (const float*)d_in[3];
  char* ws = (char*)d_ws;
  unsigned short* Xb  = (unsigned short*)(ws + 0);          // 8192*1024*2   = 16,777,216
  unsigned short* Wt  = (unsigned short*)(ws + 16777216);   // 3*1024*1024*2 =  6,291,456
  unsigned short* Qb  = (unsigned short*)(ws + 23068672);   // 16,777,216
  unsigned short* Kb  = (unsigned short*)(ws + 39845888);   // 16,777,216
  unsigned short* Vtb = (unsigned short*)(ws + 56623104);   // 16,777,216  (total 73,400,320)
  float* out = (float*)d_out;

  conv_x<<<2048, 256, 0, stream>>>(emb, Xb, 2097152);
  conv_w<<<dim3(256, 3), 256, 0, stream>>>(Wq, Wk, Wv, Wt);
  qkv_gemm<<<dim3(64, 24), 256, 0, stream>>>(Xb, Wt, Qb, Kb, Vtb);
  attn<<<dim3(16, 64), 256, 0, stream>>>(Qb, Kb, Vtb, out);
}

// Round 2
// 298.661 us; speedup vs baseline: 1.5018x; 1.5018x over previous
//
#include <hip/hip_runtime.h>

// Problem: B=4, S=2048, E=1024, H=16, DH=64
// out[b][s][h*64+d] = softmax_causal(Q K^T / 8) V, with Q/K/V = X @ W{q,k,v}[h]
//
// Pipeline:
//   1) conv_x:  embedded f32 -> bf16 (row-major [8192][1024])
//   2) conv_w:  W[p][h][e][d] f32 -> bf16 transposed Wt[p][h*64+d][e]
//   3) qkv_gemm: 128x128 tile, BK=32, global_load_lds(16B), mfma 16x16x32 bf16
//        p=0 -> Q [b][h][s][d], p=1 -> K [b][h][s][d], p=2 -> V^T [b][h][d][s]
//   4) attn: flash, paired causal tiles {31-p, p} (uniform 33 units/block),
//        4 waves x 16 q-rows, 64-key tiles, T14 split staging, DPP rowmax,
//        ones-MFMA rowsum, defer-max.

typedef short bf16x8 __attribute__((ext_vector_type(8)));
typedef float f32x4 __attribute__((ext_vector_type(4)));
typedef unsigned short u16x4 __attribute__((ext_vector_type(4)));
typedef unsigned short u16x8 __attribute__((ext_vector_type(8)));

#define SCL 0.1803368801111204f   /* log2(e)/8 : folds the 1/sqrt(64) into exp2 */

static __device__ __forceinline__ unsigned short f2bf(float f) {
  unsigned int u = __builtin_bit_cast(unsigned int, f);
  u += 0x7fffu + ((u >> 16) & 1u);   // RNE
  return (unsigned short)(u >> 16);
}

static __device__ __forceinline__ void gload16(const void* g, void* l) {
  __builtin_amdgcn_global_load_lds((__attribute__((address_space(1))) void*)g,
                                   (__attribute__((address_space(3))) void*)l, 16, 0, 0);
}

// max-reduce over the 16-lane row (lane&15 direction) via DPP row rotations
#define DPPMAX(x, ctrl) \
  fmaxf(x, __builtin_bit_cast(float, __builtin_amdgcn_update_dpp( \
               0, __builtin_bit_cast(int, x), ctrl, 0xf, 0xf, 1)))
static __device__ __forceinline__ float rowmax16(float x) {
  x = DPPMAX(x, 0x128);  // row_ror:8
  x = DPPMAX(x, 0x124);  // row_ror:4
  x = DPPMAX(x, 0x122);  // row_ror:2
  x = DPPMAX(x, 0x121);  // row_ror:1
  return x;
}

// ---------------- 1) X f32 -> bf16 ----------------
__global__ __launch_bounds__(256) void conv_x(const float* __restrict__ x,
                                              unsigned short* __restrict__ y, int n4) {
  int i0 = blockIdx.x * 256 + threadIdx.x;
  int stride = gridDim.x * 256;
  for (int c = i0; c < n4; c += stride) {
    float4 v = ((const float4*)x)[c];
    u16x4 o;
    o[0] = f2bf(v.x); o[1] = f2bf(v.y); o[2] = f2bf(v.z); o[3] = f2bf(v.w);
    ((u16x4*)y)[c] = o;
  }
}

// ---------------- 2) W transpose+convert: [p][h][e][d] -> Wt[(p*1024 + h*64 + d)][e] ----
__global__ __launch_bounds__(256) void conv_w(const float* __restrict__ Wq,
                                              const float* __restrict__ Wk,
                                              const float* __restrict__ Wv,
                                              unsigned short* __restrict__ Wt) {
  const int p = blockIdx.y;
  const float* Wsrc = (p == 0) ? Wq : ((p == 1) ? Wk : Wv);
  const int h = blockIdx.x >> 4, et = blockIdx.x & 15;   // 64-wide e tile
  const int t = threadIdx.x;
  __shared__ __align__(16) unsigned short tile[64][72];  // [e][d], padded

  const float* src = Wsrc + (h * 1024 + et * 64) * 64;   // rows e (64), cols d (64)
#pragma unroll
  for (int i = 0; i < 4; ++i) {
    int c = i * 256 + t;
    int r = c >> 4, cc = (c & 15) * 4;
    float4 v = *(const float4*)(src + r * 64 + cc);
    tile[r][cc + 0] = f2bf(v.x); tile[r][cc + 1] = f2bf(v.y);
    tile[r][cc + 2] = f2bf(v.z); tile[r][cc + 3] = f2bf(v.w);
  }
  __syncthreads();
#pragma unroll
  for (int i = 0; i < 2; ++i) {
    int c = i * 256 + t;
    int d = c >> 3, ec = (c & 7) * 8;
    u16x8 o;
#pragma unroll
    for (int j = 0; j < 8; ++j) o[j] = tile[ec + j][d];
    *(u16x8*)(Wt + (p * 1024 + h * 64 + d) * 1024 + et * 64 + ec) = o;
  }
}

// ---------------- 3) QKV projection GEMM ----------------
__global__ __launch_bounds__(256) void qkv_gemm(const unsigned short* __restrict__ Xb,
                                                const unsigned short* __restrict__ Wt,
                                                unsigned short* __restrict__ Qb,
                                                unsigned short* __restrict__ Kb,
                                                unsigned short* __restrict__ Vtb) {
  __shared__ __align__(16) unsigned short As[128 * 32];  // [m][k] rows 64B
  __shared__ __align__(16) unsigned short Bs[128 * 32];  // [n][k] rows 64B
  const int t = threadIdx.x, lane = t & 63, w = t >> 6;
  const int wr = w >> 1, wc = w & 1;
  const int m0 = blockIdx.x * 128;
  const int pt = blockIdx.y;
  const int p = pt >> 3, n0 = (pt & 7) * 128;

  f32x4 acc[4][4] = {};

  const unsigned short* Ag = Xb + (m0 + w * 32 + (lane >> 2)) * 1024 + (lane & 3) * 8;
  const unsigned short* Bg = Wt + (p * 1024 + n0 + w * 32 + (lane >> 2)) * 1024 + (lane & 3) * 8;
  unsigned short* AsW = &As[w * 1024];
  unsigned short* BsW = &Bs[w * 1024];

  for (int kt = 0; kt < 32; ++kt) {
    __syncthreads();
    gload16(Ag + kt * 32,             AsW);
    gload16(Ag + kt * 32 + 16 * 1024, AsW + 512);
    gload16(Bg + kt * 32,             BsW);
    gload16(Bg + kt * 32 + 16 * 1024, BsW + 512);
    asm volatile("s_waitcnt vmcnt(0)" ::: "memory");
    __syncthreads();

    bf16x8 a[4], bfr[4];
#pragma unroll
    for (int mi = 0; mi < 4; ++mi)
      a[mi] = *(const bf16x8*)&As[(wr * 64 + mi * 16 + (lane & 15)) * 32 + (lane >> 4) * 8];
#pragma unroll
    for (int ni = 0; ni < 4; ++ni)
      bfr[ni] = *(const bf16x8*)&Bs[(wc * 64 + ni * 16 + (lane & 15)) * 32 + (lane >> 4) * 8];

    if (p != 2) {
#pragma unroll
      for (int mi = 0; mi < 4; ++mi)
#pragma unroll
        for (int ni = 0; ni < 4; ++ni)
          acc[mi][ni] = __builtin_amdgcn_mfma_f32_16x16x32_bf16(a[mi], bfr[ni], acc[mi][ni], 0, 0, 0);
    } else {  // C^T so V stores coalesce in [d][s] layout
#pragma unroll
      for (int mi = 0; mi < 4; ++mi)
#pragma unroll
        for (int ni = 0; ni < 4; ++ni)
          acc[mi][ni] = __builtin_amdgcn_mfma_f32_16x16x32_bf16(bfr[ni], a[mi], acc[mi][ni], 0, 0, 0);
    }
  }

  if (p != 2) {
    unsigned short* dst = (p == 0) ? Qb : Kb;
#pragma unroll
    for (int mi = 0; mi < 4; ++mi)
#pragma unroll
      for (int ni = 0; ni < 4; ++ni)
#pragma unroll
        for (int r = 0; r < 4; ++r) {
          int m_g = m0 + wr * 64 + mi * 16 + (lane >> 4) * 4 + r;
          int n_g = n0 + wc * 64 + ni * 16 + (lane & 15);
          int b = m_g >> 11, s = m_g & 2047;
          dst[((b * 16 + (n_g >> 6)) * 2048 + s) * 64 + (n_g & 63)] = f2bf(acc[mi][ni][r]);
        }
  } else {
#pragma unroll
    for (int mi = 0; mi < 4; ++mi)
#pragma unroll
      for (int ni = 0; ni < 4; ++ni)
#pragma unroll
        for (int r = 0; r < 4; ++r) {
          int n_g = n0 + wc * 64 + ni * 16 + (lane >> 4) * 4 + r;  // d
          int m_g = m0 + wr * 64 + mi * 16 + (lane & 15);          // s
          int b = m_g >> 11, s = m_g & 2047;
          Vtb[((b * 16 + (n_g >> 6)) * 64 + (n_g & 63)) * 2048 + s] = f2bf(acc[mi][ni][r]);
        }
  }
}

// ---------------- 4) Flash attention (causal, paired tiles) ----------------
// grid (16 pairs, 64 bh). Block p handles q-tiles {31-p, p} (64 rows each) ->
// uniform 33 k-tile units per block. 4 waves x 16 q-rows.
__global__ __launch_bounds__(256, 4) void attn(const unsigned short* __restrict__ Qb,
                                               const unsigned short* __restrict__ Kb,
                                               const unsigned short* __restrict__ Vtb,
                                               float* __restrict__ out) {
  const int bh = blockIdx.y;
  const int t = threadIdx.x, lane = t & 63, w = t >> 6;
  const int g = lane >> 4, c = lane & 15;
  const int b = bh >> 4, h = bh & 15;

  __shared__ __align__(16) unsigned short Ks[64][72];      // [key][d] padded
  __shared__ __align__(16) unsigned short Vs[64][72];      // [d][key] padded
  __shared__ __align__(16) unsigned short Ps[4][16][72];   // per-wave P [qrow][key]

  const short onev = (c == 0) ? (short)0x3f80 : (short)0;  // bf16 1.0 in col 0
  bf16x8 onesf = {onev, onev, onev, onev, onev, onev, onev, onev};

  for (int job = 0; job < 2; ++job) {
    const int qt = job ? (int)blockIdx.x : 31 - (int)blockIdx.x;
    const int q0 = qt * 64;
    const int ktiles = qt + 1;

    bf16x8 qf[2];
#pragma unroll
    for (int kc = 0; kc < 2; ++kc)
      qf[kc] = *(const bf16x8*)(Qb + ((bh * 2048 + q0 + w * 16 + c) << 6) + kc * 32 + g * 8);

    f32x4 o_acc[4] = {};
    f32x4 o_l = {};
    float m_r[4] = {-INFINITY, -INFINITY, -INFINITY, -INFINITY};

    uint4 kr[2], vr[2];
    // prologue: stage tile 0
#pragma unroll
    for (int i = 0; i < 2; ++i) {
      int cid = i * 256 + t;
      kr[i] = *(const uint4*)(Kb + ((bh * 2048) << 6) + cid * 8);
      vr[i] = *(const uint4*)(Vtb + ((bh * 64 + (cid >> 3)) << 11) + (cid & 7) * 8);
    }
#pragma unroll
    for (int i = 0; i < 2; ++i) {
      int cid = i * 256 + t;
      *(uint4*)&Ks[cid >> 3][(cid & 7) * 8] = kr[i];
      *(uint4*)&Vs[cid >> 3][(cid & 7) * 8] = vr[i];
    }
    __syncthreads();

    for (int kt = 0; kt < ktiles; ++kt) {
      // T14: issue next tile's global loads before compute (latency hides)
      if (kt + 1 < ktiles) {
        const int kv0 = (kt + 1) * 64;
#pragma unroll
        for (int i = 0; i < 2; ++i) {
          int cid = i * 256 + t;
          kr[i] = *(const uint4*)(Kb + ((bh * 2048 + kv0) << 6) + cid * 8);
          vr[i] = *(const uint4*)(Vtb + ((bh * 64 + (cid >> 3)) << 11) + kv0 + (cid & 7) * 8);
        }
      }

      // QK^T (raw scores; 1/8 scale folded into exp2 later)
      f32x4 sc[4];
#pragma unroll
      for (int sub = 0; sub < 4; ++sub) {
        bf16x8 kf0 = *(const bf16x8*)&Ks[sub * 16 + c][g * 8];
        bf16x8 kf1 = *(const bf16x8*)&Ks[sub * 16 + c][32 + g * 8];
        f32x4 z = {};
        z = __builtin_amdgcn_mfma_f32_16x16x32_bf16(qf[0], kf0, z, 0, 0, 0);
        z = __builtin_amdgcn_mfma_f32_16x16x32_bf16(qf[1], kf1, z, 0, 0, 0);
        sc[sub] = z;
      }

      if (kt == qt) {  // diagonal tile: causal mask
#pragma unroll
        for (int sub = 0; sub < 4; ++sub)
#pragma unroll
          for (int r = 0; r < 4; ++r)
            if (sub * 16 + c > w * 16 + 4 * g + r) sc[sub][r] = -INFINITY;
      }

      // row max (in-reg over 4 subs, then DPP over the 16-lane row)
      float rm[4];
#pragma unroll
      for (int r = 0; r < 4; ++r) {
        float v = fmaxf(fmaxf(sc[0][r], sc[1][r]), fmaxf(sc[2][r], sc[3][r]));
        rm[r] = rowmax16(v);
      }
      // defer-max: only rescale when max grew materially (THR=44 raw ~ 8 nats)
      bool small = (rm[0] <= m_r[0] + 44.f) & (rm[1] <= m_r[1] + 44.f) &
                   (rm[2] <= m_r[2] + 44.f) & (rm[3] <= m_r[3] + 44.f);
      if (!__all(small)) {
#pragma unroll
        for (int r = 0; r < 4; ++r) {
          float mnew = fmaxf(m_r[r], rm[r]);
          float corr = __builtin_amdgcn_exp2f((m_r[r] - mnew) * SCL);
          m_r[r] = mnew;
#pragma unroll
          for (int ni = 0; ni < 4; ++ni) o_acc[ni][r] *= corr;
          o_l[r] *= corr;
        }
      }

      // P = exp2((s - m)*SCL) -> bf16 -> per-wave LDS
#pragma unroll
      for (int r = 0; r < 4; ++r) {
        float a = -m_r[r] * SCL;
#pragma unroll
        for (int sub = 0; sub < 4; ++sub) {
          float e = __builtin_amdgcn_exp2f(fmaf(sc[sub][r], SCL, a));
          Ps[w][4 * g + r][sub * 16 + c] = f2bf(e);
        }
      }

      // PV + rowsum via ones-column MFMA
      bf16x8 pf0 = *(const bf16x8*)&Ps[w][c][g * 8];
      bf16x8 pf1 = *(const bf16x8*)&Ps[w][c][32 + g * 8];
#pragma unroll
      for (int ni = 0; ni < 4; ++ni) {
        bf16x8 vf0 = *(const bf16x8*)&Vs[ni * 16 + c][g * 8];
        bf16x8 vf1 = *(const bf16x8*)&Vs[ni * 16 + c][32 + g * 8];
        o_acc[ni] = __builtin_amdgcn_mfma_f32_16x16x32_bf16(pf0, vf0, o_acc[ni], 0, 0, 0);
        o_acc[ni] = __builtin_amdgcn_mfma_f32_16x16x32_bf16(pf1, vf1, o_acc[ni], 0, 0, 0);
      }
      o_l = __builtin_amdgcn_mfma_f32_16x16x32_bf16(pf0, onesf, o_l, 0, 0, 0);
      o_l = __builtin_amdgcn_mfma_f32_16x16x32_bf16(pf1, onesf, o_l, 0, 0, 0);

      __syncthreads();                       // all waves done reading Ks/Vs
      if (kt + 1 < ktiles) {                 // T14: write prefetched tile
#pragma unroll
        for (int i = 0; i < 2; ++i) {
          int cid = i * 256 + t;
          *(uint4*)&Ks[cid >> 3][(cid & 7) * 8] = kr[i];
          *(uint4*)&Vs[cid >> 3][(cid & 7) * 8] = vr[i];
        }
        __syncthreads();                     // visible before next iter
      }
    }

    // epilogue: out[b][q][h*64+d] = O / l   (l sits in col-0 lanes of o_l)
#pragma unroll
    for (int r = 0; r < 4; ++r) {
      float l = __shfl(o_l[r], lane & 48);
      float inv = 1.f / l;
      int q_g = q0 + w * 16 + 4 * g + r;
#pragma unroll
      for (int ni = 0; ni < 4; ++ni)
        out[(b * 2048 + q_g) * 1024 + h * 64 + ni * 16 + c] = o_acc[ni][r] * inv;
    }
  }
}

// ---------------- launch ----------------
extern "C" void kernel_launch(void* const* d_in, const int* in_sizes, int n_in,
                              void* d_out, int out_size, void* d_ws, size_t ws_size,
                              hipStream_t stream) {
  const float* emb = (const float*)d_in[0];
  const float* Wq  = (const float*)d_in[1];
  const float* Wk  = (const float*)d_in[2];
  const float* Wv  = (const float*)d_in[3];
  char* ws = (char*)d_ws;
  unsigned short* Xb  = (unsigned short*)(ws + 0);          // 16,777,216
  unsigned short* Wt  = (unsigned short*)(ws + 16777216);   //  6,291,456
  unsigned short* Qb  = (unsigned short*)(ws + 23068672);   // 16,777,216
  unsigned short* Kb  = (unsigned short*)(ws + 39845888);   // 16,777,216
  unsigned short* Vtb = (unsigned short*)(ws + 56623104);   // 16,777,216
  float* out = (float*)d_out;

  conv_x<<<2048, 256, 0, stream>>>(emb, Xb, 2097152);
  conv_w<<<dim3(256, 3), 256, 0, stream>>>(Wq, Wk, Wv, Wt);
  qkv_gemm<<<dim3(64, 24), 256, 0, stream>>>(Xb, Wt, Qb, Kb, Vtb);
  attn<<<dim3(16, 64), 256, 0, stream>>>(Qb, Kb, Vtb, out);
}

// Round 3
// 251.420 us; speedup vs baseline: 1.7839x; 1.1879x over previous
//
#include <hip/hip_runtime.h>

// Problem: B=4, S=2048, E=1024, H=16, DH=64
// out[b][s][h*64+d] = softmax_causal(Q K^T / 8) V, with Q/K/V = X @ W{q,k,v}[h]
//
// Pipeline:
//   1) conv_x:  embedded f32 -> bf16 (row-major [8192][1024])
//   2) conv_w:  W[p][h][e][d] f32 -> bf16 transposed Wt[p][h*64+d][e]
//   3) qkv_gemm: 128x128 tile, BK=32, global_load_lds(16B), mfma 16x16x32 bf16
//        p=0 -> Q [b][h][s][d], p=1 -> K [b][h][s][d], p=2 -> V^T [b][h][d][s]
//   4) attn: flash. 128-row q-tiles, paired {15-p, p} (uniform 34 k-units/block),
//        XCD-grouped grid (all blocks of a head share one L2), 4 waves x 32 rows,
//        T14 reg prefetch (NO launch-bounds squeeze -> no spills), DPP rowmax,
//        ones-MFMA rowsum, defer-max.

typedef short bf16x8 __attribute__((ext_vector_type(8)));
typedef float f32x4 __attribute__((ext_vector_type(4)));
typedef unsigned short u16x4 __attribute__((ext_vector_type(4)));
typedef unsigned short u16x8 __attribute__((ext_vector_type(8)));

#define SCL 0.1803368801111204f   /* log2(e)/8 : folds the 1/sqrt(64) into exp2 */

static __device__ __forceinline__ unsigned short f2bf(float f) {
  unsigned int u = __builtin_bit_cast(unsigned int, f);
  u += 0x7fffu + ((u >> 16) & 1u);   // RNE
  return (unsigned short)(u >> 16);
}

static __device__ __forceinline__ void gload16(const void* g, void* l) {
  __builtin_amdgcn_global_load_lds((__attribute__((address_space(1))) void*)g,
                                   (__attribute__((address_space(3))) void*)l, 16, 0, 0);
}

// max-reduce over the 16-lane row (lane&15 direction) via DPP row rotations
#define DPPMAX(x, ctrl) \
  fmaxf(x, __builtin_bit_cast(float, __builtin_amdgcn_update_dpp( \
               0, __builtin_bit_cast(int, x), ctrl, 0xf, 0xf, 1)))
static __device__ __forceinline__ float rowmax16(float x) {
  x = DPPMAX(x, 0x128);  // row_ror:8
  x = DPPMAX(x, 0x124);  // row_ror:4
  x = DPPMAX(x, 0x122);  // row_ror:2
  x = DPPMAX(x, 0x121);  // row_ror:1
  return x;
}

// ---------------- 1) X f32 -> bf16 ----------------
__global__ __launch_bounds__(256) void conv_x(const float* __restrict__ x,
                                              unsigned short* __restrict__ y, int n4) {
  int i0 = blockIdx.x * 256 + threadIdx.x;
  int stride = gridDim.x * 256;
  for (int c = i0; c < n4; c += stride) {
    float4 v = ((const float4*)x)[c];
    u16x4 o;
    o[0] = f2bf(v.x); o[1] = f2bf(v.y); o[2] = f2bf(v.z); o[3] = f2bf(v.w);
    ((u16x4*)y)[c] = o;
  }
}

// ---------------- 2) W transpose+convert: [p][h][e][d] -> Wt[(p*1024 + h*64 + d)][e] ----
__global__ __launch_bounds__(256) void conv_w(const float* __restrict__ Wq,
                                              const float* __restrict__ Wk,
                                              const float* __restrict__ Wv,
                                              unsigned short* __restrict__ Wt) {
  const int p = blockIdx.y;
  const float* Wsrc = (p == 0) ? Wq : ((p == 1) ? Wk : Wv);
  const int h = blockIdx.x >> 4, et = blockIdx.x & 15;   // 64-wide e tile
  const int t = threadIdx.x;
  __shared__ __align__(16) unsigned short tile[64][72];  // [e][d], padded

  const float* src = Wsrc + (h * 1024 + et * 64) * 64;   // rows e (64), cols d (64)
#pragma unroll
  for (int i = 0; i < 4; ++i) {
    int c = i * 256 + t;
    int r = c >> 4, cc = (c & 15) * 4;
    float4 v = *(const float4*)(src + r * 64 + cc);
    tile[r][cc + 0] = f2bf(v.x); tile[r][cc + 1] = f2bf(v.y);
    tile[r][cc + 2] = f2bf(v.z); tile[r][cc + 3] = f2bf(v.w);
  }
  __syncthreads();
#pragma unroll
  for (int i = 0; i < 2; ++i) {
    int c = i * 256 + t;
    int d = c >> 3, ec = (c & 7) * 8;
    u16x8 o;
#pragma unroll
    for (int j = 0; j < 8; ++j) o[j] = tile[ec + j][d];
    *(u16x8*)(Wt + (p * 1024 + h * 64 + d) * 1024 + et * 64 + ec) = o;
  }
}

// ---------------- 3) QKV projection GEMM ----------------
__global__ __launch_bounds__(256) void qkv_gemm(const unsigned short* __restrict__ Xb,
                                                const unsigned short* __restrict__ Wt,
                                                unsigned short* __restrict__ Qb,
                                                unsigned short* __restrict__ Kb,
                                                unsigned short* __restrict__ Vtb) {
  __shared__ __align__(16) unsigned short As[128 * 32];  // [m][k] rows 64B
  __shared__ __align__(16) unsigned short Bs[128 * 32];  // [n][k] rows 64B
  const int t = threadIdx.x, lane = t & 63, w = t >> 6;
  const int wr = w >> 1, wc = w & 1;
  const int m0 = blockIdx.x * 128;
  const int pt = blockIdx.y;
  const int p = pt >> 3, n0 = (pt & 7) * 128;

  f32x4 acc[4][4] = {};

  const unsigned short* Ag = Xb + (m0 + w * 32 + (lane >> 2)) * 1024 + (lane & 3) * 8;
  const unsigned short* Bg = Wt + (p * 1024 + n0 + w * 32 + (lane >> 2)) * 1024 + (lane & 3) * 8;
  unsigned short* AsW = &As[w * 1024];
  unsigned short* BsW = &Bs[w * 1024];

  for (int kt = 0; kt < 32; ++kt) {
    __syncthreads();
    gload16(Ag + kt * 32,             AsW);
    gload16(Ag + kt * 32 + 16 * 1024, AsW + 512);
    gload16(Bg + kt * 32,             BsW);
    gload16(Bg + kt * 32 + 16 * 1024, BsW + 512);
    asm volatile("s_waitcnt vmcnt(0)" ::: "memory");
    __syncthreads();

    bf16x8 a[4], bfr[4];
#pragma unroll
    for (int mi = 0; mi < 4; ++mi)
      a[mi] = *(const bf16x8*)&As[(wr * 64 + mi * 16 + (lane & 15)) * 32 + (lane >> 4) * 8];
#pragma unroll
    for (int ni = 0; ni < 4; ++ni)
      bfr[ni] = *(const bf16x8*)&Bs[(wc * 64 + ni * 16 + (lane & 15)) * 32 + (lane >> 4) * 8];

    if (p != 2) {
#pragma unroll
      for (int mi = 0; mi < 4; ++mi)
#pragma unroll
        for (int ni = 0; ni < 4; ++ni)
          acc[mi][ni] = __builtin_amdgcn_mfma_f32_16x16x32_bf16(a[mi], bfr[ni], acc[mi][ni], 0, 0, 0);
    } else {  // C^T so V stores coalesce in [d][s] layout
#pragma unroll
      for (int mi = 0; mi < 4; ++mi)
#pragma unroll
        for (int ni = 0; ni < 4; ++ni)
          acc[mi][ni] = __builtin_amdgcn_mfma_f32_16x16x32_bf16(bfr[ni], a[mi], acc[mi][ni], 0, 0, 0);
    }
  }

  if (p != 2) {
    unsigned short* dst = (p == 0) ? Qb : Kb;
#pragma unroll
    for (int mi = 0; mi < 4; ++mi)
#pragma unroll
      for (int ni = 0; ni < 4; ++ni)
#pragma unroll
        for (int r = 0; r < 4; ++r) {
          int m_g = m0 + wr * 64 + mi * 16 + (lane >> 4) * 4 + r;
          int n_g = n0 + wc * 64 + ni * 16 + (lane & 15);
          int b = m_g >> 11, s = m_g & 2047;
          dst[((b * 16 + (n_g >> 6)) * 2048 + s) * 64 + (n_g & 63)] = f2bf(acc[mi][ni][r]);
        }
  } else {
#pragma unroll
    for (int mi = 0; mi < 4; ++mi)
#pragma unroll
      for (int ni = 0; ni < 4; ++ni)
#pragma unroll
        for (int r = 0; r < 4; ++r) {
          int n_g = n0 + wc * 64 + ni * 16 + (lane >> 4) * 4 + r;  // d
          int m_g = m0 + wr * 64 + mi * 16 + (lane & 15);          // s
          int b = m_g >> 11, s = m_g & 2047;
          Vtb[((b * 16 + (n_g >> 6)) * 64 + (n_g & 63)) * 2048 + s] = f2bf(acc[mi][ni][r]);
        }
  }
}

// ---------------- 4) Flash attention (causal, 128-row paired tiles, XCD-grouped) ----
// 1D grid 512. xcd = bid&7; 8 heads per XCD; 8 pair-blocks per head.
// Block pair p handles q-tiles {15-p, p} (128 rows each) -> uniform 34 k-units.
// 4 waves x 32 q-rows; 64-key k-tiles.
__global__ __launch_bounds__(256) void attn(const unsigned short* __restrict__ Qb,
                                            const unsigned short* __restrict__ Kb,
                                            const unsigned short* __restrict__ Vtb,
                                            float* __restrict__ out) {
  const int bid = blockIdx.x;
  const int xcd = bid & 7, slot = bid >> 3;
  const int bh = xcd * 8 + (slot >> 3);     // all blocks of a head on one XCD
  const int pp = slot & 7;                  // pair index 0..7
  const int b = bh >> 4, h = bh & 15;
  const int t = threadIdx.x, lane = t & 63, w = t >> 6;
  const int g = lane >> 4, c = lane & 15;

  __shared__ __align__(16) unsigned short Ks[64][72];      // [key][d] padded
  __shared__ __align__(16) unsigned short Vs[64][72];      // [d][key] padded
  __shared__ __align__(16) unsigned short Ps[4][32][72];   // per-wave P [qrow][key]

  const short onev = (c == 0) ? (short)0x3f80 : (short)0;  // bf16 1.0 in col 0
  const bf16x8 onesf = {onev, onev, onev, onev, onev, onev, onev, onev};

  for (int job = 0; job < 2; ++job) {
    const int qt = job ? pp : 15 - pp;
    const int q0 = qt * 128;
    const int ktiles = 2 * qt + 2;

    bf16x8 qf[2][2];
#pragma unroll
    for (int mi = 0; mi < 2; ++mi)
#pragma unroll
      for (int kc = 0; kc < 2; ++kc)
        qf[mi][kc] = *(const bf16x8*)(Qb + ((bh * 2048 + q0 + w * 32 + mi * 16 + c) << 6)
                                         + kc * 32 + g * 8);

    f32x4 o_acc[2][4] = {};
    f32x4 o_l[2] = {};
    float m_r[2][4];
#pragma unroll
    for (int mi = 0; mi < 2; ++mi)
#pragma unroll
      for (int r = 0; r < 4; ++r) m_r[mi][r] = -INFINITY;

    uint4 kr[2], vr[2];
    // prologue: stage k-tile 0
#pragma unroll
    for (int i = 0; i < 2; ++i) {
      int cid = i * 256 + t;
      kr[i] = *(const uint4*)(Kb + ((bh * 2048) << 6) + cid * 8);
      vr[i] = *(const uint4*)(Vtb + ((bh * 64 + (cid >> 3)) << 11) + (cid & 7) * 8);
    }
#pragma unroll
    for (int i = 0; i < 2; ++i) {
      int cid = i * 256 + t;
      *(uint4*)&Ks[cid >> 3][(cid & 7) * 8] = kr[i];
      *(uint4*)&Vs[cid >> 3][(cid & 7) * 8] = vr[i];
    }
    __syncthreads();

    for (int kt = 0; kt < ktiles; ++kt) {
      // T14: issue next tile's global loads before compute
      if (kt + 1 < ktiles) {
        const int kv0 = (kt + 1) * 64;
#pragma unroll
        for (int i = 0; i < 2; ++i) {
          int cid = i * 256 + t;
          kr[i] = *(const uint4*)(Kb + ((bh * 2048 + kv0) << 6) + cid * 8);
          vr[i] = *(const uint4*)(Vtb + ((bh * 64 + (cid >> 3)) << 11) + kv0 + (cid & 7) * 8);
        }
      }

      // QK^T (raw scores; 1/8 folded into exp2)
      f32x4 sc[2][4];
#pragma unroll
      for (int sub = 0; sub < 4; ++sub) {
        bf16x8 kf0 = *(const bf16x8*)&Ks[sub * 16 + c][g * 8];
        bf16x8 kf1 = *(const bf16x8*)&Ks[sub * 16 + c][32 + g * 8];
#pragma unroll
        for (int mi = 0; mi < 2; ++mi) {
          f32x4 z = {};
          z = __builtin_amdgcn_mfma_f32_16x16x32_bf16(qf[mi][0], kf0, z, 0, 0, 0);
          z = __builtin_amdgcn_mfma_f32_16x16x32_bf16(qf[mi][1], kf1, z, 0, 0, 0);
          sc[mi][sub] = z;
        }
      }

      if (kt >= 2 * qt) {  // diagonal-adjacent tiles: causal mask
        const int koff = (kt - 2 * qt) * 64;
#pragma unroll
        for (int mi = 0; mi < 2; ++mi) {
          const int wrow = w * 32 + mi * 16 + 4 * g;
#pragma unroll
          for (int sub = 0; sub < 4; ++sub)
#pragma unroll
            for (int r = 0; r < 4; ++r)
              if (koff + sub * 16 + c > wrow + r) sc[mi][sub][r] = -INFINITY;
        }
      }

      // row max per (mi, r): in-reg over subs, then DPP over 16-lane row
      float rm[2][4];
#pragma unroll
      for (int mi = 0; mi < 2; ++mi)
#pragma unroll
        for (int r = 0; r < 4; ++r) {
          float v = fmaxf(fmaxf(sc[mi][0][r], sc[mi][1][r]),
                          fmaxf(sc[mi][2][r], sc[mi][3][r]));
          rm[mi][r] = rowmax16(v);
        }

      // defer-max: rescale only when the max grew materially (44 raw ~ 8 nats)
      bool small = true;
#pragma unroll
      for (int mi = 0; mi < 2; ++mi)
#pragma unroll
        for (int r = 0; r < 4; ++r)
          small &= (rm[mi][r] <= m_r[mi][r] + 44.f);
      if (!__all(small)) {
#pragma unroll
        for (int mi = 0; mi < 2; ++mi)
#pragma unroll
          for (int r = 0; r < 4; ++r) {
            float mnew = fmaxf(m_r[mi][r], rm[mi][r]);
            float corr = __builtin_amdgcn_exp2f((m_r[mi][r] - mnew) * SCL);
            m_r[mi][r] = mnew;
#pragma unroll
            for (int ni = 0; ni < 4; ++ni) o_acc[mi][ni][r] *= corr;
            o_l[mi][r] *= corr;
          }
      }

      // P = exp2((s - m)*SCL) -> bf16 -> per-wave LDS
#pragma unroll
      for (int mi = 0; mi < 2; ++mi)
#pragma unroll
        for (int r = 0; r < 4; ++r) {
          float a = -m_r[mi][r] * SCL;
#pragma unroll
          for (int sub = 0; sub < 4; ++sub) {
            float e = __builtin_amdgcn_exp2f(fmaf(sc[mi][sub][r], SCL, a));
            Ps[w][mi * 16 + 4 * g + r][sub * 16 + c] = f2bf(e);
          }
        }

      // PV + rowsum via ones-column MFMA
      bf16x8 pf[2][2];
#pragma unroll
      for (int mi = 0; mi < 2; ++mi) {
        pf[mi][0] = *(const bf16x8*)&Ps[w][mi * 16 + c][g * 8];
        pf[mi][1] = *(const bf16x8*)&Ps[w][mi * 16 + c][32 + g * 8];
      }
#pragma unroll
      for (int ni = 0; ni < 4; ++ni) {
        bf16x8 vf0 = *(const bf16x8*)&Vs[ni * 16 + c][g * 8];
        bf16x8 vf1 = *(const bf16x8*)&Vs[ni * 16 + c][32 + g * 8];
#pragma unroll
        for (int mi = 0; mi < 2; ++mi) {
          o_acc[mi][ni] = __builtin_amdgcn_mfma_f32_16x16x32_bf16(pf[mi][0], vf0, o_acc[mi][ni], 0, 0, 0);
          o_acc[mi][ni] = __builtin_amdgcn_mfma_f32_16x16x32_bf16(pf[mi][1], vf1, o_acc[mi][ni], 0, 0, 0);
        }
      }
#pragma unroll
      for (int mi = 0; mi < 2; ++mi) {
        o_l[mi] = __builtin_amdgcn_mfma_f32_16x16x32_bf16(pf[mi][0], onesf, o_l[mi], 0, 0, 0);
        o_l[mi] = __builtin_amdgcn_mfma_f32_16x16x32_bf16(pf[mi][1], onesf, o_l[mi], 0, 0, 0);
      }

      __syncthreads();                       // all waves done reading Ks/Vs
      if (kt + 1 < ktiles) {                 // T14: write prefetched tile
#pragma unroll
        for (int i = 0; i < 2; ++i) {
          int cid = i * 256 + t;
          *(uint4*)&Ks[cid >> 3][(cid & 7) * 8] = kr[i];
          *(uint4*)&Vs[cid >> 3][(cid & 7) * 8] = vr[i];
        }
        __syncthreads();                     // visible before next iter
      }
    }

    // epilogue: out[b][q][h*64+d] = O / l   (l in col-0 lanes of o_l)
#pragma unroll
    for (int mi = 0; mi < 2; ++mi)
#pragma unroll
      for (int r = 0; r < 4; ++r) {
        float l = __shfl(o_l[mi][r], lane & 48);
        float inv = 1.f / l;
        int q_g = q0 + w * 32 + mi * 16 + 4 * g + r;
#pragma unroll
        for (int ni = 0; ni < 4; ++ni)
          out[(b * 2048 + q_g) * 1024 + h * 64 + ni * 16 + c] = o_acc[mi][ni][r] * inv;
      }
  }
}

// ---------------- launch ----------------
extern "C" void kernel_launch(void* const* d_in, const int* in_sizes, int n_in,
                              void* d_out, int out_size, void* d_ws, size_t ws_size,
                              hipStream_t stream) {
  const float* emb = (const float*)d_in[0];
  const float* Wq  = (const float*)d_in[1];
  const float* Wk  = (const float*)d_in[2];
  const float* Wv  = (const float*)d_in[3];
  char* ws = (char*)d_ws;
  unsigned short* Xb  = (unsigned short*)(ws + 0);          // 16,777,216
  unsigned short* Wt  = (unsigned short*)(ws + 16777216);   //  6,291,456
  unsigned short* Qb  = (unsigned short*)(ws + 23068672);   // 16,777,216
  unsigned short* Kb  = (unsigned short*)(ws + 39845888);   // 16,777,216
  unsigned short* Vtb = (unsigned short*)(ws + 56623104);   // 16,777,216
  float* out = (float*)d_out;

  conv_x<<<2048, 256, 0, stream>>>(emb, Xb, 2097152);
  conv_w<<<dim3(256, 3), 256, 0, stream>>>(Wq, Wk, Wv, Wt);
  qkv_gemm<<<dim3(64, 24), 256, 0, stream>>>(Xb, Wt, Qb, Kb, Vtb);
  attn<<<512, 256, 0, stream>>>(Qb, Kb, Vtb, out);
}

// Round 4
// 207.595 us; speedup vs baseline: 2.1605x; 1.2111x over previous
//
#include <hip/hip_runtime.h>

// Problem: B=4, S=2048, E=1024, H=16, DH=64
// out[b][s][h*64+d] = softmax_causal(Q K^T / 8) V, with Q/K/V = X @ W{q,k,v}[h]
//
// Pipeline:
//   1) conv_x:  embedded f32 -> bf16 (row-major [8192][1024])
//   2) conv_w:  W[p][h][e][d] f32 -> bf16 transposed Wt[p][h*64+d][e]
//   3) qkv_gemm: 128x128 tile, BK=32, global_load_lds(16B), mfma 16x16x32 bf16
//        p=0 -> Q [b][h][s][d], p=1 -> K [b][h][s][d], p=2 -> V^T [b][h][d][s]
//   4) attn: flash, swapped-QK^T (S^T in regs -> lane-local softmax, P never
//        touches LDS), permuted-k PV (O^T = mfma(V^T, P^T)), K/V LDS double
//        buffer (1 barrier/tile), T14 reg prefetch, XCD-grouped grid,
//        paired causal tiles {15-p, p} (uniform 36 k-units/block).

typedef short bf16x4 __attribute__((ext_vector_type(4)));
typedef short bf16x8 __attribute__((ext_vector_type(8)));
typedef float f32x4 __attribute__((ext_vector_type(4)));
typedef unsigned short u16x4 __attribute__((ext_vector_type(4)));
typedef unsigned short u16x8 __attribute__((ext_vector_type(8)));

#define SCL 0.1803368801111204f   /* log2(e)/8 : folds the 1/sqrt(64) into exp2 */

static __device__ __forceinline__ unsigned short f2bf(float f) {
  unsigned int u = __builtin_bit_cast(unsigned int, f);
  u += 0x7fffu + ((u >> 16) & 1u);   // RNE
  return (unsigned short)(u >> 16);
}

static __device__ __forceinline__ void gload16(const void* g, void* l) {
  __builtin_amdgcn_global_load_lds((__attribute__((address_space(1))) void*)g,
                                   (__attribute__((address_space(3))) void*)l, 16, 0, 0);
}

// ---------------- 1) X f32 -> bf16 ----------------
__global__ __launch_bounds__(256) void conv_x(const float* __restrict__ x,
                                              unsigned short* __restrict__ y, int n4) {
  int i0 = blockIdx.x * 256 + threadIdx.x;
  int stride = gridDim.x * 256;
  for (int c = i0; c < n4; c += stride) {
    float4 v = ((const float4*)x)[c];
    u16x4 o;
    o[0] = f2bf(v.x); o[1] = f2bf(v.y); o[2] = f2bf(v.z); o[3] = f2bf(v.w);
    ((u16x4*)y)[c] = o;
  }
}

// ---------------- 2) W transpose+convert: [p][h][e][d] -> Wt[(p*1024 + h*64 + d)][e] ----
__global__ __launch_bounds__(256) void conv_w(const float* __restrict__ Wq,
                                              const float* __restrict__ Wk,
                                              const float* __restrict__ Wv,
                                              unsigned short* __restrict__ Wt) {
  const int p = blockIdx.y;
  const float* Wsrc = (p == 0) ? Wq : ((p == 1) ? Wk : Wv);
  const int h = blockIdx.x >> 4, et = blockIdx.x & 15;   // 64-wide e tile
  const int t = threadIdx.x;
  __shared__ __align__(16) unsigned short tile[64][72];  // [e][d], padded

  const float* src = Wsrc + (h * 1024 + et * 64) * 64;   // rows e (64), cols d (64)
#pragma unroll
  for (int i = 0; i < 4; ++i) {
    int c = i * 256 + t;
    int r = c >> 4, cc = (c & 15) * 4;
    float4 v = *(const float4*)(src + r * 64 + cc);
    tile[r][cc + 0] = f2bf(v.x); tile[r][cc + 1] = f2bf(v.y);
    tile[r][cc + 2] = f2bf(v.z); tile[r][cc + 3] = f2bf(v.w);
  }
  __syncthreads();
#pragma unroll
  for (int i = 0; i < 2; ++i) {
    int c = i * 256 + t;
    int d = c >> 3, ec = (c & 7) * 8;
    u16x8 o;
#pragma unroll
    for (int j = 0; j < 8; ++j) o[j] = tile[ec + j][d];
    *(u16x8*)(Wt + (p * 1024 + h * 64 + d) * 1024 + et * 64 + ec) = o;
  }
}

// ---------------- 3) QKV projection GEMM ----------------
__global__ __launch_bounds__(256) void qkv_gemm(const unsigned short* __restrict__ Xb,
                                                const unsigned short* __restrict__ Wt,
                                                unsigned short* __restrict__ Qb,
                                                unsigned short* __restrict__ Kb,
                                                unsigned short* __restrict__ Vtb) {
  __shared__ __align__(16) unsigned short As[128 * 32];  // [m][k] rows 64B
  __shared__ __align__(16) unsigned short Bs[128 * 32];  // [n][k] rows 64B
  const int t = threadIdx.x, lane = t & 63, w = t >> 6;
  const int wr = w >> 1, wc = w & 1;
  const int m0 = blockIdx.x * 128;
  const int pt = blockIdx.y;
  const int p = pt >> 3, n0 = (pt & 7) * 128;

  f32x4 acc[4][4] = {};

  const unsigned short* Ag = Xb + (m0 + w * 32 + (lane >> 2)) * 1024 + (lane & 3) * 8;
  const unsigned short* Bg = Wt + (p * 1024 + n0 + w * 32 + (lane >> 2)) * 1024 + (lane & 3) * 8;
  unsigned short* AsW = &As[w * 1024];
  unsigned short* BsW = &Bs[w * 1024];

  for (int kt = 0; kt < 32; ++kt) {
    __syncthreads();
    gload16(Ag + kt * 32,             AsW);
    gload16(Ag + kt * 32 + 16 * 1024, AsW + 512);
    gload16(Bg + kt * 32,             BsW);
    gload16(Bg + kt * 32 + 16 * 1024, BsW + 512);
    asm volatile("s_waitcnt vmcnt(0)" ::: "memory");
    __syncthreads();

    bf16x8 a[4], bfr[4];
#pragma unroll
    for (int mi = 0; mi < 4; ++mi)
      a[mi] = *(const bf16x8*)&As[(wr * 64 + mi * 16 + (lane & 15)) * 32 + (lane >> 4) * 8];
#pragma unroll
    for (int ni = 0; ni < 4; ++ni)
      bfr[ni] = *(const bf16x8*)&Bs[(wc * 64 + ni * 16 + (lane & 15)) * 32 + (lane >> 4) * 8];

    if (p != 2) {
#pragma unroll
      for (int mi = 0; mi < 4; ++mi)
#pragma unroll
        for (int ni = 0; ni < 4; ++ni)
          acc[mi][ni] = __builtin_amdgcn_mfma_f32_16x16x32_bf16(a[mi], bfr[ni], acc[mi][ni], 0, 0, 0);
    } else {  // C^T so V stores coalesce in [d][s] layout
#pragma unroll
      for (int mi = 0; mi < 4; ++mi)
#pragma unroll
        for (int ni = 0; ni < 4; ++ni)
          acc[mi][ni] = __builtin_amdgcn_mfma_f32_16x16x32_bf16(bfr[ni], a[mi], acc[mi][ni], 0, 0, 0);
    }
  }

  if (p != 2) {
    unsigned short* dst = (p == 0) ? Qb : Kb;
#pragma unroll
    for (int mi = 0; mi < 4; ++mi)
#pragma unroll
      for (int ni = 0; ni < 4; ++ni)
#pragma unroll
        for (int r = 0; r < 4; ++r) {
          int m_g = m0 + wr * 64 + mi * 16 + (lane >> 4) * 4 + r;
          int n_g = n0 + wc * 64 + ni * 16 + (lane & 15);
          int b = m_g >> 11, s = m_g & 2047;
          dst[((b * 16 + (n_g >> 6)) * 2048 + s) * 64 + (n_g & 63)] = f2bf(acc[mi][ni][r]);
        }
  } else {
#pragma unroll
    for (int mi = 0; mi < 4; ++mi)
#pragma unroll
      for (int ni = 0; ni < 4; ++ni)
#pragma unroll
        for (int r = 0; r < 4; ++r) {
          int n_g = n0 + wc * 64 + ni * 16 + (lane >> 4) * 4 + r;  // d
          int m_g = m0 + wr * 64 + mi * 16 + (lane & 15);          // s
          int b = m_g >> 11, s = m_g & 2047;
          Vtb[((b * 16 + (n_g >> 6)) * 64 + (n_g & 63)) * 2048 + s] = f2bf(acc[mi][ni][r]);
        }
  }
}

// ---------------- 4) Flash attention (swapped-QK^T, in-register P) ----------------
// 1D grid 512. xcd = bid&7; 8 heads/XCD; 8 pair-blocks/head; pair p: {15-p, p}.
// 4 waves x 32 q-rows (mi=2 x 16). 64-key tiles. K/V double-buffered, 1 barrier/tile.
//
// S^T = mfma(A=K, B=Q): lane -> (q = lane&15, keys = sub*16 + 4g + r). Softmax
// lane-local (scalar m,l per mi). PV: O^T = mfma(A=V^T, B=P^T) with k-slot
// permutation k(g,j) = (j>>2)*16 + 4g + (j&3) applied identically to both
// fragments (P packed in regs; V via 2x ds_read_b64). O^T regs: lane holds
// d = ni*16 + 4g + r (contiguous over r) for its q -> dwordx4 stores that
// fully cover 64B lines.
__global__ __launch_bounds__(256) void attn(const unsigned short* __restrict__ Qb,
                                            const unsigned short* __restrict__ Kb,
                                            const unsigned short* __restrict__ Vtb,
                                            float* __restrict__ out) {
  const int bid = blockIdx.x;
  const int xcd = bid & 7, slot = bid >> 3;
  const int bh = xcd * 8 + (slot >> 3);
  const int pp = slot & 7;
  const int b = bh >> 4, h = bh & 15;
  const int t = threadIdx.x, lane = t & 63, w = t >> 6;
  const int g = lane >> 4, c = lane & 15;

  __shared__ __align__(16) unsigned short Ks[2][64][72];  // [buf][key][d] padded
  __shared__ __align__(16) unsigned short Vs[2][64][72];  // [buf][d][key] padded

  for (int job = 0; job < 2; ++job) {
    const int qt = job ? pp : 15 - pp;
    const int q0 = qt * 128;
    const int ktiles = 2 * qt + 2;

    // Q^T B-fragments: lane holds Q[q0 + w*32 + mi*16 + c][e = kc*32 + g*8 + j]
    bf16x8 qf[2][2];
#pragma unroll
    for (int mi = 0; mi < 2; ++mi)
#pragma unroll
      for (int kc = 0; kc < 2; ++kc)
        qf[mi][kc] = *(const bf16x8*)(Qb + ((bh * 2048 + q0 + w * 32 + mi * 16 + c) << 6)
                                         + kc * 32 + g * 8);

    f32x4 o_acc[2][4] = {};
    float m_r[2] = {-INFINITY, -INFINITY};
    float l_r[2] = {0.f, 0.f};

    uint4 kr[2], vr[2];
    // prologue: stage k-tile 0 into buf 0
#pragma unroll
    for (int i = 0; i < 2; ++i) {
      int cid = i * 256 + t;
      kr[i] = *(const uint4*)(Kb + ((bh * 2048) << 6) + cid * 8);
      vr[i] = *(const uint4*)(Vtb + ((bh * 64 + (cid >> 3)) << 11) + (cid & 7) * 8);
    }
#pragma unroll
    for (int i = 0; i < 2; ++i) {
      int cid = i * 256 + t;
      *(uint4*)&Ks[0][cid >> 3][(cid & 7) * 8] = kr[i];
      *(uint4*)&Vs[0][cid >> 3][(cid & 7) * 8] = vr[i];
    }
    __syncthreads();

    for (int kt = 0; kt < ktiles; ++kt) {
      const int cur = kt & 1;
      // T14: issue next tile's global loads before compute
      if (kt + 1 < ktiles) {
        const int kv0n = (kt + 1) * 64;
#pragma unroll
        for (int i = 0; i < 2; ++i) {
          int cid = i * 256 + t;
          kr[i] = *(const uint4*)(Kb + ((bh * 2048 + kv0n) << 6) + cid * 8);
          vr[i] = *(const uint4*)(Vtb + ((bh * 64 + (cid >> 3)) << 11) + kv0n + (cid & 7) * 8);
        }
      }

      // S^T = K Q^T : sc[mi][sub][r] = S[q = q0+w*32+mi*16+c][key = kv0+sub*16+4g+r]
      f32x4 sc[2][4];
#pragma unroll
      for (int sub = 0; sub < 4; ++sub) {
        bf16x8 kf0 = *(const bf16x8*)&Ks[cur][sub * 16 + c][g * 8];
        bf16x8 kf1 = *(const bf16x8*)&Ks[cur][sub * 16 + c][32 + g * 8];
#pragma unroll
        for (int mi = 0; mi < 2; ++mi) {
          f32x4 z = {};
          z = __builtin_amdgcn_mfma_f32_16x16x32_bf16(kf0, qf[mi][0], z, 0, 0, 0);
          z = __builtin_amdgcn_mfma_f32_16x16x32_bf16(kf1, qf[mi][1], z, 0, 0, 0);
          sc[mi][sub] = z;
        }
      }

      if (kt >= 2 * qt) {  // diagonal-adjacent tiles: causal mask (key > q)
        const int koff = (kt - 2 * qt) * 64;
#pragma unroll
        for (int mi = 0; mi < 2; ++mi) {
          const int q_l = w * 32 + mi * 16 + c;
#pragma unroll
          for (int sub = 0; sub < 4; ++sub)
#pragma unroll
            for (int r = 0; r < 4; ++r)
              if (koff + sub * 16 + 4 * g + r > q_l) sc[mi][sub][r] = -INFINITY;
        }
      }

      // lane-local rowmax (16 in-reg) + reduce across the 4 g-lanes of this q
      float mx[2];
#pragma unroll
      for (int mi = 0; mi < 2; ++mi) {
        float v0 = fmaxf(fmaxf(sc[mi][0][0], sc[mi][0][1]), fmaxf(sc[mi][0][2], sc[mi][0][3]));
        float v1 = fmaxf(fmaxf(sc[mi][1][0], sc[mi][1][1]), fmaxf(sc[mi][1][2], sc[mi][1][3]));
        float v2 = fmaxf(fmaxf(sc[mi][2][0], sc[mi][2][1]), fmaxf(sc[mi][2][2], sc[mi][2][3]));
        float v3 = fmaxf(fmaxf(sc[mi][3][0], sc[mi][3][1]), fmaxf(sc[mi][3][2], sc[mi][3][3]));
        float v = fmaxf(fmaxf(v0, v1), fmaxf(v2, v3));
        v = fmaxf(v, __shfl_xor(v, 16));
        v = fmaxf(v, __shfl_xor(v, 32));
        mx[mi] = v;
      }

      // defer-max: rescale only when max grew materially (44 raw ~ 5.5 nats)
      bool need = (mx[0] > m_r[0] + 44.f) || (mx[1] > m_r[1] + 44.f);
      if (__any(need)) {
#pragma unroll
        for (int mi = 0; mi < 2; ++mi) {
          float mnew = fmaxf(m_r[mi], mx[mi]);
          float corr = __builtin_amdgcn_exp2f((m_r[mi] - mnew) * SCL);
          m_r[mi] = mnew;
          l_r[mi] *= corr;
#pragma unroll
          for (int ni = 0; ni < 4; ++ni) o_acc[mi][ni] *= corr;
        }
      }

      // P = exp2((s-m)*SCL) in regs; rowsum in regs; pack bf16 B-fragments
      bf16x8 pb[2][2];
#pragma unroll
      for (int mi = 0; mi < 2; ++mi) {
        const float a = -m_r[mi] * SCL;
        float s = 0.f;
#pragma unroll
        for (int sub = 0; sub < 4; ++sub)
#pragma unroll
          for (int r = 0; r < 4; ++r) {
            float e = __builtin_amdgcn_exp2f(fmaf(sc[mi][sub][r], SCL, a));
            sc[mi][sub][r] = e;
            s += e;
          }
        s += __shfl_xor(s, 16);
        s += __shfl_xor(s, 32);
        l_r[mi] += s;
#pragma unroll
        for (int j = 0; j < 8; ++j) {
          pb[mi][0][j] = (short)f2bf(sc[mi][j >> 2][j & 3]);        // subs 0,1
          pb[mi][1][j] = (short)f2bf(sc[mi][2 + (j >> 2)][j & 3]);  // subs 2,3
        }
      }

      // PV: O^T += V^T x P^T with matching k-slot permutation
#pragma unroll
      for (int ni = 0; ni < 4; ++ni)
#pragma unroll
        for (int half = 0; half < 2; ++half) {
          bf16x4 lo = *(const bf16x4*)&Vs[cur][ni * 16 + c][half * 32 + 4 * g];
          bf16x4 hi = *(const bf16x4*)&Vs[cur][ni * 16 + c][half * 32 + 16 + 4 * g];
          bf16x8 vt = __builtin_shufflevector(lo, hi, 0, 1, 2, 3, 4, 5, 6, 7);
#pragma unroll
          for (int mi = 0; mi < 2; ++mi)
            o_acc[mi][ni] = __builtin_amdgcn_mfma_f32_16x16x32_bf16(vt, pb[mi][half],
                                                                    o_acc[mi][ni], 0, 0, 0);
        }

      // write prefetched tile into the other buffer, then single barrier
      if (kt + 1 < ktiles) {
#pragma unroll
        for (int i = 0; i < 2; ++i) {
          int cid = i * 256 + t;
          *(uint4*)&Ks[cur ^ 1][cid >> 3][(cid & 7) * 8] = kr[i];
          *(uint4*)&Vs[cur ^ 1][cid >> 3][(cid & 7) * 8] = vr[i];
        }
      }
      __syncthreads();
    }

    // epilogue: out[b][q][h*64 + d] = O/l ; o_acc[mi][ni][r] = O[q][d=ni*16+4g+r]
#pragma unroll
    for (int mi = 0; mi < 2; ++mi) {
      const float inv = 1.f / l_r[mi];
      const int q_g = q0 + w * 32 + mi * 16 + c;
      float* orow = out + (b * 2048 + q_g) * 1024 + h * 64;
#pragma unroll
      for (int ni = 0; ni < 4; ++ni) {
        f32x4 o = o_acc[mi][ni] * inv;
        *(f32x4*)(orow + ni * 16 + 4 * g) = o;
      }
    }
  }
}

// ---------------- launch ----------------
extern "C" void kernel_launch(void* const* d_in, const int* in_sizes, int n_in,
                              void* d_out, int out_size, void* d_ws, size_t ws_size,
                              hipStream_t stream) {
  const float* emb = (const float*)d_in[0];
  const float* Wq  = (const float*)d_in[1];
  const float* Wk  = (const float*)d_in[2];
  const float* Wv  = (const float*)d_in[3];
  char* ws = (char*)d_ws;
  unsigned short* Xb  = (unsigned short*)(ws + 0);          // 16,777,216
  unsigned short* Wt  = (unsigned short*)(ws + 16777216);   //  6,291,456
  unsigned short* Qb  = (unsigned short*)(ws + 23068672);   // 16,777,216
  unsigned short* Kb  = (unsigned short*)(ws + 39845888);   // 16,777,216
  unsigned short* Vtb = (unsigned short*)(ws + 56623104);   // 16,777,216
  float* out = (float*)d_out;

  conv_x<<<2048, 256, 0, stream>>>(emb, Xb, 2097152);
  conv_w<<<dim3(256, 3), 256, 0, stream>>>(Wq, Wk, Wv, Wt);
  qkv_gemm<<<dim3(64, 24), 256, 0, stream>>>(Xb, Wt, Qb, Kb, Vtb);
  attn<<<512, 256, 0, stream>>>(Qb, Kb, Vtb, out);
}

// Round 5
// 207.517 us; speedup vs baseline: 2.1614x; 1.0004x over previous
//
#include <hip/hip_runtime.h>

// Problem: B=4, S=2048, E=1024, H=16, DH=64
// out[b][s][h*64+d] = softmax_causal(Q K^T / 8) V, with Q/K/V = X @ W{q,k,v}[h]
//
// Pipeline:
//   1) conv_x:  embedded f32 -> bf16 (row-major [8192][1024])
//   2) conv_w:  W[p][h][e][d] f32 -> bf16 transposed Wt[p][h*64+d][e]
//   3) qkv_gemm: 128x128 tile, BK=32, depth-2 pipelined global_load_lds (3 LDS
//        buffers, counted vmcnt(4), raw s_barrier -- 1 barrier/k-step),
//        mfma 16x16x32 bf16. p=0 -> Q [b][h][s][d], p=1 -> K, p=2 -> V^T [b][h][d][s]
//   4) attn: flash, swapped-QK^T (S^T in regs -> lane-local softmax, P never
//        touches LDS), permuted-k PV (O^T = mfma(V^T, P^T)), K/V LDS double
//        buffer (1 barrier/tile), T14 reg prefetch, XCD-grouped grid,
//        paired causal tiles {15-p, p}.

typedef short bf16x4 __attribute__((ext_vector_type(4)));
typedef short bf16x8 __attribute__((ext_vector_type(8)));
typedef float f32x4 __attribute__((ext_vector_type(4)));
typedef unsigned short u16x4 __attribute__((ext_vector_type(4)));
typedef unsigned short u16x8 __attribute__((ext_vector_type(8)));

#define SCL 0.1803368801111204f   /* log2(e)/8 : folds the 1/sqrt(64) into exp2 */

static __device__ __forceinline__ unsigned short f2bf(float f) {
  unsigned int u = __builtin_bit_cast(unsigned int, f);
  u += 0x7fffu + ((u >> 16) & 1u);   // RNE
  return (unsigned short)(u >> 16);
}

static __device__ __forceinline__ void gload16(const void* g, void* l) {
  __builtin_amdgcn_global_load_lds((__attribute__((address_space(1))) void*)g,
                                   (__attribute__((address_space(3))) void*)l, 16, 0, 0);
}

// ---------------- 1) X f32 -> bf16 ----------------
__global__ __launch_bounds__(256) void conv_x(const float* __restrict__ x,
                                              unsigned short* __restrict__ y, int n4) {
  int i0 = blockIdx.x * 256 + threadIdx.x;
  int stride = gridDim.x * 256;
  for (int c = i0; c < n4; c += stride) {
    float4 v = ((const float4*)x)[c];
    u16x4 o;
    o[0] = f2bf(v.x); o[1] = f2bf(v.y); o[2] = f2bf(v.z); o[3] = f2bf(v.w);
    ((u16x4*)y)[c] = o;
  }
}

// ---------------- 2) W transpose+convert: [p][h][e][d] -> Wt[(p*1024 + h*64 + d)][e] ----
__global__ __launch_bounds__(256) void conv_w(const float* __restrict__ Wq,
                                              const float* __restrict__ Wk,
                                              const float* __restrict__ Wv,
                                              unsigned short* __restrict__ Wt) {
  const int p = blockIdx.y;
  const float* Wsrc = (p == 0) ? Wq : ((p == 1) ? Wk : Wv);
  const int h = blockIdx.x >> 4, et = blockIdx.x & 15;   // 64-wide e tile
  const int t = threadIdx.x;
  __shared__ __align__(16) unsigned short tile[64][72];  // [e][d], padded

  const float* src = Wsrc + (h * 1024 + et * 64) * 64;   // rows e (64), cols d (64)
#pragma unroll
  for (int i = 0; i < 4; ++i) {
    int c = i * 256 + t;
    int r = c >> 4, cc = (c & 15) * 4;
    float4 v = *(const float4*)(src + r * 64 + cc);
    tile[r][cc + 0] = f2bf(v.x); tile[r][cc + 1] = f2bf(v.y);
    tile[r][cc + 2] = f2bf(v.z); tile[r][cc + 3] = f2bf(v.w);
  }
  __syncthreads();
#pragma unroll
  for (int i = 0; i < 2; ++i) {
    int c = i * 256 + t;
    int d = c >> 3, ec = (c & 7) * 8;
    u16x8 o;
#pragma unroll
    for (int j = 0; j < 8; ++j) o[j] = tile[ec + j][d];
    *(u16x8*)(Wt + (p * 1024 + h * 64 + d) * 1024 + et * 64 + ec) = o;
  }
}

// ---------------- 3) QKV projection GEMM (depth-2 pipelined) ----------------
__global__ __launch_bounds__(256) void qkv_gemm(const unsigned short* __restrict__ Xb,
                                                const unsigned short* __restrict__ Wt,
                                                unsigned short* __restrict__ Qb,
                                                unsigned short* __restrict__ Kb,
                                                unsigned short* __restrict__ Vtb) {
  __shared__ __align__(16) unsigned short As[3][128 * 32];  // ring of 3 [m][k] tiles
  __shared__ __align__(16) unsigned short Bs[3][128 * 32];  // ring of 3 [n][k] tiles
  const int t = threadIdx.x, lane = t & 63, w = t >> 6;
  const int wr = w >> 1, wc = w & 1;
  const int m0 = blockIdx.x * 128;
  const int pt = blockIdx.y;
  const int p = pt >> 3, n0 = (pt & 7) * 128;

  f32x4 acc[4][4] = {};

  const unsigned short* Ag = Xb + (m0 + w * 32 + (lane >> 2)) * 1024 + (lane & 3) * 8;
  const unsigned short* Bg = Wt + (p * 1024 + n0 + w * 32 + (lane >> 2)) * 1024 + (lane & 3) * 8;
  const int ldsW = w * 1024;  // wave-uniform LDS chunk (bytes w*2048)

  // prologue: stage tiles 0 and 1 (8 loads in flight; never drained to 0 mid-loop)
#pragma unroll
  for (int pf = 0; pf < 2; ++pf) {
    gload16(Ag + pf * 32,             &As[pf][ldsW]);
    gload16(Ag + pf * 32 + 16 * 1024, &As[pf][ldsW + 512]);
    gload16(Bg + pf * 32,             &Bs[pf][ldsW]);
    gload16(Bg + pf * 32 + 16 * 1024, &Bs[pf][ldsW + 512]);
  }

  int cur = 0, nxt = 2;
  for (int kt = 0; kt < 32; ++kt) {
    // T4: counted wait -- tile kt landed (tile kt+1 still in flight), then raw
    // barrier (no compiler-forced vmcnt(0) drain).
    if (kt < 31) { asm volatile("s_waitcnt vmcnt(4)" ::: "memory"); }
    else         { asm volatile("s_waitcnt vmcnt(0)" ::: "memory"); }
    __builtin_amdgcn_s_barrier();

    bf16x8 a[4], bfr[4];
#pragma unroll
    for (int mi = 0; mi < 4; ++mi)
      a[mi] = *(const bf16x8*)&As[cur][(wr * 64 + mi * 16 + (lane & 15)) * 32 + (lane >> 4) * 8];
#pragma unroll
    for (int ni = 0; ni < 4; ++ni)
      bfr[ni] = *(const bf16x8*)&Bs[cur][(wc * 64 + ni * 16 + (lane & 15)) * 32 + (lane >> 4) * 8];

    if (p != 2) {
#pragma unroll
      for (int mi = 0; mi < 4; ++mi)
#pragma unroll
        for (int ni = 0; ni < 4; ++ni)
          acc[mi][ni] = __builtin_amdgcn_mfma_f32_16x16x32_bf16(a[mi], bfr[ni], acc[mi][ni], 0, 0, 0);
    } else {  // C^T so V stores coalesce in [d][s] layout
#pragma unroll
      for (int mi = 0; mi < 4; ++mi)
#pragma unroll
        for (int ni = 0; ni < 4; ++ni)
          acc[mi][ni] = __builtin_amdgcn_mfma_f32_16x16x32_bf16(bfr[ni], a[mi], acc[mi][ni], 0, 0, 0);
    }

    // stage tile kt+2 into the ring slot last read at iter kt-1 (protected by
    // this iteration's barrier)
    if (kt + 2 < 32) {
      const int off = (kt + 2) * 32;
      gload16(Ag + off,             &As[nxt][ldsW]);
      gload16(Ag + off + 16 * 1024, &As[nxt][ldsW + 512]);
      gload16(Bg + off,             &Bs[nxt][ldsW]);
      gload16(Bg + off + 16 * 1024, &Bs[nxt][ldsW + 512]);
    }
    cur = (cur == 2) ? 0 : cur + 1;
    nxt = (nxt == 2) ? 0 : nxt + 1;
  }

  if (p != 2) {
    unsigned short* dst = (p == 0) ? Qb : Kb;
#pragma unroll
    for (int mi = 0; mi < 4; ++mi)
#pragma unroll
      for (int ni = 0; ni < 4; ++ni)
#pragma unroll
        for (int r = 0; r < 4; ++r) {
          int m_g = m0 + wr * 64 + mi * 16 + (lane >> 4) * 4 + r;
          int n_g = n0 + wc * 64 + ni * 16 + (lane & 15);
          int b = m_g >> 11, s = m_g & 2047;
          dst[((b * 16 + (n_g >> 6)) * 2048 + s) * 64 + (n_g & 63)] = f2bf(acc[mi][ni][r]);
        }
  } else {
#pragma unroll
    for (int mi = 0; mi < 4; ++mi)
#pragma unroll
      for (int ni = 0; ni < 4; ++ni)
#pragma unroll
        for (int r = 0; r < 4; ++r) {
          int n_g = n0 + wc * 64 + ni * 16 + (lane >> 4) * 4 + r;  // d
          int m_g = m0 + wr * 64 + mi * 16 + (lane & 15);          // s
          int b = m_g >> 11, s = m_g & 2047;
          Vtb[((b * 16 + (n_g >> 6)) * 64 + (n_g & 63)) * 2048 + s] = f2bf(acc[mi][ni][r]);
        }
  }
}

// ---------------- 4) Flash attention (swapped-QK^T, in-register P) ----------------
// 1D grid 512. xcd = bid&7; 8 heads/XCD; 8 pair-blocks/head; pair p: {15-p, p}.
// 4 waves x 32 q-rows (mi=2 x 16). 64-key tiles. K/V double-buffered, 1 barrier/tile.
//
// S^T = mfma(A=K, B=Q): lane -> (q = lane&15, keys = sub*16 + 4g + r). Softmax
// lane-local (scalar m,l per mi). PV: O^T = mfma(A=V^T, B=P^T) with k-slot
// permutation k(g,j) = (j>>2)*16 + 4g + (j&3) applied identically to both
// fragments. O^T regs: lane holds d = ni*16 + 4g + r for its q -> f32x4 stores.
__global__ __launch_bounds__(256) void attn(const unsigned short* __restrict__ Qb,
                                            const unsigned short* __restrict__ Kb,
                                            const unsigned short* __restrict__ Vtb,
                                            float* __restrict__ out) {
  const int bid = blockIdx.x;
  const int xcd = bid & 7, slot = bid >> 3;
  const int bh = xcd * 8 + (slot >> 3);
  const int pp = slot & 7;
  const int b = bh >> 4, h = bh & 15;
  const int t = threadIdx.x, lane = t & 63, w = t >> 6;
  const int g = lane >> 4, c = lane & 15;

  __shared__ __align__(16) unsigned short Ks[2][64][72];  // [buf][key][d] padded
  __shared__ __align__(16) unsigned short Vs[2][64][72];  // [buf][d][key] padded

  for (int job = 0; job < 2; ++job) {
    const int qt = job ? pp : 15 - pp;
    const int q0 = qt * 128;
    const int ktiles = 2 * qt + 2;

    // Q^T B-fragments: lane holds Q[q0 + w*32 + mi*16 + c][e = kc*32 + g*8 + j]
    bf16x8 qf[2][2];
#pragma unroll
    for (int mi = 0; mi < 2; ++mi)
#pragma unroll
      for (int kc = 0; kc < 2; ++kc)
        qf[mi][kc] = *(const bf16x8*)(Qb + ((bh * 2048 + q0 + w * 32 + mi * 16 + c) << 6)
                                         + kc * 32 + g * 8);

    f32x4 o_acc[2][4] = {};
    float m_r[2] = {-INFINITY, -INFINITY};
    float l_r[2] = {0.f, 0.f};

    uint4 kr[2], vr[2];
    // prologue: stage k-tile 0 into buf 0
#pragma unroll
    for (int i = 0; i < 2; ++i) {
      int cid = i * 256 + t;
      kr[i] = *(const uint4*)(Kb + ((bh * 2048) << 6) + cid * 8);
      vr[i] = *(const uint4*)(Vtb + ((bh * 64 + (cid >> 3)) << 11) + (cid & 7) * 8);
    }
#pragma unroll
    for (int i = 0; i < 2; ++i) {
      int cid = i * 256 + t;
      *(uint4*)&Ks[0][cid >> 3][(cid & 7) * 8] = kr[i];
      *(uint4*)&Vs[0][cid >> 3][(cid & 7) * 8] = vr[i];
    }
    __syncthreads();

    for (int kt = 0; kt < ktiles; ++kt) {
      const int cur = kt & 1;
      // T14: issue next tile's global loads before compute
      if (kt + 1 < ktiles) {
        const int kv0n = (kt + 1) * 64;
#pragma unroll
        for (int i = 0; i < 2; ++i) {
          int cid = i * 256 + t;
          kr[i] = *(const uint4*)(Kb + ((bh * 2048 + kv0n) << 6) + cid * 8);
          vr[i] = *(const uint4*)(Vtb + ((bh * 64 + (cid >> 3)) << 11) + kv0n + (cid & 7) * 8);
        }
      }

      // S^T = K Q^T : sc[mi][sub][r] = S[q = q0+w*32+mi*16+c][key = kv0+sub*16+4g+r]
      f32x4 sc[2][4];
#pragma unroll
      for (int sub = 0; sub < 4; ++sub) {
        bf16x8 kf0 = *(const bf16x8*)&Ks[cur][sub * 16 + c][g * 8];
        bf16x8 kf1 = *(const bf16x8*)&Ks[cur][sub * 16 + c][32 + g * 8];
#pragma unroll
        for (int mi = 0; mi < 2; ++mi) {
          f32x4 z = {};
          z = __builtin_amdgcn_mfma_f32_16x16x32_bf16(kf0, qf[mi][0], z, 0, 0, 0);
          z = __builtin_amdgcn_mfma_f32_16x16x32_bf16(kf1, qf[mi][1], z, 0, 0, 0);
          sc[mi][sub] = z;
        }
      }

      if (kt >= 2 * qt) {  // diagonal-adjacent tiles: causal mask (key > q)
        const int koff = (kt - 2 * qt) * 64;
#pragma unroll
        for (int mi = 0; mi < 2; ++mi) {
          const int q_l = w * 32 + mi * 16 + c;
#pragma unroll
          for (int sub = 0; sub < 4; ++sub)
#pragma unroll
            for (int r = 0; r < 4; ++r)
              if (koff + sub * 16 + 4 * g + r > q_l) sc[mi][sub][r] = -INFINITY;
        }
      }

      // lane-local rowmax (16 in-reg) + reduce across the 4 g-lanes of this q
      float mx[2];
#pragma unroll
      for (int mi = 0; mi < 2; ++mi) {
        float v0 = fmaxf(fmaxf(sc[mi][0][0], sc[mi][0][1]), fmaxf(sc[mi][0][2], sc[mi][0][3]));
        float v1 = fmaxf(fmaxf(sc[mi][1][0], sc[mi][1][1]), fmaxf(sc[mi][1][2], sc[mi][1][3]));
        float v2 = fmaxf(fmaxf(sc[mi][2][0], sc[mi][2][1]), fmaxf(sc[mi][2][2], sc[mi][2][3]));
        float v3 = fmaxf(fmaxf(sc[mi][3][0], sc[mi][3][1]), fmaxf(sc[mi][3][2], sc[mi][3][3]));
        float v = fmaxf(fmaxf(v0, v1), fmaxf(v2, v3));
        v = fmaxf(v, __shfl_xor(v, 16));
        v = fmaxf(v, __shfl_xor(v, 32));
        mx[mi] = v;
      }

      // defer-max: rescale only when max grew materially (44 raw ~ 5.5 nats)
      bool need = (mx[0] > m_r[0] + 44.f) || (mx[1] > m_r[1] + 44.f);
      if (__any(need)) {
#pragma unroll
        for (int mi = 0; mi < 2; ++mi) {
          float mnew = fmaxf(m_r[mi], mx[mi]);
          float corr = __builtin_amdgcn_exp2f((m_r[mi] - mnew) * SCL);
          m_r[mi] = mnew;
          l_r[mi] *= corr;
#pragma unroll
          for (int ni = 0; ni < 4; ++ni) o_acc[mi][ni] *= corr;
        }
      }

      // P = exp2((s-m)*SCL) in regs; rowsum in regs; pack bf16 B-fragments
      bf16x8 pb[2][2];
#pragma unroll
      for (int mi = 0; mi < 2; ++mi) {
        const float a = -m_r[mi] * SCL;
        float s = 0.f;
#pragma unroll
        for (int sub = 0; sub < 4; ++sub)
#pragma unroll
          for (int r = 0; r < 4; ++r) {
            float e = __builtin_amdgcn_exp2f(fmaf(sc[mi][sub][r], SCL, a));
            sc[mi][sub][r] = e;
            s += e;
          }
        s += __shfl_xor(s, 16);
        s += __shfl_xor(s, 32);
        l_r[mi] += s;
#pragma unroll
        for (int j = 0; j < 8; ++j) {
          pb[mi][0][j] = (short)f2bf(sc[mi][j >> 2][j & 3]);        // subs 0,1
          pb[mi][1][j] = (short)f2bf(sc[mi][2 + (j >> 2)][j & 3]);  // subs 2,3
        }
      }

      // PV: O^T += V^T x P^T with matching k-slot permutation
#pragma unroll
      for (int ni = 0; ni < 4; ++ni)
#pragma unroll
        for (int half = 0; half < 2; ++half) {
          bf16x4 lo = *(const bf16x4*)&Vs[cur][ni * 16 + c][half * 32 + 4 * g];
          bf16x4 hi = *(const bf16x4*)&Vs[cur][ni * 16 + c][half * 32 + 16 + 4 * g];
          bf16x8 vt = __builtin_shufflevector(lo, hi, 0, 1, 2, 3, 4, 5, 6, 7);
#pragma unroll
          for (int mi = 0; mi < 2; ++mi)
            o_acc[mi][ni] = __builtin_amdgcn_mfma_f32_16x16x32_bf16(vt, pb[mi][half],
                                                                    o_acc[mi][ni], 0, 0, 0);
        }

      // write prefetched tile into the other buffer, then single barrier
      if (kt + 1 < ktiles) {
#pragma unroll
        for (int i = 0; i < 2; ++i) {
          int cid = i * 256 + t;
          *(uint4*)&Ks[cur ^ 1][cid >> 3][(cid & 7) * 8] = kr[i];
          *(uint4*)&Vs[cur ^ 1][cid >> 3][(cid & 7) * 8] = vr[i];
        }
      }
      __syncthreads();
    }

    // epilogue: out[b][q][h*64 + d] = O/l ; o_acc[mi][ni][r] = O[q][d=ni*16+4g+r]
#pragma unroll
    for (int mi = 0; mi < 2; ++mi) {
      const float inv = 1.f / l_r[mi];
      const int q_g = q0 + w * 32 + mi * 16 + c;
      float* orow = out + (b * 2048 + q_g) * 1024 + h * 64;
#pragma unroll
      for (int ni = 0; ni < 4; ++ni) {
        f32x4 o = o_acc[mi][ni] * inv;
        *(f32x4*)(orow + ni * 16 + 4 * g) = o;
      }
    }
  }
}

// ---------------- launch ----------------
extern "C" void kernel_launch(void* const* d_in, const int* in_sizes, int n_in,
                              void* d_out, int out_size, void* d_ws, size_t ws_size,
                              hipStream_t stream) {
  const float* emb = (const float*)d_in[0];
  const float* Wq  = (const float*)d_in[1];
  const float* Wk  = (const float*)d_in[2];
  const float* Wv  = (const float*)d_in[3];
  char* ws = (char*)d_ws;
  unsigned short* Xb  = (unsigned short*)(ws + 0);          // 16,777,216
  unsigned short* Wt  = (unsigned short*)(ws + 16777216);   //  6,291,456
  unsigned short* Qb  = (unsigned short*)(ws + 23068672);   // 16,777,216
  unsigned short* Kb  = (unsigned short*)(ws + 39845888);   // 16,777,216
  unsigned short* Vtb = (unsigned short*)(ws + 56623104);   // 16,777,216
  float* out = (float*)d_out;

  conv_x<<<2048, 256, 0, stream>>>(emb, Xb, 2097152);
  conv_w<<<dim3(256, 3), 256, 0, stream>>>(Wq, Wk, Wv, Wt);
  qkv_gemm<<<dim3(64, 24), 256, 0, stream>>>(Xb, Wt, Qb, Kb, Vtb);
  attn<<<512, 256, 0, stream>>>(Qb, Kb, Vtb, out);
}

// Round 6
// 201.660 us; speedup vs baseline: 2.2241x; 1.0290x over previous
//
#include <hip/hip_runtime.h>

// Problem: B=4, S=2048, E=1024, H=16, DH=64
// out[b][s][h*64+d] = softmax_causal(Q K^T / 8) V, with Q/K/V = X @ W{q,k,v}[h]
//
// Pipeline:
//   1) conv_x:  embedded f32 -> bf16 (row-major [8192][1024])
//   2) conv_w:  W[p][h][e][d] f32 -> bf16 transposed Wt[p][h*64+d][e]
//   3) qkv_gemm: 128x128 tile, BK=32, depth-2 pipelined global_load_lds (3 LDS
//        buffers, counted vmcnt(4), raw s_barrier), mfma 16x16x32 bf16,
//        XOR-swizzled LDS (pre-swizzled GLOBAL source + swizzled ds_read --
//        kills the 8-way bank conflict of the 64B-row fragment reads).
//        p=0 -> Q [b][h][s][d], p=1 -> K, p=2 -> V^T [b][h][d][s]
//   4) attn: flash, swapped-QK^T (S^T in regs -> lane-local softmax, P never
//        touches LDS), permuted-k PV (O^T = mfma(V^T, P^T)), K/V LDS double
//        buffer (1 barrier/tile), T14 reg prefetch, XCD-grouped grid,
//        paired causal tiles {15-p, p}.

typedef short bf16x4 __attribute__((ext_vector_type(4)));
typedef short bf16x8 __attribute__((ext_vector_type(8)));
typedef float f32x4 __attribute__((ext_vector_type(4)));
typedef unsigned short u16x4 __attribute__((ext_vector_type(4)));
typedef unsigned short u16x8 __attribute__((ext_vector_type(8)));

#define SCL 0.1803368801111204f   /* log2(e)/8 : folds the 1/sqrt(64) into exp2 */

static __device__ __forceinline__ unsigned short f2bf(float f) {
  unsigned int u = __builtin_bit_cast(unsigned int, f);
  u += 0x7fffu + ((u >> 16) & 1u);   // RNE
  return (unsigned short)(u >> 16);
}

static __device__ __forceinline__ void gload16(const void* g, void* l) {
  __builtin_amdgcn_global_load_lds((__attribute__((address_space(1))) void*)g,
                                   (__attribute__((address_space(3))) void*)l, 16, 0, 0);
}

// Swizzled fragment offset (elements) into a [128][32] bf16 tile staged in
// 1024B groups of 16 rows. Logical (row R, k-chunk g) -> physical 16B chunk
// c_phys = (r*4+g) ^ ((r>>1)&7), r = R&15. Involution; staging pre-applies
// the same map to the global source so LDS dest stays linear (G21).
static __device__ __forceinline__ int swzoff(int R, int g) {
  const int r = R & 15;
  const int cphys = (r * 4 + g) ^ ((r >> 1) & 7);
  return (R >> 4) * 512 + cphys * 8;
}

// ---------------- 1) X f32 -> bf16 ----------------
__global__ __launch_bounds__(256) void conv_x(const float* __restrict__ x,
                                              unsigned short* __restrict__ y, int n4) {
  int i0 = blockIdx.x * 256 + threadIdx.x;
  int stride = gridDim.x * 256;
  for (int c = i0; c < n4; c += stride) {
    float4 v = ((const float4*)x)[c];
    u16x4 o;
    o[0] = f2bf(v.x); o[1] = f2bf(v.y); o[2] = f2bf(v.z); o[3] = f2bf(v.w);
    ((u16x4*)y)[c] = o;
  }
}

// ---------------- 2) W transpose+convert: [p][h][e][d] -> Wt[(p*1024 + h*64 + d)][e] ----
__global__ __launch_bounds__(256) void conv_w(const float* __restrict__ Wq,
                                              const float* __restrict__ Wk,
                                              const float* __restrict__ Wv,
                                              unsigned short* __restrict__ Wt) {
  const int p = blockIdx.y;
  const float* Wsrc = (p == 0) ? Wq : ((p == 1) ? Wk : Wv);
  const int h = blockIdx.x >> 4, et = blockIdx.x & 15;   // 64-wide e tile
  const int t = threadIdx.x;
  __shared__ __align__(16) unsigned short tile[64][72];  // [e][d], padded

  const float* src = Wsrc + (h * 1024 + et * 64) * 64;   // rows e (64), cols d (64)
#pragma unroll
  for (int i = 0; i < 4; ++i) {
    int c = i * 256 + t;
    int r = c >> 4, cc = (c & 15) * 4;
    float4 v = *(const float4*)(src + r * 64 + cc);
    tile[r][cc + 0] = f2bf(v.x); tile[r][cc + 1] = f2bf(v.y);
    tile[r][cc + 2] = f2bf(v.z); tile[r][cc + 3] = f2bf(v.w);
  }
  __syncthreads();
#pragma unroll
  for (int i = 0; i < 2; ++i) {
    int c = i * 256 + t;
    int d = c >> 3, ec = (c & 7) * 8;
    u16x8 o;
#pragma unroll
    for (int j = 0; j < 8; ++j) o[j] = tile[ec + j][d];
    *(u16x8*)(Wt + (p * 1024 + h * 64 + d) * 1024 + et * 64 + ec) = o;
  }
}

// ---------------- 3) QKV projection GEMM (depth-2 pipelined, swizzled LDS) ----
__global__ __launch_bounds__(256) void qkv_gemm(const unsigned short* __restrict__ Xb,
                                                const unsigned short* __restrict__ Wt,
                                                unsigned short* __restrict__ Qb,
                                                unsigned short* __restrict__ Kb,
                                                unsigned short* __restrict__ Vtb) {
  __shared__ __align__(16) unsigned short As[3][128 * 32];  // ring of 3 [m][k] tiles
  __shared__ __align__(16) unsigned short Bs[3][128 * 32];  // ring of 3 [n][k] tiles
  const int t = threadIdx.x, lane = t & 63, w = t >> 6;
  const int wr = w >> 1, wc = w & 1, c16 = lane & 15, g = lane >> 4;
  const int m0 = blockIdx.x * 128;
  const int pt = blockIdx.y;
  const int p = pt >> 3, n0 = (pt & 7) * 128;

  f32x4 acc[4][4] = {};

  // pre-swizzled global source: lane's physical 16B slot i holds logical chunk
  // c_log = i ^ ((i>>3)&7) -> row c_log>>2, k-chunk c_log&3.
  const int cl = lane ^ ((lane >> 3) & 7);
  const int srow = cl >> 2, scol = (cl & 3) * 8;
  const unsigned short* Ag = Xb + (m0 + w * 32 + srow) * 1024 + scol;
  const unsigned short* Bg = Wt + (p * 1024 + n0 + w * 32 + srow) * 1024 + scol;
  const int ldsW = w * 1024;  // wave-uniform LDS chunk (bytes w*2048)

  // prologue: stage tiles 0 and 1
#pragma unroll
  for (int pf = 0; pf < 2; ++pf) {
    gload16(Ag + pf * 32,             &As[pf][ldsW]);
    gload16(Ag + pf * 32 + 16 * 1024, &As[pf][ldsW + 512]);
    gload16(Bg + pf * 32,             &Bs[pf][ldsW]);
    gload16(Bg + pf * 32 + 16 * 1024, &Bs[pf][ldsW + 512]);
  }

  int cur = 0, nxt = 2;
  for (int kt = 0; kt < 32; ++kt) {
    // counted wait: tile kt landed (kt+1 still in flight), raw barrier (no drain)
    if (kt < 31) { asm volatile("s_waitcnt vmcnt(4)" ::: "memory"); }
    else         { asm volatile("s_waitcnt vmcnt(0)" ::: "memory"); }
    __builtin_amdgcn_s_barrier();

    bf16x8 a[4], bfr[4];
#pragma unroll
    for (int mi = 0; mi < 4; ++mi)
      a[mi] = *(const bf16x8*)&As[cur][swzoff(wr * 64 + mi * 16 + c16, g)];
#pragma unroll
    for (int ni = 0; ni < 4; ++ni)
      bfr[ni] = *(const bf16x8*)&Bs[cur][swzoff(wc * 64 + ni * 16 + c16, g)];

    if (p != 2) {
#pragma unroll
      for (int mi = 0; mi < 4; ++mi)
#pragma unroll
        for (int ni = 0; ni < 4; ++ni)
          acc[mi][ni] = __builtin_amdgcn_mfma_f32_16x16x32_bf16(a[mi], bfr[ni], acc[mi][ni], 0, 0, 0);
    } else {  // C^T so V stores coalesce in [d][s] layout
#pragma unroll
      for (int mi = 0; mi < 4; ++mi)
#pragma unroll
        for (int ni = 0; ni < 4; ++ni)
          acc[mi][ni] = __builtin_amdgcn_mfma_f32_16x16x32_bf16(bfr[ni], a[mi], acc[mi][ni], 0, 0, 0);
    }

    // stage tile kt+2 into the slot last read at iter kt-1
    if (kt + 2 < 32) {
      const int off = (kt + 2) * 32;
      gload16(Ag + off,             &As[nxt][ldsW]);
      gload16(Ag + off + 16 * 1024, &As[nxt][ldsW + 512]);
      gload16(Bg + off,             &Bs[nxt][ldsW]);
      gload16(Bg + off + 16 * 1024, &Bs[nxt][ldsW + 512]);
    }
    cur = (cur == 2) ? 0 : cur + 1;
    nxt = (nxt == 2) ? 0 : nxt + 1;
  }

  if (p != 2) {
    unsigned short* dst = (p == 0) ? Qb : Kb;
#pragma unroll
    for (int mi = 0; mi < 4; ++mi)
#pragma unroll
      for (int ni = 0; ni < 4; ++ni)
#pragma unroll
        for (int r = 0; r < 4; ++r) {
          int m_g = m0 + wr * 64 + mi * 16 + g * 4 + r;
          int n_g = n0 + wc * 64 + ni * 16 + c16;
          int b = m_g >> 11, s = m_g & 2047;
          dst[((b * 16 + (n_g >> 6)) * 2048 + s) * 64 + (n_g & 63)] = f2bf(acc[mi][ni][r]);
        }
  } else {
#pragma unroll
    for (int mi = 0; mi < 4; ++mi)
#pragma unroll
      for (int ni = 0; ni < 4; ++ni)
#pragma unroll
        for (int r = 0; r < 4; ++r) {
          int n_g = n0 + wc * 64 + ni * 16 + g * 4 + r;  // d
          int m_g = m0 + wr * 64 + mi * 16 + c16;        // s
          int b = m_g >> 11, s = m_g & 2047;
          Vtb[((b * 16 + (n_g >> 6)) * 64 + (n_g & 63)) * 2048 + s] = f2bf(acc[mi][ni][r]);
        }
  }
}

// ---------------- 4) Flash attention (swapped-QK^T, in-register P) ----------------
// 1D grid 512. xcd = bid&7; 8 heads/XCD; 8 pair-blocks/head; pair p: {15-p, p}.
// 4 waves x 32 q-rows (mi=2 x 16). 64-key tiles. K/V double-buffered, 1 barrier/tile.
__global__ __launch_bounds__(256) void attn(const unsigned short* __restrict__ Qb,
                                            const unsigned short* __restrict__ Kb,
                                            const unsigned short* __restrict__ Vtb,
                                            float* __restrict__ out) {
  const int bid = blockIdx.x;
  const int xcd = bid & 7, slot = bid >> 3;
  const int bh = xcd * 8 + (slot >> 3);
  const int pp = slot & 7;
  const int b = bh >> 4, h = bh & 15;
  const int t = threadIdx.x, lane = t & 63, w = t >> 6;
  const int g = lane >> 4, c = lane & 15;

  __shared__ __align__(16) unsigned short Ks[2][64][72];  // [buf][key][d] padded
  __shared__ __align__(16) unsigned short Vs[2][64][72];  // [buf][d][key] padded

  for (int job = 0; job < 2; ++job) {
    const int qt = job ? pp : 15 - pp;
    const int q0 = qt * 128;
    const int ktiles = 2 * qt + 2;

    // Q^T B-fragments: lane holds Q[q0 + w*32 + mi*16 + c][e = kc*32 + g*8 + j]
    bf16x8 qf[2][2];
#pragma unroll
    for (int mi = 0; mi < 2; ++mi)
#pragma unroll
      for (int kc = 0; kc < 2; ++kc)
        qf[mi][kc] = *(const bf16x8*)(Qb + ((bh * 2048 + q0 + w * 32 + mi * 16 + c) << 6)
                                         + kc * 32 + g * 8);

    f32x4 o_acc[2][4] = {};
    float m_r[2] = {-INFINITY, -INFINITY};
    float l_r[2] = {0.f, 0.f};

    uint4 kr[2], vr[2];
    // prologue: stage k-tile 0 into buf 0
#pragma unroll
    for (int i = 0; i < 2; ++i) {
      int cid = i * 256 + t;
      kr[i] = *(const uint4*)(Kb + ((bh * 2048) << 6) + cid * 8);
      vr[i] = *(const uint4*)(Vtb + ((bh * 64 + (cid >> 3)) << 11) + (cid & 7) * 8);
    }
#pragma unroll
    for (int i = 0; i < 2; ++i) {
      int cid = i * 256 + t;
      *(uint4*)&Ks[0][cid >> 3][(cid & 7) * 8] = kr[i];
      *(uint4*)&Vs[0][cid >> 3][(cid & 7) * 8] = vr[i];
    }
    __syncthreads();

    for (int kt = 0; kt < ktiles; ++kt) {
      const int cur = kt & 1;
      // T14: issue next tile's global loads before compute
      if (kt + 1 < ktiles) {
        const int kv0n = (kt + 1) * 64;
#pragma unroll
        for (int i = 0; i < 2; ++i) {
          int cid = i * 256 + t;
          kr[i] = *(const uint4*)(Kb + ((bh * 2048 + kv0n) << 6) + cid * 8);
          vr[i] = *(const uint4*)(Vtb + ((bh * 64 + (cid >> 3)) << 11) + kv0n + (cid & 7) * 8);
        }
      }

      // S^T = K Q^T : sc[mi][sub][r] = S[q = q0+w*32+mi*16+c][key = kv0+sub*16+4g+r]
      f32x4 sc[2][4];
#pragma unroll
      for (int sub = 0; sub < 4; ++sub) {
        bf16x8 kf0 = *(const bf16x8*)&Ks[cur][sub * 16 + c][g * 8];
        bf16x8 kf1 = *(const bf16x8*)&Ks[cur][sub * 16 + c][32 + g * 8];
#pragma unroll
        for (int mi = 0; mi < 2; ++mi) {
          f32x4 z = {};
          z = __builtin_amdgcn_mfma_f32_16x16x32_bf16(kf0, qf[mi][0], z, 0, 0, 0);
          z = __builtin_amdgcn_mfma_f32_16x16x32_bf16(kf1, qf[mi][1], z, 0, 0, 0);
          sc[mi][sub] = z;
        }
      }

      if (kt >= 2 * qt) {  // diagonal-adjacent tiles: causal mask (key > q)
        const int koff = (kt - 2 * qt) * 64;
#pragma unroll
        for (int mi = 0; mi < 2; ++mi) {
          const int q_l = w * 32 + mi * 16 + c;
#pragma unroll
          for (int sub = 0; sub < 4; ++sub)
#pragma unroll
            for (int r = 0; r < 4; ++r)
              if (koff + sub * 16 + 4 * g + r > q_l) sc[mi][sub][r] = -INFINITY;
        }
      }

      // lane-local rowmax (16 in-reg) + reduce across the 4 g-lanes of this q
      float mx[2];
#pragma unroll
      for (int mi = 0; mi < 2; ++mi) {
        float v0 = fmaxf(fmaxf(sc[mi][0][0], sc[mi][0][1]), fmaxf(sc[mi][0][2], sc[mi][0][3]));
        float v1 = fmaxf(fmaxf(sc[mi][1][0], sc[mi][1][1]), fmaxf(sc[mi][1][2], sc[mi][1][3]));
        float v2 = fmaxf(fmaxf(sc[mi][2][0], sc[mi][2][1]), fmaxf(sc[mi][2][2], sc[mi][2][3]));
        float v3 = fmaxf(fmaxf(sc[mi][3][0], sc[mi][3][1]), fmaxf(sc[mi][3][2], sc[mi][3][3]));
        float v = fmaxf(fmaxf(v0, v1), fmaxf(v2, v3));
        v = fmaxf(v, __shfl_xor(v, 16));
        v = fmaxf(v, __shfl_xor(v, 32));
        mx[mi] = v;
      }

      // defer-max: rescale only when max grew materially
      bool need = (mx[0] > m_r[0] + 44.f) || (mx[1] > m_r[1] + 44.f);
      if (__any(need)) {
#pragma unroll
        for (int mi = 0; mi < 2; ++mi) {
          float mnew = fmaxf(m_r[mi], mx[mi]);
          float corr = __builtin_amdgcn_exp2f((m_r[mi] - mnew) * SCL);
          m_r[mi] = mnew;
          l_r[mi] *= corr;
#pragma unroll
          for (int ni = 0; ni < 4; ++ni) o_acc[mi][ni] *= corr;
        }
      }

      // P = exp2((s-m)*SCL) in regs; rowsum in regs; pack bf16 B-fragments
      bf16x8 pb[2][2];
#pragma unroll
      for (int mi = 0; mi < 2; ++mi) {
        const float a = -m_r[mi] * SCL;
        float s = 0.f;
#pragma unroll
        for (int sub = 0; sub < 4; ++sub)
#pragma unroll
          for (int r = 0; r < 4; ++r) {
            float e = __builtin_amdgcn_exp2f(fmaf(sc[mi][sub][r], SCL, a));
            sc[mi][sub][r] = e;
            s += e;
          }
        s += __shfl_xor(s, 16);
        s += __shfl_xor(s, 32);
        l_r[mi] += s;
#pragma unroll
        for (int j = 0; j < 8; ++j) {
          pb[mi][0][j] = (short)f2bf(sc[mi][j >> 2][j & 3]);        // subs 0,1
          pb[mi][1][j] = (short)f2bf(sc[mi][2 + (j >> 2)][j & 3]);  // subs 2,3
        }
      }

      // PV: O^T += V^T x P^T with matching k-slot permutation
#pragma unroll
      for (int ni = 0; ni < 4; ++ni)
#pragma unroll
        for (int half = 0; half < 2; ++half) {
          bf16x4 lo = *(const bf16x4*)&Vs[cur][ni * 16 + c][half * 32 + 4 * g];
          bf16x4 hi = *(const bf16x4*)&Vs[cur][ni * 16 + c][half * 32 + 16 + 4 * g];
          bf16x8 vt = __builtin_shufflevector(lo, hi, 0, 1, 2, 3, 4, 5, 6, 7);
#pragma unroll
          for (int mi = 0; mi < 2; ++mi)
            o_acc[mi][ni] = __builtin_amdgcn_mfma_f32_16x16x32_bf16(vt, pb[mi][half],
                                                                    o_acc[mi][ni], 0, 0, 0);
        }

      // write prefetched tile into the other buffer, then single barrier
      if (kt + 1 < ktiles) {
#pragma unroll
        for (int i = 0; i < 2; ++i) {
          int cid = i * 256 + t;
          *(uint4*)&Ks[cur ^ 1][cid >> 3][(cid & 7) * 8] = kr[i];
          *(uint4*)&Vs[cur ^ 1][cid >> 3][(cid & 7) * 8] = vr[i];
        }
      }
      __syncthreads();
    }

    // epilogue: out[b][q][h*64 + d] = O/l ; o_acc[mi][ni][r] = O[q][d=ni*16+4g+r]
#pragma unroll
    for (int mi = 0; mi < 2; ++mi) {
      const float inv = 1.f / l_r[mi];
      const int q_g = q0 + w * 32 + mi * 16 + c;
      float* orow = out + (b * 2048 + q_g) * 1024 + h * 64;
#pragma unroll
      for (int ni = 0; ni < 4; ++ni) {
        f32x4 o = o_acc[mi][ni] * inv;
        *(f32x4*)(orow + ni * 16 + 4 * g) = o;
      }
    }
  }
}

// ---------------- launch ----------------
extern "C" void kernel_launch(void* const* d_in, const int* in_sizes, int n_in,
                              void* d_out, int out_size, void* d_ws, size_t ws_size,
                              hipStream_t stream) {
  const float* emb = (const float*)d_in[0];
  const float* Wq  = (const float*)d_in[1];
  const float* Wk  = (const float*)d_in[2];
  const float* Wv  = (const float*)d_in[3];
  char* ws = (char*)d_ws;
  unsigned short* Xb  = (unsigned short*)(ws + 0);          // 16,777,216
  unsigned short* Wt  = (unsigned short*)(ws + 16777216);   //  6,291,456
  unsigned short* Qb  = (unsigned short*)(ws + 23068672);   // 16,777,216
  unsigned short* Kb  = (unsigned short*)(ws + 39845888);   // 16,777,216
  unsigned short* Vtb = (unsigned short*)(ws + 56623104);   // 16,777,216
  float* out = (float*)d_out;

  conv_x<<<2048, 256, 0, stream>>>(emb, Xb, 2097152);
  conv_w<<<dim3(256, 3), 256, 0, stream>>>(Wq, Wk, Wv, Wt);
  qkv_gemm<<<dim3(64, 24), 256, 0, stream>>>(Xb, Wt, Qb, Kb, Vtb);
  attn<<<512, 256, 0, stream>>>(Qb, Kb, Vtb, out);
}

// Round 7
// 199.559 us; speedup vs baseline: 2.2476x; 1.0105x over previous
//
#include <hip/hip_runtime.h>

// Problem: B=4, S=2048, E=1024, H=16, DH=64
// out[b][s][h*64+d] = softmax_causal(Q K^T / 8) V, with Q/K/V = X @ W{q,k,v}[h]
//
// Pipeline:
//   1) conv_x:  embedded f32 -> bf16 (row-major [8192][1024])
//   2) conv_w:  W[p][h][e][d] f32 -> bf16 transposed Wt[p][h*64+d][e]
//   3) qkv_gemm: 128x128 tile, BK=32, depth-2 pipelined global_load_lds (3 LDS
//        buffers, counted vmcnt(4), raw s_barrier), swizzled LDS (0 bank
//        conflicts), XCD-aware grid: xcd = bid&7 owns an 8-m-tile stripe
//        (A-stripe 2MB L2-resident), walked pt-major (B-column streamed once).
//        p=0 -> Q [b][h][s][d], p=1 -> K, p=2 -> V^T [b][h][d][s]
//   4) attn: flash, swapped-QK^T (S^T in regs -> lane-local softmax, P never
//        touches LDS), permuted-k PV (O^T = mfma(V^T, P^T)), K/V LDS double
//        buffer (1 barrier/tile), T14 reg prefetch, XCD-grouped grid,
//        paired causal tiles {15-p, p}.

typedef short bf16x4 __attribute__((ext_vector_type(4)));
typedef short bf16x8 __attribute__((ext_vector_type(8)));
typedef float f32x4 __attribute__((ext_vector_type(4)));
typedef unsigned short u16x4 __attribute__((ext_vector_type(4)));
typedef unsigned short u16x8 __attribute__((ext_vector_type(8)));

#define SCL 0.1803368801111204f   /* log2(e)/8 : folds the 1/sqrt(64) into exp2 */

static __device__ __forceinline__ unsigned short f2bf(float f) {
  unsigned int u = __builtin_bit_cast(unsigned int, f);
  u += 0x7fffu + ((u >> 16) & 1u);   // RNE
  return (unsigned short)(u >> 16);
}

static __device__ __forceinline__ void gload16(const void* g, void* l) {
  __builtin_amdgcn_global_load_lds((__attribute__((address_space(1))) void*)g,
                                   (__attribute__((address_space(3))) void*)l, 16, 0, 0);
}

// Swizzled fragment offset (elements) into a [128][32] bf16 tile staged in
// 1024B groups of 16 rows. Logical (row R, k-chunk g) -> physical 16B chunk
// c_phys = (r*4+g) ^ ((r>>1)&7), r = R&15. Involution; staging pre-applies
// the same map to the global source so LDS dest stays linear (G21).
static __device__ __forceinline__ int swzoff(int R, int g) {
  const int r = R & 15;
  const int cphys = (r * 4 + g) ^ ((r >> 1) & 7);
  return (R >> 4) * 512 + cphys * 8;
}

// ---------------- 1) X f32 -> bf16 ----------------
__global__ __launch_bounds__(256) void conv_x(const float* __restrict__ x,
                                              unsigned short* __restrict__ y, int n4) {
  int i0 = blockIdx.x * 256 + threadIdx.x;
  int stride = gridDim.x * 256;
  for (int c = i0; c < n4; c += stride) {
    float4 v = ((const float4*)x)[c];
    u16x4 o;
    o[0] = f2bf(v.x); o[1] = f2bf(v.y); o[2] = f2bf(v.z); o[3] = f2bf(v.w);
    ((u16x4*)y)[c] = o;
  }
}

// ---------------- 2) W transpose+convert: [p][h][e][d] -> Wt[(p*1024 + h*64 + d)][e] ----
__global__ __launch_bounds__(256) void conv_w(const float* __restrict__ Wq,
                                              const float* __restrict__ Wk,
                                              const float* __restrict__ Wv,
                                              unsigned short* __restrict__ Wt) {
  const int p = blockIdx.y;
  const float* Wsrc = (p == 0) ? Wq : ((p == 1) ? Wk : Wv);
  const int h = blockIdx.x >> 4, et = blockIdx.x & 15;   // 64-wide e tile
  const int t = threadIdx.x;
  __shared__ __align__(16) unsigned short tile[64][72];  // [e][d], padded

  const float* src = Wsrc + (h * 1024 + et * 64) * 64;   // rows e (64), cols d (64)
#pragma unroll
  for (int i = 0; i < 4; ++i) {
    int c = i * 256 + t;
    int r = c >> 4, cc = (c & 15) * 4;
    float4 v = *(const float4*)(src + r * 64 + cc);
    tile[r][cc + 0] = f2bf(v.x); tile[r][cc + 1] = f2bf(v.y);
    tile[r][cc + 2] = f2bf(v.z); tile[r][cc + 3] = f2bf(v.w);
  }
  __syncthreads();
#pragma unroll
  for (int i = 0; i < 2; ++i) {
    int c = i * 256 + t;
    int d = c >> 3, ec = (c & 7) * 8;
    u16x8 o;
#pragma unroll
    for (int j = 0; j < 8; ++j) o[j] = tile[ec + j][d];
    *(u16x8*)(Wt + (p * 1024 + h * 64 + d) * 1024 + et * 64 + ec) = o;
  }
}

// ---------------- 3) QKV projection GEMM (depth-2 pipelined, swizzled, XCD-local) ----
// 1D grid 1536. bid = (pt*8 + m_local)*8 + xcd : XCD xcd owns m-tiles
// [xcd*8, xcd*8+8) and walks pt-major, so its 2MB A-stripe stays L2-resident
// and each 256KB B-column is streamed once per XCD.
__global__ __launch_bounds__(256) void qkv_gemm(const unsigned short* __restrict__ Xb,
                                                const unsigned short* __restrict__ Wt,
                                                unsigned short* __restrict__ Qb,
                                                unsigned short* __restrict__ Kb,
                                                unsigned short* __restrict__ Vtb) {
  __shared__ __align__(16) unsigned short As[3][128 * 32];  // ring of 3 [m][k] tiles
  __shared__ __align__(16) unsigned short Bs[3][128 * 32];  // ring of 3 [n][k] tiles
  const int t = threadIdx.x, lane = t & 63, w = t >> 6;
  const int wr = w >> 1, wc = w & 1, c16 = lane & 15, g = lane >> 4;

  const int bid = blockIdx.x;
  const int xcd = bid & 7, l = bid >> 3;     // l in 0..191, arrival order = l
  const int pt = l >> 3;                     // 0..23, pt-major walk
  const int m0 = (xcd * 8 + (l & 7)) * 128;  // XCD-local m stripe
  const int p = pt >> 3, n0 = (pt & 7) * 128;

  f32x4 acc[4][4] = {};

  // pre-swizzled global source: lane's physical 16B slot i holds logical chunk
  // c_log = i ^ ((i>>3)&7) -> row c_log>>2, k-chunk c_log&3.
  const int cl = lane ^ ((lane >> 3) & 7);
  const int srow = cl >> 2, scol = (cl & 3) * 8;
  const unsigned short* Ag = Xb + (m0 + w * 32 + srow) * 1024 + scol;
  const unsigned short* Bg = Wt + (p * 1024 + n0 + w * 32 + srow) * 1024 + scol;
  const int ldsW = w * 1024;  // wave-uniform LDS chunk (bytes w*2048)

  // prologue: stage tiles 0 and 1
#pragma unroll
  for (int pf = 0; pf < 2; ++pf) {
    gload16(Ag + pf * 32,             &As[pf][ldsW]);
    gload16(Ag + pf * 32 + 16 * 1024, &As[pf][ldsW + 512]);
    gload16(Bg + pf * 32,             &Bs[pf][ldsW]);
    gload16(Bg + pf * 32 + 16 * 1024, &Bs[pf][ldsW + 512]);
  }

  int cur = 0, nxt = 2;
  for (int kt = 0; kt < 32; ++kt) {
    // counted wait: tile kt landed (kt+1 still in flight), raw barrier (no drain)
    if (kt < 31) { asm volatile("s_waitcnt vmcnt(4)" ::: "memory"); }
    else         { asm volatile("s_waitcnt vmcnt(0)" ::: "memory"); }
    __builtin_amdgcn_s_barrier();

    bf16x8 a[4], bfr[4];
#pragma unroll
    for (int mi = 0; mi < 4; ++mi)
      a[mi] = *(const bf16x8*)&As[cur][swzoff(wr * 64 + mi * 16 + c16, g)];
#pragma unroll
    for (int ni = 0; ni < 4; ++ni)
      bfr[ni] = *(const bf16x8*)&Bs[cur][swzoff(wc * 64 + ni * 16 + c16, g)];

    if (p != 2) {
#pragma unroll
      for (int mi = 0; mi < 4; ++mi)
#pragma unroll
        for (int ni = 0; ni < 4; ++ni)
          acc[mi][ni] = __builtin_amdgcn_mfma_f32_16x16x32_bf16(a[mi], bfr[ni], acc[mi][ni], 0, 0, 0);
    } else {  // C^T so V stores coalesce in [d][s] layout
#pragma unroll
      for (int mi = 0; mi < 4; ++mi)
#pragma unroll
        for (int ni = 0; ni < 4; ++ni)
          acc[mi][ni] = __builtin_amdgcn_mfma_f32_16x16x32_bf16(bfr[ni], a[mi], acc[mi][ni], 0, 0, 0);
    }

    // stage tile kt+2 into the slot last read at iter kt-1
    if (kt + 2 < 32) {
      const int off = (kt + 2) * 32;
      gload16(Ag + off,             &As[nxt][ldsW]);
      gload16(Ag + off + 16 * 1024, &As[nxt][ldsW + 512]);
      gload16(Bg + off,             &Bs[nxt][ldsW]);
      gload16(Bg + off + 16 * 1024, &Bs[nxt][ldsW + 512]);
    }
    cur = (cur == 2) ? 0 : cur + 1;
    nxt = (nxt == 2) ? 0 : nxt + 1;
  }

  if (p != 2) {
    unsigned short* dst = (p == 0) ? Qb : Kb;
#pragma unroll
    for (int mi = 0; mi < 4; ++mi)
#pragma unroll
      for (int ni = 0; ni < 4; ++ni)
#pragma unroll
        for (int r = 0; r < 4; ++r) {
          int m_g = m0 + wr * 64 + mi * 16 + g * 4 + r;
          int n_g = n0 + wc * 64 + ni * 16 + c16;
          int b = m_g >> 11, s = m_g & 2047;
          dst[((b * 16 + (n_g >> 6)) * 2048 + s) * 64 + (n_g & 63)] = f2bf(acc[mi][ni][r]);
        }
  } else {
#pragma unroll
    for (int mi = 0; mi < 4; ++mi)
#pragma unroll
      for (int ni = 0; ni < 4; ++ni)
#pragma unroll
        for (int r = 0; r < 4; ++r) {
          int n_g = n0 + wc * 64 + ni * 16 + g * 4 + r;  // d
          int m_g = m0 + wr * 64 + mi * 16 + c16;        // s
          int b = m_g >> 11, s = m_g & 2047;
          Vtb[((b * 16 + (n_g >> 6)) * 64 + (n_g & 63)) * 2048 + s] = f2bf(acc[mi][ni][r]);
        }
  }
}

// ---------------- 4) Flash attention (swapped-QK^T, in-register P) ----------------
// 1D grid 512. xcd = bid&7; 8 heads/XCD; 8 pair-blocks/head; pair p: {15-p, p}.
// 4 waves x 32 q-rows (mi=2 x 16). 64-key tiles. K/V double-buffered, 1 barrier/tile.
__global__ __launch_bounds__(256) void attn(const unsigned short* __restrict__ Qb,
                                            const unsigned short* __restrict__ Kb,
                                            const unsigned short* __restrict__ Vtb,
                                            float* __restrict__ out) {
  const int bid = blockIdx.x;
  const int xcd = bid & 7, slot = bid >> 3;
  const int bh = xcd * 8 + (slot >> 3);
  const int pp = slot & 7;
  const int b = bh >> 4, h = bh & 15;
  const int t = threadIdx.x, lane = t & 63, w = t >> 6;
  const int g = lane >> 4, c = lane & 15;

  __shared__ __align__(16) unsigned short Ks[2][64][72];  // [buf][key][d] padded
  __shared__ __align__(16) unsigned short Vs[2][64][72];  // [buf][d][key] padded

  for (int job = 0; job < 2; ++job) {
    const int qt = job ? pp : 15 - pp;
    const int q0 = qt * 128;
    const int ktiles = 2 * qt + 2;

    // Q^T B-fragments: lane holds Q[q0 + w*32 + mi*16 + c][e = kc*32 + g*8 + j]
    bf16x8 qf[2][2];
#pragma unroll
    for (int mi = 0; mi < 2; ++mi)
#pragma unroll
      for (int kc = 0; kc < 2; ++kc)
        qf[mi][kc] = *(const bf16x8*)(Qb + ((bh * 2048 + q0 + w * 32 + mi * 16 + c) << 6)
                                         + kc * 32 + g * 8);

    f32x4 o_acc[2][4] = {};
    float m_r[2] = {-INFINITY, -INFINITY};
    float l_r[2] = {0.f, 0.f};

    uint4 kr[2], vr[2];
    // prologue: stage k-tile 0 into buf 0
#pragma unroll
    for (int i = 0; i < 2; ++i) {
      int cid = i * 256 + t;
      kr[i] = *(const uint4*)(Kb + ((bh * 2048) << 6) + cid * 8);
      vr[i] = *(const uint4*)(Vtb + ((bh * 64 + (cid >> 3)) << 11) + (cid & 7) * 8);
    }
#pragma unroll
    for (int i = 0; i < 2; ++i) {
      int cid = i * 256 + t;
      *(uint4*)&Ks[0][cid >> 3][(cid & 7) * 8] = kr[i];
      *(uint4*)&Vs[0][cid >> 3][(cid & 7) * 8] = vr[i];
    }
    __syncthreads();

    for (int kt = 0; kt < ktiles; ++kt) {
      const int cur = kt & 1;
      // T14: issue next tile's global loads before compute
      if (kt + 1 < ktiles) {
        const int kv0n = (kt + 1) * 64;
#pragma unroll
        for (int i = 0; i < 2; ++i) {
          int cid = i * 256 + t;
          kr[i] = *(const uint4*)(Kb + ((bh * 2048 + kv0n) << 6) + cid * 8);
          vr[i] = *(const uint4*)(Vtb + ((bh * 64 + (cid >> 3)) << 11) + kv0n + (cid & 7) * 8);
        }
      }

      // S^T = K Q^T : sc[mi][sub][r] = S[q = q0+w*32+mi*16+c][key = kv0+sub*16+4g+r]
      f32x4 sc[2][4];
#pragma unroll
      for (int sub = 0; sub < 4; ++sub) {
        bf16x8 kf0 = *(const bf16x8*)&Ks[cur][sub * 16 + c][g * 8];
        bf16x8 kf1 = *(const bf16x8*)&Ks[cur][sub * 16 + c][32 + g * 8];
#pragma unroll
        for (int mi = 0; mi < 2; ++mi) {
          f32x4 z = {};
          z = __builtin_amdgcn_mfma_f32_16x16x32_bf16(kf0, qf[mi][0], z, 0, 0, 0);
          z = __builtin_amdgcn_mfma_f32_16x16x32_bf16(kf1, qf[mi][1], z, 0, 0, 0);
          sc[mi][sub] = z;
        }
      }

      if (kt >= 2 * qt) {  // diagonal-adjacent tiles: causal mask (key > q)
        const int koff = (kt - 2 * qt) * 64;
#pragma unroll
        for (int mi = 0; mi < 2; ++mi) {
          const int q_l = w * 32 + mi * 16 + c;
#pragma unroll
          for (int sub = 0; sub < 4; ++sub)
#pragma unroll
            for (int r = 0; r < 4; ++r)
              if (koff + sub * 16 + 4 * g + r > q_l) sc[mi][sub][r] = -INFINITY;
        }
      }

      // lane-local rowmax (16 in-reg) + reduce across the 4 g-lanes of this q
      float mx[2];
#pragma unroll
      for (int mi = 0; mi < 2; ++mi) {
        float v0 = fmaxf(fmaxf(sc[mi][0][0], sc[mi][0][1]), fmaxf(sc[mi][0][2], sc[mi][0][3]));
        float v1 = fmaxf(fmaxf(sc[mi][1][0], sc[mi][1][1]), fmaxf(sc[mi][1][2], sc[mi][1][3]));
        float v2 = fmaxf(fmaxf(sc[mi][2][0], sc[mi][2][1]), fmaxf(sc[mi][2][2], sc[mi][2][3]));
        float v3 = fmaxf(fmaxf(sc[mi][3][0], sc[mi][3][1]), fmaxf(sc[mi][3][2], sc[mi][3][3]));
        float v = fmaxf(fmaxf(v0, v1), fmaxf(v2, v3));
        v = fmaxf(v, __shfl_xor(v, 16));
        v = fmaxf(v, __shfl_xor(v, 32));
        mx[mi] = v;
      }

      // defer-max: rescale only when max grew materially
      bool need = (mx[0] > m_r[0] + 44.f) || (mx[1] > m_r[1] + 44.f);
      if (__any(need)) {
#pragma unroll
        for (int mi = 0; mi < 2; ++mi) {
          float mnew = fmaxf(m_r[mi], mx[mi]);
          float corr = __builtin_amdgcn_exp2f((m_r[mi] - mnew) * SCL);
          m_r[mi] = mnew;
          l_r[mi] *= corr;
#pragma unroll
          for (int ni = 0; ni < 4; ++ni) o_acc[mi][ni] *= corr;
        }
      }

      // P = exp2((s-m)*SCL) in regs; rowsum in regs; pack bf16 B-fragments
      bf16x8 pb[2][2];
#pragma unroll
      for (int mi = 0; mi < 2; ++mi) {
        const float a = -m_r[mi] * SCL;
        float s = 0.f;
#pragma unroll
        for (int sub = 0; sub < 4; ++sub)
#pragma unroll
          for (int r = 0; r < 4; ++r) {
            float e = __builtin_amdgcn_exp2f(fmaf(sc[mi][sub][r], SCL, a));
            sc[mi][sub][r] = e;
            s += e;
          }
        s += __shfl_xor(s, 16);
        s += __shfl_xor(s, 32);
        l_r[mi] += s;
#pragma unroll
        for (int j = 0; j < 8; ++j) {
          pb[mi][0][j] = (short)f2bf(sc[mi][j >> 2][j & 3]);        // subs 0,1
          pb[mi][1][j] = (short)f2bf(sc[mi][2 + (j >> 2)][j & 3]);  // subs 2,3
        }
      }

      // PV: O^T += V^T x P^T with matching k-slot permutation
#pragma unroll
      for (int ni = 0; ni < 4; ++ni)
#pragma unroll
        for (int half = 0; half < 2; ++half) {
          bf16x4 lo = *(const bf16x4*)&Vs[cur][ni * 16 + c][half * 32 + 4 * g];
          bf16x4 hi = *(const bf16x4*)&Vs[cur][ni * 16 + c][half * 32 + 16 + 4 * g];
          bf16x8 vt = __builtin_shufflevector(lo, hi, 0, 1, 2, 3, 4, 5, 6, 7);
#pragma unroll
          for (int mi = 0; mi < 2; ++mi)
            o_acc[mi][ni] = __builtin_amdgcn_mfma_f32_16x16x32_bf16(vt, pb[mi][half],
                                                                    o_acc[mi][ni], 0, 0, 0);
        }

      // write prefetched tile into the other buffer, then single barrier
      if (kt + 1 < ktiles) {
#pragma unroll
        for (int i = 0; i < 2; ++i) {
          int cid = i * 256 + t;
          *(uint4*)&Ks[cur ^ 1][cid >> 3][(cid & 7) * 8] = kr[i];
          *(uint4*)&Vs[cur ^ 1][cid >> 3][(cid & 7) * 8] = vr[i];
        }
      }
      __syncthreads();
    }

    // epilogue: out[b][q][h*64 + d] = O/l ; o_acc[mi][ni][r] = O[q][d=ni*16+4g+r]
#pragma unroll
    for (int mi = 0; mi < 2; ++mi) {
      const float inv = 1.f / l_r[mi];
      const int q_g = q0 + w * 32 + mi * 16 + c;
      float* orow = out + (b * 2048 + q_g) * 1024 + h * 64;
#pragma unroll
      for (int ni = 0; ni < 4; ++ni) {
        f32x4 o = o_acc[mi][ni] * inv;
        *(f32x4*)(orow + ni * 16 + 4 * g) = o;
      }
    }
  }
}

// ---------------- launch ----------------
extern "C" void kernel_launch(void* const* d_in, const int* in_sizes, int n_in,
                              void* d_out, int out_size, void* d_ws, size_t ws_size,
                              hipStream_t stream) {
  const float* emb = (const float*)d_in[0];
  const float* Wq  = (const float*)d_in[1];
  const float* Wk  = (const float*)d_in[2];
  const float* Wv  = (const float*)d_in[3];
  char* ws = (char*)d_ws;
  unsigned short* Xb  = (unsigned short*)(ws + 0);          // 16,777,216
  unsigned short* Wt  = (unsigned short*)(ws + 16777216);   //  6,291,456
  unsigned short* Qb  = (unsigned short*)(ws + 23068672);   // 16,777,216
  unsigned short* Kb  = (unsigned short*)(ws + 39845888);   // 16,777,216
  unsigned short* Vtb = (unsigned short*)(ws + 56623104);   // 16,777,216
  float* out = (float*)d_out;

  conv_x<<<2048, 256, 0, stream>>>(emb, Xb, 2097152);
  conv_w<<<dim3(256, 3), 256, 0, stream>>>(Wq, Wk, Wv, Wt);
  qkv_gemm<<<1536, 256, 0, stream>>>(Xb, Wt, Qb, Kb, Vtb);
  attn<<<512, 256, 0, stream>>>(Qb, Kb, Vtb, out);
}

// Round 8
// 190.652 us; speedup vs baseline: 2.3526x; 1.0467x over previous
//
#include <hip/hip_runtime.h>

// Problem: B=4, S=2048, E=1024, H=16, DH=64
// out[b][s][h*64+d] = softmax_causal(Q K^T / 8) V, with Q/K/V = X @ W{q,k,v}[h]
//
// Pipeline:
//   1) conv_x:  embedded f32 -> bf16 (row-major [8192][1024])
//   2) conv_w:  W[p][h][e][d] f32 -> bf16 transposed Wt[p][h*64+d][e]
//   3) qkv_gemm: m201-style 8-phase 256x256 tile, BK=64, 8 waves (2Mx4N),
//        128KB LDS double-buffer, per-phase {ds_read || global_load_lds} ->
//        barrier -> lgkmcnt(0) -> setprio(1) 16 MFMA setprio(0) -> barrier,
//        XOR-swizzled LDS (pre-swizzled global source, linear LDS dest),
//        XCD-local block mapping. p=0 -> Q, p=1 -> K, p=2 -> V^T (swapped MFMA).
//   4) attn: flash, swapped-QK^T (in-register P), permuted-k PV, K/V LDS
//        double buffer, T14 reg prefetch, XCD-grouped grid, paired causal
//        tiles {15-p, p}.

typedef short bf16x4 __attribute__((ext_vector_type(4)));
typedef short bf16x8 __attribute__((ext_vector_type(8)));
typedef float f32x4 __attribute__((ext_vector_type(4)));
typedef unsigned short u16x4 __attribute__((ext_vector_type(4)));
typedef unsigned short u16x8 __attribute__((ext_vector_type(8)));

#define SCL 0.1803368801111204f   /* log2(e)/8 : folds the 1/sqrt(64) into exp2 */

static __device__ __forceinline__ unsigned short f2bf(float f) {
  unsigned int u = __builtin_bit_cast(unsigned int, f);
  u += 0x7fffu + ((u >> 16) & 1u);   // RNE
  return (unsigned short)(u >> 16);
}

static __device__ __forceinline__ void gload16(const void* g, void* l) {
  __builtin_amdgcn_global_load_lds((__attribute__((address_space(1))) void*)g,
                                   (__attribute__((address_space(3))) void*)l, 16, 0, 0);
}

// ---------------- 1) X f32 -> bf16 ----------------
__global__ __launch_bounds__(256) void conv_x(const float* __restrict__ x,
                                              unsigned short* __restrict__ y, int n4) {
  int i0 = blockIdx.x * 256 + threadIdx.x;
  int stride = gridDim.x * 256;
  for (int c = i0; c < n4; c += stride) {
    float4 v = ((const float4*)x)[c];
    u16x4 o;
    o[0] = f2bf(v.x); o[1] = f2bf(v.y); o[2] = f2bf(v.z); o[3] = f2bf(v.w);
    ((u16x4*)y)[c] = o;
  }
}

// ---------------- 2) W transpose+convert: [p][h][e][d] -> Wt[(p*1024 + h*64 + d)][e] ----
__global__ __launch_bounds__(256) void conv_w(const float* __restrict__ Wq,
                                              const float* __restrict__ Wk,
                                              const float* __restrict__ Wv,
                                              unsigned short* __restrict__ Wt) {
  const int p = blockIdx.y;
  const float* Wsrc = (p == 0) ? Wq : ((p == 1) ? Wk : Wv);
  const int h = blockIdx.x >> 4, et = blockIdx.x & 15;   // 64-wide e tile
  const int t = threadIdx.x;
  __shared__ __align__(16) unsigned short tile[64][72];  // [e][d], padded

  const float* src = Wsrc + (h * 1024 + et * 64) * 64;   // rows e (64), cols d (64)
#pragma unroll
  for (int i = 0; i < 4; ++i) {
    int c = i * 256 + t;
    int r = c >> 4, cc = (c & 15) * 4;
    float4 v = *(const float4*)(src + r * 64 + cc);
    tile[r][cc + 0] = f2bf(v.x); tile[r][cc + 1] = f2bf(v.y);
    tile[r][cc + 2] = f2bf(v.z); tile[r][cc + 3] = f2bf(v.w);
  }
  __syncthreads();
#pragma unroll
  for (int i = 0; i < 2; ++i) {
    int c = i * 256 + t;
    int d = c >> 3, ec = (c & 7) * 8;
    u16x8 o;
#pragma unroll
    for (int j = 0; j < 8; ++j) o[j] = tile[ec + j][d];
    *(u16x8*)(Wt + (p * 1024 + h * 64 + d) * 1024 + et * 64 + ec) = o;
  }
}

// ---------------- 3) QKV projection GEMM: 8-phase 256x256 (m201 port) ----------------
// Grid 384 = 8 xcd x 4 m_local x 12 nt. bid = (nt*4 + m_local)*8 + xcd.
// 512 threads = 8 waves: wr = w>>2 (2 M-rows), wc = w&3 (4 N-cols); per-wave
// output 128x64 = acc[8][4] f32x4. K = 1024 -> 16 K-tiles of BK=64, 8 iters
// of 2 K-tiles (buf0: 2i, buf1: 2i+1). Phases 1-4 stage tile 2i+1 -> buf1
// (read in 5-8, same iter); phases 5-8 stage 2i+2 -> buf0 (read next iter).
// LDS: L[buf][A/B][half(128 rows)][128 rows x 8 chunks x 8 elems] = 128 KB.
// Swizzle: 16B chunk (row, cc): cc_phys = cc ^ (row&7). Staging pre-applies
// it on the GLOBAL source (LDS dest linear, G21); ds_read applies it on the
// address. Wave-level fragment reads land 2 lanes/bank-group = free.
__global__ __launch_bounds__(512) void qkv_gemm(const unsigned short* __restrict__ Xb,
                                                const unsigned short* __restrict__ Wt,
                                                unsigned short* __restrict__ Qb,
                                                unsigned short* __restrict__ Kb,
                                                unsigned short* __restrict__ Vtb) {
  __shared__ __align__(16) unsigned short L[2][2][2][8192];  // [buf][AB][half][elem]

  const int t = threadIdx.x, lane = t & 63, w = t >> 6;
  const int wr = w >> 2, wc = w & 3, c16 = lane & 15, g = lane >> 4;

  const int bid = blockIdx.x;
  const int xcd = bid & 7, l = bid >> 3;        // l in 0..47
  const int nt = l >> 2;                        // 0..11
  const int m0 = (xcd * 4 + (l & 3)) * 256;     // XCD-local m stripe (2MB L2-res)
  const int p = nt >> 2;                        // 0..2 (Q/K/V)
  const int nb0 = (nt & 3) * 256;               // n offset within the 1024 block

  f32x4 acc[8][4] = {};

  // staging: thread t, load j covers 16B chunk idx = j*512 + t of a half-tile
  // (128 rows x 8 chunks). LDS dest linear; global source pre-swizzled.
  const int row0 = t >> 3,          ccl0 = (t & 7) ^ (row0 & 7);
  const int row1 = (512 + t) >> 3,  ccl1 = ((512 + t) & 7) ^ (row1 & 7);

  auto stage = [&](int kt, int ht) {  // ht: 0=A.h0 1=A.h1 2=B.h0 3=B.h1; buf = implicit by caller region
    const int ab = ht >> 1, half = ht & 1;
    const unsigned short* base =
        (ab == 0) ? (Xb + (m0 + half * 128) * 1024 + kt * 64)
                  : (Wt + (p * 1024 + nb0 + half * 128) * 1024 + kt * 64);
    return base;  // row/ccl applied per-load below
  };
  (void)stage;

#define STAGE(KT, HT, BUF)                                                        \
  {                                                                               \
    const int ab_ = (HT) >> 1, half_ = (HT)&1;                                    \
    const unsigned short* b0_ =                                                   \
        (ab_ == 0) ? (Xb + (m0 + half_ * 128) * 1024 + (KT)*64)                   \
                   : (Wt + (p * 1024 + nb0 + half_ * 128) * 1024 + (KT)*64);      \
    gload16(b0_ + row0 * 1024 + ccl0 * 8, &L[BUF][ab_][half_][(0 * 512 + w * 64) * 8]); \
    gload16(b0_ + row1 * 1024 + ccl1 * 8, &L[BUF][ab_][half_][(1 * 512 + w * 64) * 8]); \
  }

  // fragment reads (swizzled): A row = mi*16+c16 in half wr; B row = wc&1 half wc>>1
#define LDA(BUF, MI, KK) \
  (*(const bf16x8*)&L[BUF][0][wr][((MI)*16 + c16) * 64 + ((((KK)*4 + g) ^ (c16 & 7)) * 8)])
#define LDB(BUF, NI, KK) \
  (*(const bf16x8*)&L[BUF][1][wc >> 1][((wc & 1) * 64 + (NI)*16 + c16) * 64 + ((((KK)*4 + g) ^ (c16 & 7)) * 8)])

  bf16x8 aq[4], bq[4];

#define PHASE(BUF, KK, MH, SKT, SHT, SBUF)                                        \
  {                                                                               \
    if ((MH) == 0) {                                                              \
      bq[0] = LDB(BUF, 0, KK); bq[1] = LDB(BUF, 1, KK);                           \
      bq[2] = LDB(BUF, 2, KK); bq[3] = LDB(BUF, 3, KK);                           \
    }                                                                             \
    aq[0] = LDA(BUF, (MH)*4 + 0, KK); aq[1] = LDA(BUF, (MH)*4 + 1, KK);           \
    aq[2] = LDA(BUF, (MH)*4 + 2, KK); aq[3] = LDA(BUF, (MH)*4 + 3, KK);           \
    if ((SKT) < 16) STAGE(SKT, SHT, SBUF);                                        \
    __builtin_amdgcn_sched_barrier(0);                                            \
    __builtin_amdgcn_s_barrier();                                                 \
    asm volatile("s_waitcnt lgkmcnt(0)" ::: "memory");                            \
    __builtin_amdgcn_sched_barrier(0);                                            \
    __builtin_amdgcn_s_setprio(1);                                                \
    if (p != 2) {                                                                 \
      _Pragma("unroll") for (int q = 0; q < 4; ++q)                               \
        _Pragma("unroll") for (int ni = 0; ni < 4; ++ni)                          \
          acc[(MH)*4 + q][ni] = __builtin_amdgcn_mfma_f32_16x16x32_bf16(          \
              aq[q], bq[ni], acc[(MH)*4 + q][ni], 0, 0, 0);                       \
    } else {                                                                      \
      _Pragma("unroll") for (int q = 0; q < 4; ++q)                               \
        _Pragma("unroll") for (int ni = 0; ni < 4; ++ni)                          \
          acc[(MH)*4 + q][ni] = __builtin_amdgcn_mfma_f32_16x16x32_bf16(          \
              bq[ni], aq[q], acc[(MH)*4 + q][ni], 0, 0, 0);                       \
    }                                                                             \
    __builtin_amdgcn_s_setprio(0);                                                \
  }

  // prologue: stage K-tile 0 -> buf0, drain, sync
  STAGE(0, 0, 0); STAGE(0, 1, 0); STAGE(0, 2, 0); STAGE(0, 3, 0);
  asm volatile("s_waitcnt vmcnt(0)" ::: "memory");
  __builtin_amdgcn_s_barrier();

#pragma unroll 1
  for (int i = 0; i < 8; ++i) {
    const int s1 = 2 * i + 1, s2 = 2 * i + 2;
    // group A: K-tile 2i in buf0; stage tile 2i+1 -> buf1 (one half-tile/phase)
    PHASE(0, 0, 0, s1, 0, 1); __builtin_amdgcn_s_barrier();
    PHASE(0, 0, 1, s1, 1, 1); __builtin_amdgcn_s_barrier();
    PHASE(0, 1, 0, s1, 2, 1); __builtin_amdgcn_s_barrier();
    PHASE(0, 1, 1, s1, 3, 1);
    asm volatile("s_waitcnt vmcnt(0)" ::: "memory");   // tile 2i+1 landed
    __builtin_amdgcn_s_barrier();
    // group B: K-tile 2i+1 in buf1; stage tile 2i+2 -> buf0
    PHASE(1, 0, 0, s2, 0, 0); __builtin_amdgcn_s_barrier();
    PHASE(1, 0, 1, s2, 1, 0); __builtin_amdgcn_s_barrier();
    PHASE(1, 1, 0, s2, 2, 0); __builtin_amdgcn_s_barrier();
    PHASE(1, 1, 1, s2, 3, 0);
    if (i < 7) { asm volatile("s_waitcnt vmcnt(0)" ::: "memory"); }  // tile 2i+2 landed
    __builtin_amdgcn_s_barrier();
  }

  // epilogue: per-lane 128 bf16 stores (same verified mapping, new geometry)
  if (p != 2) {
    unsigned short* dst = (p == 0) ? Qb : Kb;
#pragma unroll
    for (int mi = 0; mi < 8; ++mi)
#pragma unroll
      for (int ni = 0; ni < 4; ++ni)
#pragma unroll
        for (int r = 0; r < 4; ++r) {
          int m_g = m0 + wr * 128 + mi * 16 + g * 4 + r;          // s-dim
          int n_g = nb0 + wc * 64 + ni * 16 + c16;                // 0..1023
          int b = m_g >> 11, s = m_g & 2047;
          dst[((b * 16 + (n_g >> 6)) * 2048 + s) * 64 + (n_g & 63)] = f2bf(acc[mi][ni][r]);
        }
  } else {
#pragma unroll
    for (int mi = 0; mi < 8; ++mi)
#pragma unroll
      for (int ni = 0; ni < 4; ++ni)
#pragma unroll
        for (int r = 0; r < 4; ++r) {
          int n_g = nb0 + wc * 64 + ni * 16 + g * 4 + r;          // d-dim
          int m_g = m0 + wr * 128 + mi * 16 + c16;                // s-dim
          int b = m_g >> 11, s = m_g & 2047;
          Vtb[((b * 16 + (n_g >> 6)) * 64 + (n_g & 63)) * 2048 + s] = f2bf(acc[mi][ni][r]);
        }
  }
#undef PHASE
#undef STAGE
#undef LDA
#undef LDB
}

// ---------------- 4) Flash attention (swapped-QK^T, in-register P) ----------------
// 1D grid 512. xcd = bid&7; 8 heads/XCD; 8 pair-blocks/head; pair p: {15-p, p}.
// 4 waves x 32 q-rows (mi=2 x 16). 64-key tiles. K/V double-buffered, 1 barrier/tile.
__global__ __launch_bounds__(256) void attn(const unsigned short* __restrict__ Qb,
                                            const unsigned short* __restrict__ Kb,
                                            const unsigned short* __restrict__ Vtb,
                                            float* __restrict__ out) {
  const int bid = blockIdx.x;
  const int xcd = bid & 7, slot = bid >> 3;
  const int bh = xcd * 8 + (slot >> 3);
  const int pp = slot & 7;
  const int b = bh >> 4, h = bh & 15;
  const int t = threadIdx.x, lane = t & 63, w = t >> 6;
  const int g = lane >> 4, c = lane & 15;

  __shared__ __align__(16) unsigned short Ks[2][64][72];  // [buf][key][d] padded
  __shared__ __align__(16) unsigned short Vs[2][64][72];  // [buf][d][key] padded

  for (int job = 0; job < 2; ++job) {
    const int qt = job ? pp : 15 - pp;
    const int q0 = qt * 128;
    const int ktiles = 2 * qt + 2;

    bf16x8 qf[2][2];
#pragma unroll
    for (int mi = 0; mi < 2; ++mi)
#pragma unroll
      for (int kc = 0; kc < 2; ++kc)
        qf[mi][kc] = *(const bf16x8*)(Qb + ((bh * 2048 + q0 + w * 32 + mi * 16 + c) << 6)
                                         + kc * 32 + g * 8);

    f32x4 o_acc[2][4] = {};
    float m_r[2] = {-INFINITY, -INFINITY};
    float l_r[2] = {0.f, 0.f};

    uint4 kr[2], vr[2];
#pragma unroll
    for (int i = 0; i < 2; ++i) {
      int cid = i * 256 + t;
      kr[i] = *(const uint4*)(Kb + ((bh * 2048) << 6) + cid * 8);
      vr[i] = *(const uint4*)(Vtb + ((bh * 64 + (cid >> 3)) << 11) + (cid & 7) * 8);
    }
#pragma unroll
    for (int i = 0; i < 2; ++i) {
      int cid = i * 256 + t;
      *(uint4*)&Ks[0][cid >> 3][(cid & 7) * 8] = kr[i];
      *(uint4*)&Vs[0][cid >> 3][(cid & 7) * 8] = vr[i];
    }
    __syncthreads();

    for (int kt = 0; kt < ktiles; ++kt) {
      const int cur = kt & 1;
      if (kt + 1 < ktiles) {
        const int kv0n = (kt + 1) * 64;
#pragma unroll
        for (int i = 0; i < 2; ++i) {
          int cid = i * 256 + t;
          kr[i] = *(const uint4*)(Kb + ((bh * 2048 + kv0n) << 6) + cid * 8);
          vr[i] = *(const uint4*)(Vtb + ((bh * 64 + (cid >> 3)) << 11) + kv0n + (cid & 7) * 8);
        }
      }

      f32x4 sc[2][4];
#pragma unroll
      for (int sub = 0; sub < 4; ++sub) {
        bf16x8 kf0 = *(const bf16x8*)&Ks[cur][sub * 16 + c][g * 8];
        bf16x8 kf1 = *(const bf16x8*)&Ks[cur][sub * 16 + c][32 + g * 8];
#pragma unroll
        for (int mi = 0; mi < 2; ++mi) {
          f32x4 z = {};
          z = __builtin_amdgcn_mfma_f32_16x16x32_bf16(kf0, qf[mi][0], z, 0, 0, 0);
          z = __builtin_amdgcn_mfma_f32_16x16x32_bf16(kf1, qf[mi][1], z, 0, 0, 0);
          sc[mi][sub] = z;
        }
      }

      if (kt >= 2 * qt) {
        const int koff = (kt - 2 * qt) * 64;
#pragma unroll
        for (int mi = 0; mi < 2; ++mi) {
          const int q_l = w * 32 + mi * 16 + c;
#pragma unroll
          for (int sub = 0; sub < 4; ++sub)
#pragma unroll
            for (int r = 0; r < 4; ++r)
              if (koff + sub * 16 + 4 * g + r > q_l) sc[mi][sub][r] = -INFINITY;
        }
      }

      float mx[2];
#pragma unroll
      for (int mi = 0; mi < 2; ++mi) {
        float v0 = fmaxf(fmaxf(sc[mi][0][0], sc[mi][0][1]), fmaxf(sc[mi][0][2], sc[mi][0][3]));
        float v1 = fmaxf(fmaxf(sc[mi][1][0], sc[mi][1][1]), fmaxf(sc[mi][1][2], sc[mi][1][3]));
        float v2 = fmaxf(fmaxf(sc[mi][2][0], sc[mi][2][1]), fmaxf(sc[mi][2][2], sc[mi][2][3]));
        float v3 = fmaxf(fmaxf(sc[mi][3][0], sc[mi][3][1]), fmaxf(sc[mi][3][2], sc[mi][3][3]));
        float v = fmaxf(fmaxf(v0, v1), fmaxf(v2, v3));
        v = fmaxf(v, __shfl_xor(v, 16));
        v = fmaxf(v, __shfl_xor(v, 32));
        mx[mi] = v;
      }

      bool need = (mx[0] > m_r[0] + 44.f) || (mx[1] > m_r[1] + 44.f);
      if (__any(need)) {
#pragma unroll
        for (int mi = 0; mi < 2; ++mi) {
          float mnew = fmaxf(m_r[mi], mx[mi]);
          float corr = __builtin_amdgcn_exp2f((m_r[mi] - mnew) * SCL);
          m_r[mi] = mnew;
          l_r[mi] *= corr;
#pragma unroll
          for (int ni = 0; ni < 4; ++ni) o_acc[mi][ni] *= corr;
        }
      }

      bf16x8 pb[2][2];
#pragma unroll
      for (int mi = 0; mi < 2; ++mi) {
        const float a = -m_r[mi] * SCL;
        float s = 0.f;
#pragma unroll
        for (int sub = 0; sub < 4; ++sub)
#pragma unroll
          for (int r = 0; r < 4; ++r) {
            float e = __builtin_amdgcn_exp2f(fmaf(sc[mi][sub][r], SCL, a));
            sc[mi][sub][r] = e;
            s += e;
          }
        s += __shfl_xor(s, 16);
        s += __shfl_xor(s, 32);
        l_r[mi] += s;
#pragma unroll
        for (int j = 0; j < 8; ++j) {
          pb[mi][0][j] = (short)f2bf(sc[mi][j >> 2][j & 3]);
          pb[mi][1][j] = (short)f2bf(sc[mi][2 + (j >> 2)][j & 3]);
        }
      }

#pragma unroll
      for (int ni = 0; ni < 4; ++ni)
#pragma unroll
        for (int half = 0; half < 2; ++half) {
          bf16x4 lo = *(const bf16x4*)&Vs[cur][ni * 16 + c][half * 32 + 4 * g];
          bf16x4 hi = *(const bf16x4*)&Vs[cur][ni * 16 + c][half * 32 + 16 + 4 * g];
          bf16x8 vt = __builtin_shufflevector(lo, hi, 0, 1, 2, 3, 4, 5, 6, 7);
#pragma unroll
          for (int mi = 0; mi < 2; ++mi)
            o_acc[mi][ni] = __builtin_amdgcn_mfma_f32_16x16x32_bf16(vt, pb[mi][half],
                                                                    o_acc[mi][ni], 0, 0, 0);
        }

      if (kt + 1 < ktiles) {
#pragma unroll
        for (int i = 0; i < 2; ++i) {
          int cid = i * 256 + t;
          *(uint4*)&Ks[cur ^ 1][cid >> 3][(cid & 7) * 8] = kr[i];
          *(uint4*)&Vs[cur ^ 1][cid >> 3][(cid & 7) * 8] = vr[i];
        }
      }
      __syncthreads();
    }

#pragma unroll
    for (int mi = 0; mi < 2; ++mi) {
      const float inv = 1.f / l_r[mi];
      const int q_g = q0 + w * 32 + mi * 16 + c;
      float* orow = out + (b * 2048 + q_g) * 1024 + h * 64;
#pragma unroll
      for (int ni = 0; ni < 4; ++ni) {
        f32x4 o = o_acc[mi][ni] * inv;
        *(f32x4*)(orow + ni * 16 + 4 * g) = o;
      }
    }
  }
}

// ---------------- launch ----------------
extern "C" void kernel_launch(void* const* d_in, const int* in_sizes, int n_in,
                              void* d_out, int out_size, void* d_ws, size_t ws_size,
                              hipStream_t stream) {
  const float* emb = (const float*)d_in[0];
  const float* Wq  = (const float*)d_in[1];
  const float* Wk  = (const float*)d_in[2];
  const float* Wv  = (const float*)d_in[3];
  char* ws = (char*)d_ws;
  unsigned short* Xb  = (unsigned short*)(ws + 0);          // 16,777,216
  unsigned short* Wt  = (unsigned short*)(ws + 16777216);   //  6,291,456
  unsigned short* Qb  = (unsigned short*)(ws + 23068672);   // 16,777,216
  unsigned short* Kb  = (unsigned short*)(ws + 39845888);   // 16,777,216
  unsigned short* Vtb = (unsigned short*)(ws + 56623104);   // 16,777,216
  float* out = (float*)d_out;

  conv_x<<<2048, 256, 0, stream>>>(emb, Xb, 2097152);
  conv_w<<<dim3(256, 3), 256, 0, stream>>>(Wq, Wk, Wv, Wt);
  qkv_gemm<<<384, 512, 0, stream>>>(Xb, Wt, Qb, Kb, Vtb);
  attn<<<512, 256, 0, stream>>>(Qb, Kb, Vtb, out);
}

// Round 9
// 178.661 us; speedup vs baseline: 2.5105x; 1.0671x over previous
//
#include <hip/hip_runtime.h>

// Problem: B=4, S=2048, E=1024, H=16, DH=64
// out[b][s][h*64+d] = softmax_causal(Q K^T / 8) V, with Q/K/V = X @ W{q,k,v}[h]
//
// Pipeline:
//   1) conv_x:  embedded f32 -> bf16 (row-major [8192][1024])
//   2) conv_w:  W[p][h][e][d] f32 -> bf16 transposed Wt[p][h*64+d][e]
//   3) qkv_gemm: 256x256 tile, BK=32, 3-buffer LDS ring (96KB), depth-2
//        prefetch with counted vmcnt(4) (never 0 mid-loop), ONE barrier per
//        K-tile, 2 MFMA phases of 16 per tile with ds_read/stage interleave,
//        XOR-swizzled LDS (pre-swizzled global source, linear LDS dest),
//        XCD-local grid. p=0 -> Q, p=1 -> K, p=2 -> V^T (swapped MFMA).
//   4) attn: flash, swapped-QK^T (in-register P), permuted-k PV, K/V LDS
//        double buffer, T14 reg prefetch, XCD-grouped grid, paired causal
//        tiles {15-p, p}.

typedef short bf16x4 __attribute__((ext_vector_type(4)));
typedef short bf16x8 __attribute__((ext_vector_type(8)));
typedef float f32x4 __attribute__((ext_vector_type(4)));
typedef unsigned short u16x4 __attribute__((ext_vector_type(4)));
typedef unsigned short u16x8 __attribute__((ext_vector_type(8)));

#define SCL 0.1803368801111204f   /* log2(e)/8 : folds the 1/sqrt(64) into exp2 */

static __device__ __forceinline__ unsigned short f2bf(float f) {
  unsigned int u = __builtin_bit_cast(unsigned int, f);
  u += 0x7fffu + ((u >> 16) & 1u);   // RNE
  return (unsigned short)(u >> 16);
}

static __device__ __forceinline__ void gload16(const void* g, void* l) {
  __builtin_amdgcn_global_load_lds((__attribute__((address_space(1))) void*)g,
                                   (__attribute__((address_space(3))) void*)l, 16, 0, 0);
}

// ---------------- 1) X f32 -> bf16 ----------------
__global__ __launch_bounds__(256) void conv_x(const float* __restrict__ x,
                                              unsigned short* __restrict__ y, int n4) {
  int i0 = blockIdx.x * 256 + threadIdx.x;
  int stride = gridDim.x * 256;
  for (int c = i0; c < n4; c += stride) {
    float4 v = ((const float4*)x)[c];
    u16x4 o;
    o[0] = f2bf(v.x); o[1] = f2bf(v.y); o[2] = f2bf(v.z); o[3] = f2bf(v.w);
    ((u16x4*)y)[c] = o;
  }
}

// ---------------- 2) W transpose+convert: [p][h][e][d] -> Wt[(p*1024 + h*64 + d)][e] ----
__global__ __launch_bounds__(256) void conv_w(const float* __restrict__ Wq,
                                              const float* __restrict__ Wk,
                                              const float* __restrict__ Wv,
                                              unsigned short* __restrict__ Wt) {
  const int p = blockIdx.y;
  const float* Wsrc = (p == 0) ? Wq : ((p == 1) ? Wk : Wv);
  const int h = blockIdx.x >> 4, et = blockIdx.x & 15;   // 64-wide e tile
  const int t = threadIdx.x;
  __shared__ __align__(16) unsigned short tile[64][72];  // [e][d], padded

  const float* src = Wsrc + (h * 1024 + et * 64) * 64;   // rows e (64), cols d (64)
#pragma unroll
  for (int i = 0; i < 4; ++i) {
    int c = i * 256 + t;
    int r = c >> 4, cc = (c & 15) * 4;
    float4 v = *(const float4*)(src + r * 64 + cc);
    tile[r][cc + 0] = f2bf(v.x); tile[r][cc + 1] = f2bf(v.y);
    tile[r][cc + 2] = f2bf(v.z); tile[r][cc + 3] = f2bf(v.w);
  }
  __syncthreads();
#pragma unroll
  for (int i = 0; i < 2; ++i) {
    int c = i * 256 + t;
    int d = c >> 3, ec = (c & 7) * 8;
    u16x8 o;
#pragma unroll
    for (int j = 0; j < 8; ++j) o[j] = tile[ec + j][d];
    *(u16x8*)(Wt + (p * 1024 + h * 64 + d) * 1024 + et * 64 + ec) = o;
  }
}

// ---------------- 3) QKV GEMM: 256x256, BK=32, 3-buf ring, counted vmcnt ----------------
// Grid 384 = 8 xcd x 4 m_local x 12 nt. 512 threads = 8 waves (2M x 4N),
// per-wave 128x64 out = acc[8][4] f32x4. K = 1024 -> 32 K-tiles of BK=32.
// LDS L[3][2][256*32]: ring of 3 tile-buffers (A+B), 96 KB.
// Per K-tile: vmcnt(4) -> s_barrier -> {ds_read 8 || stage A(kt+2)} ->
// lgkmcnt(0) -> 16 MFMA -> {ds_read 4 || stage B(kt+2)} -> lgkmcnt(0) ->
// 16 MFMA. One barrier/tile; loads stay in flight across barriers (T4).
// Swizzle: chunk_phys = chunk_log ^ (row&3) ^ ((row>>2)&3) applied on the
// PRE-SWIZZLED GLOBAL source (LDS dest linear, G21) and on the ds_read addr;
// 16-lane fragment groups land 2 lanes/bank-pair = conflict-free.
__global__ __launch_bounds__(512) void qkv_gemm(const unsigned short* __restrict__ Xb,
                                                const unsigned short* __restrict__ Wt,
                                                unsigned short* __restrict__ Qb,
                                                unsigned short* __restrict__ Kb,
                                                unsigned short* __restrict__ Vtb) {
  __shared__ __align__(16) unsigned short L[3][2][256 * 32];  // [buf][A/B][row*32+chunk*8]

  const int t = threadIdx.x, lane = t & 63, w = t >> 6;
  const int wr = w >> 2, wc = w & 3, c16 = lane & 15, g = lane >> 4;

  const int bid = blockIdx.x;
  const int xcd = bid & 7, l = bid >> 3;        // l in 0..47
  const int nt = l >> 2;                        // 0..11
  const int m0 = (xcd * 4 + (l & 3)) * 256;     // XCD-local m stripe
  const int p = nt >> 2;                        // 0..2 (Q/K/V)
  const int nb0 = (nt & 3) * 256;               // n offset within the 1024 block

  f32x4 acc[8][4] = {};

  // staging: thread t covers 16B chunk t of a 128-row half (128 rows x 4 chunks)
  const int srow = t >> 2;
  const int scl = (t & 3) ^ ((srow & 3) ^ ((srow >> 2) & 3));  // pre-swizzled src chunk
  // fragment read: physical chunk = g ^ (c16&3) ^ ((c16>>2)&3), constant/thread
  const int chp = (g ^ ((c16 & 3) ^ ((c16 >> 2) & 3))) * 8;

#define STAGE(KT, AB, HALF, BUF)                                                   \
  {                                                                                \
    const unsigned short* s_ =                                                     \
        (((AB) == 0) ? (Xb + (m0 + (HALF)*128) * 1024)                             \
                     : (Wt + (p * 1024 + nb0 + (HALF)*128) * 1024)) +              \
        (KT)*32 + srow * 1024 + scl * 8;                                           \
    gload16(s_, &L[BUF][AB][(HALF)*4096 + w * 512]);                               \
  }
#define LDA(BUF, MI) (*(const bf16x8*)&L[BUF][0][(wr * 128 + (MI)*16 + c16) * 32 + chp])
#define LDB(BUF, NI) (*(const bf16x8*)&L[BUF][1][(wc * 64 + (NI)*16 + c16) * 32 + chp])

  // prologue: stage tiles 0 (buf0) and 1 (buf1); 8 loads in flight
  STAGE(0, 0, 0, 0); STAGE(0, 0, 1, 0); STAGE(0, 1, 0, 0); STAGE(0, 1, 1, 0);
  STAGE(1, 0, 0, 1); STAGE(1, 0, 1, 1); STAGE(1, 1, 0, 1); STAGE(1, 1, 1, 1);

  int buf = 0;
#pragma unroll 1
  for (int kt = 0; kt < 32; ++kt) {
    const int sbuf = (buf == 0) ? 2 : buf - 1;  // = (kt+2)%3, freed by this barrier
    if (kt < 31) { asm volatile("s_waitcnt vmcnt(4)" ::: "memory"); }  // tile kt landed
    else         { asm volatile("s_waitcnt vmcnt(0)" ::: "memory"); }
    __builtin_amdgcn_s_barrier();

    bf16x8 bq[4], aq[4];
#pragma unroll
    for (int ni = 0; ni < 4; ++ni) bq[ni] = LDB(buf, ni);
#pragma unroll
    for (int mi = 0; mi < 4; ++mi) aq[mi] = LDA(buf, mi);
    if (kt < 30) { STAGE(kt + 2, 0, 0, sbuf); STAGE(kt + 2, 0, 1, sbuf); }
    asm volatile("s_waitcnt lgkmcnt(0)" ::: "memory");
    __builtin_amdgcn_sched_barrier(0);
    __builtin_amdgcn_s_setprio(1);
    if (p != 2) {
#pragma unroll
      for (int q = 0; q < 4; ++q)
#pragma unroll
        for (int ni = 0; ni < 4; ++ni)
          acc[q][ni] = __builtin_amdgcn_mfma_f32_16x16x32_bf16(aq[q], bq[ni], acc[q][ni], 0, 0, 0);
    } else {
#pragma unroll
      for (int q = 0; q < 4; ++q)
#pragma unroll
        for (int ni = 0; ni < 4; ++ni)
          acc[q][ni] = __builtin_amdgcn_mfma_f32_16x16x32_bf16(bq[ni], aq[q], acc[q][ni], 0, 0, 0);
    }
    __builtin_amdgcn_s_setprio(0);

    bf16x8 aq2[4];
#pragma unroll
    for (int mi = 0; mi < 4; ++mi) aq2[mi] = LDA(buf, 4 + mi);
    if (kt < 30) { STAGE(kt + 2, 1, 0, sbuf); STAGE(kt + 2, 1, 1, sbuf); }
    asm volatile("s_waitcnt lgkmcnt(0)" ::: "memory");
    __builtin_amdgcn_sched_barrier(0);
    __builtin_amdgcn_s_setprio(1);
    if (p != 2) {
#pragma unroll
      for (int q = 0; q < 4; ++q)
#pragma unroll
        for (int ni = 0; ni < 4; ++ni)
          acc[4 + q][ni] = __builtin_amdgcn_mfma_f32_16x16x32_bf16(aq2[q], bq[ni], acc[4 + q][ni], 0, 0, 0);
    } else {
#pragma unroll
      for (int q = 0; q < 4; ++q)
#pragma unroll
        for (int ni = 0; ni < 4; ++ni)
          acc[4 + q][ni] = __builtin_amdgcn_mfma_f32_16x16x32_bf16(bq[ni], aq2[q], acc[4 + q][ni], 0, 0, 0);
    }
    __builtin_amdgcn_s_setprio(0);

    buf = (buf == 2) ? 0 : buf + 1;
  }

  // epilogue (verified mapping, 256^2 geometry)
  if (p != 2) {
    unsigned short* dst = (p == 0) ? Qb : Kb;
#pragma unroll
    for (int mi = 0; mi < 8; ++mi)
#pragma unroll
      for (int ni = 0; ni < 4; ++ni)
#pragma unroll
        for (int r = 0; r < 4; ++r) {
          int m_g = m0 + wr * 128 + mi * 16 + g * 4 + r;          // s-dim
          int n_g = nb0 + wc * 64 + ni * 16 + c16;                // 0..1023
          int b = m_g >> 11, s = m_g & 2047;
          dst[((b * 16 + (n_g >> 6)) * 2048 + s) * 64 + (n_g & 63)] = f2bf(acc[mi][ni][r]);
        }
  } else {
#pragma unroll
    for (int mi = 0; mi < 8; ++mi)
#pragma unroll
      for (int ni = 0; ni < 4; ++ni)
#pragma unroll
        for (int r = 0; r < 4; ++r) {
          int n_g = nb0 + wc * 64 + ni * 16 + g * 4 + r;          // d-dim
          int m_g = m0 + wr * 128 + mi * 16 + c16;                // s-dim
          int b = m_g >> 11, s = m_g & 2047;
          Vtb[((b * 16 + (n_g >> 6)) * 64 + (n_g & 63)) * 2048 + s] = f2bf(acc[mi][ni][r]);
        }
  }
#undef STAGE
#undef LDA
#undef LDB
}

// ---------------- 4) Flash attention (swapped-QK^T, in-register P) ----------------
// 1D grid 512. xcd = bid&7; 8 heads/XCD; 8 pair-blocks/head; pair p: {15-p, p}.
// 4 waves x 32 q-rows (mi=2 x 16). 64-key tiles. K/V double-buffered, 1 barrier/tile.
__global__ __launch_bounds__(256) void attn(const unsigned short* __restrict__ Qb,
                                            const unsigned short* __restrict__ Kb,
                                            const unsigned short* __restrict__ Vtb,
                                            float* __restrict__ out) {
  const int bid = blockIdx.x;
  const int xcd = bid & 7, slot = bid >> 3;
  const int bh = xcd * 8 + (slot >> 3);
  const int pp = slot & 7;
  const int b = bh >> 4, h = bh & 15;
  const int t = threadIdx.x, lane = t & 63, w = t >> 6;
  const int g = lane >> 4, c = lane & 15;

  __shared__ __align__(16) unsigned short Ks[2][64][72];  // [buf][key][d] padded
  __shared__ __align__(16) unsigned short Vs[2][64][72];  // [buf][d][key] padded

  for (int job = 0; job < 2; ++job) {
    const int qt = job ? pp : 15 - pp;
    const int q0 = qt * 128;
    const int ktiles = 2 * qt + 2;

    bf16x8 qf[2][2];
#pragma unroll
    for (int mi = 0; mi < 2; ++mi)
#pragma unroll
      for (int kc = 0; kc < 2; ++kc)
        qf[mi][kc] = *(const bf16x8*)(Qb + ((bh * 2048 + q0 + w * 32 + mi * 16 + c) << 6)
                                         + kc * 32 + g * 8);

    f32x4 o_acc[2][4] = {};
    float m_r[2] = {-INFINITY, -INFINITY};
    float l_r[2] = {0.f, 0.f};

    uint4 kr[2], vr[2];
#pragma unroll
    for (int i = 0; i < 2; ++i) {
      int cid = i * 256 + t;
      kr[i] = *(const uint4*)(Kb + ((bh * 2048) << 6) + cid * 8);
      vr[i] = *(const uint4*)(Vtb + ((bh * 64 + (cid >> 3)) << 11) + (cid & 7) * 8);
    }
#pragma unroll
    for (int i = 0; i < 2; ++i) {
      int cid = i * 256 + t;
      *(uint4*)&Ks[0][cid >> 3][(cid & 7) * 8] = kr[i];
      *(uint4*)&Vs[0][cid >> 3][(cid & 7) * 8] = vr[i];
    }
    __syncthreads();

    for (int kt = 0; kt < ktiles; ++kt) {
      const int cur = kt & 1;
      if (kt + 1 < ktiles) {
        const int kv0n = (kt + 1) * 64;
#pragma unroll
        for (int i = 0; i < 2; ++i) {
          int cid = i * 256 + t;
          kr[i] = *(const uint4*)(Kb + ((bh * 2048 + kv0n) << 6) + cid * 8);
          vr[i] = *(const uint4*)(Vtb + ((bh * 64 + (cid >> 3)) << 11) + kv0n + (cid & 7) * 8);
        }
      }

      f32x4 sc[2][4];
#pragma unroll
      for (int sub = 0; sub < 4; ++sub) {
        bf16x8 kf0 = *(const bf16x8*)&Ks[cur][sub * 16 + c][g * 8];
        bf16x8 kf1 = *(const bf16x8*)&Ks[cur][sub * 16 + c][32 + g * 8];
#pragma unroll
        for (int mi = 0; mi < 2; ++mi) {
          f32x4 z = {};
          z = __builtin_amdgcn_mfma_f32_16x16x32_bf16(kf0, qf[mi][0], z, 0, 0, 0);
          z = __builtin_amdgcn_mfma_f32_16x16x32_bf16(kf1, qf[mi][1], z, 0, 0, 0);
          sc[mi][sub] = z;
        }
      }

      if (kt >= 2 * qt) {
        const int koff = (kt - 2 * qt) * 64;
#pragma unroll
        for (int mi = 0; mi < 2; ++mi) {
          const int q_l = w * 32 + mi * 16 + c;
#pragma unroll
          for (int sub = 0; sub < 4; ++sub)
#pragma unroll
            for (int r = 0; r < 4; ++r)
              if (koff + sub * 16 + 4 * g + r > q_l) sc[mi][sub][r] = -INFINITY;
        }
      }

      float mx[2];
#pragma unroll
      for (int mi = 0; mi < 2; ++mi) {
        float v0 = fmaxf(fmaxf(sc[mi][0][0], sc[mi][0][1]), fmaxf(sc[mi][0][2], sc[mi][0][3]));
        float v1 = fmaxf(fmaxf(sc[mi][1][0], sc[mi][1][1]), fmaxf(sc[mi][1][2], sc[mi][1][3]));
        float v2 = fmaxf(fmaxf(sc[mi][2][0], sc[mi][2][1]), fmaxf(sc[mi][2][2], sc[mi][2][3]));
        float v3 = fmaxf(fmaxf(sc[mi][3][0], sc[mi][3][1]), fmaxf(sc[mi][3][2], sc[mi][3][3]));
        float v = fmaxf(fmaxf(v0, v1), fmaxf(v2, v3));
        v = fmaxf(v, __shfl_xor(v, 16));
        v = fmaxf(v, __shfl_xor(v, 32));
        mx[mi] = v;
      }

      bool need = (mx[0] > m_r[0] + 44.f) || (mx[1] > m_r[1] + 44.f);
      if (__any(need)) {
#pragma unroll
        for (int mi = 0; mi < 2; ++mi) {
          float mnew = fmaxf(m_r[mi], mx[mi]);
          float corr = __builtin_amdgcn_exp2f((m_r[mi] - mnew) * SCL);
          m_r[mi] = mnew;
          l_r[mi] *= corr;
#pragma unroll
          for (int ni = 0; ni < 4; ++ni) o_acc[mi][ni] *= corr;
        }
      }

      bf16x8 pb[2][2];
#pragma unroll
      for (int mi = 0; mi < 2; ++mi) {
        const float a = -m_r[mi] * SCL;
        float s = 0.f;
#pragma unroll
        for (int sub = 0; sub < 4; ++sub)
#pragma unroll
          for (int r = 0; r < 4; ++r) {
            float e = __builtin_amdgcn_exp2f(fmaf(sc[mi][sub][r], SCL, a));
            sc[mi][sub][r] = e;
            s += e;
          }
        s += __shfl_xor(s, 16);
        s += __shfl_xor(s, 32);
        l_r[mi] += s;
#pragma unroll
        for (int j = 0; j < 8; ++j) {
          pb[mi][0][j] = (short)f2bf(sc[mi][j >> 2][j & 3]);
          pb[mi][1][j] = (short)f2bf(sc[mi][2 + (j >> 2)][j & 3]);
        }
      }

#pragma unroll
      for (int ni = 0; ni < 4; ++ni)
#pragma unroll
        for (int half = 0; half < 2; ++half) {
          bf16x4 lo = *(const bf16x4*)&Vs[cur][ni * 16 + c][half * 32 + 4 * g];
          bf16x4 hi = *(const bf16x4*)&Vs[cur][ni * 16 + c][half * 32 + 16 + 4 * g];
          bf16x8 vt = __builtin_shufflevector(lo, hi, 0, 1, 2, 3, 4, 5, 6, 7);
#pragma unroll
          for (int mi = 0; mi < 2; ++mi)
            o_acc[mi][ni] = __builtin_amdgcn_mfma_f32_16x16x32_bf16(vt, pb[mi][half],
                                                                    o_acc[mi][ni], 0, 0, 0);
        }

      if (kt + 1 < ktiles) {
#pragma unroll
        for (int i = 0; i < 2; ++i) {
          int cid = i * 256 + t;
          *(uint4*)&Ks[cur ^ 1][cid >> 3][(cid & 7) * 8] = kr[i];
          *(uint4*)&Vs[cur ^ 1][cid >> 3][(cid & 7) * 8] = vr[i];
        }
      }
      __syncthreads();
    }

#pragma unroll
    for (int mi = 0; mi < 2; ++mi) {
      const float inv = 1.f / l_r[mi];
      const int q_g = q0 + w * 32 + mi * 16 + c;
      float* orow = out + (b * 2048 + q_g) * 1024 + h * 64;
#pragma unroll
      for (int ni = 0; ni < 4; ++ni) {
        f32x4 o = o_acc[mi][ni] * inv;
        *(f32x4*)(orow + ni * 16 + 4 * g) = o;
      }
    }
  }
}

// ---------------- launch ----------------
extern "C" void kernel_launch(void* const* d_in, const int* in_sizes, int n_in,
                              void* d_out, int out_size, void* d_ws, size_t ws_size,
                              hipStream_t stream) {
  const float* emb = (const float*)d_in[0];
  const float* Wq  = (const float*)d_in[1];
  const float* Wk  = (const float*)d_in[2];
  const float* Wv  = (const float*)d_in[3];
  char* ws = (char*)d_ws;
  unsigned short* Xb  = (unsigned short*)(ws + 0);          // 16,777,216
  unsigned short* Wt  = (unsigned short*)(ws + 16777216);   //  6,291,456
  unsigned short* Qb  = (unsigned short*)(ws + 23068672);   // 16,777,216
  unsigned short* Kb  = (unsigned short*)(ws + 39845888);   // 16,777,216
  unsigned short* Vtb = (unsigned short*)(ws + 56623104);   // 16,777,216
  float* out = (float*)d_out;

  conv_x<<<2048, 256, 0, stream>>>(emb, Xb, 2097152);
  conv_w<<<dim3(256, 3), 256, 0, stream>>>(Wq, Wk, Wv, Wt);
  qkv_gemm<<<384, 512, 0, stream>>>(Xb, Wt, Qb, Kb, Vtb);
  attn<<<512, 256, 0, stream>>>(Qb, Kb, Vtb, out);
}

// Round 10
// 178.492 us; speedup vs baseline: 2.5128x; 1.0009x over previous
//
#include <hip/hip_runtime.h>

// Problem: B=4, S=2048, E=1024, H=16, DH=64
// out[b][s][h*64+d] = softmax_causal(Q K^T / 8) V, with Q/K/V = X @ W{q,k,v}[h]
//
// Pipeline:
//   1) conv_x:  embedded f32 -> bf16 (row-major [8192][1024])
//   2) conv_w:  W[p][h][e][d] f32 -> bf16 transposed Wt[p][h*64+d][e]
//   3) qkv_gemm: 256x256 tile, BK=32, 3-buffer LDS ring (96KB), depth-2
//        prefetch with counted vmcnt(4), ONE barrier per K-tile, 2 MFMA
//        phases of 16 per tile, swizzled LDS, XCD-local grid.
//        __launch_bounds__(512, 2): 256-VGPR budget -- acc[8][4] f32x4 is
//        128 VGPRs by itself; the default 128-cap spilled it to scratch
//        (rounds 8-9: VGPR_Count=128, all pipes <21% busy).
//        p=0 -> Q, p=1 -> K, p=2 -> V^T (swapped MFMA).
//   4) attn: flash, swapped-QK^T (in-register P), permuted-k PV, K/V LDS
//        double buffer, T14 reg prefetch, XCD-grouped grid, paired causal
//        tiles {15-p, p}.

typedef short bf16x4 __attribute__((ext_vector_type(4)));
typedef short bf16x8 __attribute__((ext_vector_type(8)));
typedef float f32x4 __attribute__((ext_vector_type(4)));
typedef unsigned short u16x4 __attribute__((ext_vector_type(4)));
typedef unsigned short u16x8 __attribute__((ext_vector_type(8)));

#define SCL 0.1803368801111204f   /* log2(e)/8 : folds the 1/sqrt(64) into exp2 */

static __device__ __forceinline__ unsigned short f2bf(float f) {
  unsigned int u = __builtin_bit_cast(unsigned int, f);
  u += 0x7fffu + ((u >> 16) & 1u);   // RNE
  return (unsigned short)(u >> 16);
}

static __device__ __forceinline__ void gload16(const void* g, void* l) {
  __builtin_amdgcn_global_load_lds((__attribute__((address_space(1))) void*)g,
                                   (__attribute__((address_space(3))) void*)l, 16, 0, 0);
}

// ---------------- 1) X f32 -> bf16 ----------------
__global__ __launch_bounds__(256) void conv_x(const float* __restrict__ x,
                                              unsigned short* __restrict__ y, int n4) {
  int i0 = blockIdx.x * 256 + threadIdx.x;
  int stride = gridDim.x * 256;
  for (int c = i0; c < n4; c += stride) {
    float4 v = ((const float4*)x)[c];
    u16x4 o;
    o[0] = f2bf(v.x); o[1] = f2bf(v.y); o[2] = f2bf(v.z); o[3] = f2bf(v.w);
    ((u16x4*)y)[c] = o;
  }
}

// ---------------- 2) W transpose+convert: [p][h][e][d] -> Wt[(p*1024 + h*64 + d)][e] ----
__global__ __launch_bounds__(256) void conv_w(const float* __restrict__ Wq,
                                              const float* __restrict__ Wk,
                                              const float* __restrict__ Wv,
                                              unsigned short* __restrict__ Wt) {
  const int p = blockIdx.y;
  const float* Wsrc = (p == 0) ? Wq : ((p == 1) ? Wk : Wv);
  const int h = blockIdx.x >> 4, et = blockIdx.x & 15;   // 64-wide e tile
  const int t = threadIdx.x;
  __shared__ __align__(16) unsigned short tile[64][72];  // [e][d], padded

  const float* src = Wsrc + (h * 1024 + et * 64) * 64;   // rows e (64), cols d (64)
#pragma unroll
  for (int i = 0; i < 4; ++i) {
    int c = i * 256 + t;
    int r = c >> 4, cc = (c & 15) * 4;
    float4 v = *(const float4*)(src + r * 64 + cc);
    tile[r][cc + 0] = f2bf(v.x); tile[r][cc + 1] = f2bf(v.y);
    tile[r][cc + 2] = f2bf(v.z); tile[r][cc + 3] = f2bf(v.w);
  }
  __syncthreads();
#pragma unroll
  for (int i = 0; i < 2; ++i) {
    int c = i * 256 + t;
    int d = c >> 3, ec = (c & 7) * 8;
    u16x8 o;
#pragma unroll
    for (int j = 0; j < 8; ++j) o[j] = tile[ec + j][d];
    *(u16x8*)(Wt + (p * 1024 + h * 64 + d) * 1024 + et * 64 + ec) = o;
  }
}

// ---------------- 3) QKV GEMM: 256x256, BK=32, 3-buf ring, counted vmcnt ----------------
// Grid 384 = 8 xcd x 4 m_local x 12 nt. 512 threads = 8 waves (2M x 4N),
// per-wave 128x64 out = acc[8][4] f32x4. K = 1024 -> 32 K-tiles of BK=32.
// LDS L[3][2][256*32]: ring of 3 tile-buffers (A+B), 96 KB -> 1 block/CU
// (2 waves/SIMD), which permits the full 256-VGPR/wave budget.
__global__ __launch_bounds__(512, 2) void qkv_gemm(const unsigned short* __restrict__ Xb,
                                                   const unsigned short* __restrict__ Wt,
                                                   unsigned short* __restrict__ Qb,
                                                   unsigned short* __restrict__ Kb,
                                                   unsigned short* __restrict__ Vtb) {
  __shared__ __align__(16) unsigned short L[3][2][256 * 32];  // [buf][A/B][row*32+chunk*8]

  const int t = threadIdx.x, lane = t & 63, w = t >> 6;
  const int wr = w >> 2, wc = w & 3, c16 = lane & 15, g = lane >> 4;

  const int bid = blockIdx.x;
  const int xcd = bid & 7, l = bid >> 3;        // l in 0..47
  const int nt = l >> 2;                        // 0..11
  const int m0 = (xcd * 4 + (l & 3)) * 256;     // XCD-local m stripe
  const int p = nt >> 2;                        // 0..2 (Q/K/V)
  const int nb0 = (nt & 3) * 256;               // n offset within the 1024 block

  f32x4 acc[8][4] = {};

  // staging: thread t covers 16B chunk t of a 128-row half (128 rows x 4 chunks)
  const int srow = t >> 2;
  const int scl = (t & 3) ^ ((srow & 3) ^ ((srow >> 2) & 3));  // pre-swizzled src chunk
  // fragment read: physical chunk = g ^ (c16&3) ^ ((c16>>2)&3), constant/thread
  const int chp = (g ^ ((c16 & 3) ^ ((c16 >> 2) & 3))) * 8;

#define STAGE(KT, AB, HALF, BUF)                                                   \
  {                                                                                \
    const unsigned short* s_ =                                                     \
        (((AB) == 0) ? (Xb + (m0 + (HALF)*128) * 1024)                             \
                     : (Wt + (p * 1024 + nb0 + (HALF)*128) * 1024)) +              \
        (KT)*32 + srow * 1024 + scl * 8;                                           \
    gload16(s_, &L[BUF][AB][(HALF)*4096 + w * 512]);                               \
  }
#define LDA(BUF, MI) (*(const bf16x8*)&L[BUF][0][(wr * 128 + (MI)*16 + c16) * 32 + chp])
#define LDB(BUF, NI) (*(const bf16x8*)&L[BUF][1][(wc * 64 + (NI)*16 + c16) * 32 + chp])

  // prologue: stage tiles 0 (buf0) and 1 (buf1); 8 loads in flight
  STAGE(0, 0, 0, 0); STAGE(0, 0, 1, 0); STAGE(0, 1, 0, 0); STAGE(0, 1, 1, 0);
  STAGE(1, 0, 0, 1); STAGE(1, 0, 1, 1); STAGE(1, 1, 0, 1); STAGE(1, 1, 1, 1);

  int buf = 0;
#pragma unroll 1
  for (int kt = 0; kt < 32; ++kt) {
    const int sbuf = (buf == 0) ? 2 : buf - 1;  // = (kt+2)%3, freed by this barrier
    if (kt < 31) { asm volatile("s_waitcnt vmcnt(4)" ::: "memory"); }  // tile kt landed
    else         { asm volatile("s_waitcnt vmcnt(0)" ::: "memory"); }
    __builtin_amdgcn_s_barrier();

    bf16x8 bq[4], aq[4];
#pragma unroll
    for (int ni = 0; ni < 4; ++ni) bq[ni] = LDB(buf, ni);
#pragma unroll
    for (int mi = 0; mi < 4; ++mi) aq[mi] = LDA(buf, mi);
    if (kt < 30) { STAGE(kt + 2, 0, 0, sbuf); STAGE(kt + 2, 0, 1, sbuf); }
    asm volatile("s_waitcnt lgkmcnt(0)" ::: "memory");
    __builtin_amdgcn_sched_barrier(0);
    __builtin_amdgcn_s_setprio(1);
    if (p != 2) {
#pragma unroll
      for (int q = 0; q < 4; ++q)
#pragma unroll
        for (int ni = 0; ni < 4; ++ni)
          acc[q][ni] = __builtin_amdgcn_mfma_f32_16x16x32_bf16(aq[q], bq[ni], acc[q][ni], 0, 0, 0);
    } else {
#pragma unroll
      for (int q = 0; q < 4; ++q)
#pragma unroll
        for (int ni = 0; ni < 4; ++ni)
          acc[q][ni] = __builtin_amdgcn_mfma_f32_16x16x32_bf16(bq[ni], aq[q], acc[q][ni], 0, 0, 0);
    }
    __builtin_amdgcn_s_setprio(0);

    bf16x8 aq2[4];
#pragma unroll
    for (int mi = 0; mi < 4; ++mi) aq2[mi] = LDA(buf, 4 + mi);
    if (kt < 30) { STAGE(kt + 2, 1, 0, sbuf); STAGE(kt + 2, 1, 1, sbuf); }
    asm volatile("s_waitcnt lgkmcnt(0)" ::: "memory");
    __builtin_amdgcn_sched_barrier(0);
    __builtin_amdgcn_s_setprio(1);
    if (p != 2) {
#pragma unroll
      for (int q = 0; q < 4; ++q)
#pragma unroll
        for (int ni = 0; ni < 4; ++ni)
          acc[4 + q][ni] = __builtin_amdgcn_mfma_f32_16x16x32_bf16(aq2[q], bq[ni], acc[4 + q][ni], 0, 0, 0);
    } else {
#pragma unroll
      for (int q = 0; q < 4; ++q)
#pragma unroll
        for (int ni = 0; ni < 4; ++ni)
          acc[4 + q][ni] = __builtin_amdgcn_mfma_f32_16x16x32_bf16(bq[ni], aq2[q], acc[4 + q][ni], 0, 0, 0);
    }
    __builtin_amdgcn_s_setprio(0);

    buf = (buf == 2) ? 0 : buf + 1;
  }

  // epilogue (verified mapping, 256^2 geometry)
  if (p != 2) {
    unsigned short* dst = (p == 0) ? Qb : Kb;
#pragma unroll
    for (int mi = 0; mi < 8; ++mi)
#pragma unroll
      for (int ni = 0; ni < 4; ++ni)
#pragma unroll
        for (int r = 0; r < 4; ++r) {
          int m_g = m0 + wr * 128 + mi * 16 + g * 4 + r;          // s-dim
          int n_g = nb0 + wc * 64 + ni * 16 + c16;                // 0..1023
          int b = m_g >> 11, s = m_g & 2047;
          dst[((b * 16 + (n_g >> 6)) * 2048 + s) * 64 + (n_g & 63)] = f2bf(acc[mi][ni][r]);
        }
  } else {
#pragma unroll
    for (int mi = 0; mi < 8; ++mi)
#pragma unroll
      for (int ni = 0; ni < 4; ++ni)
#pragma unroll
        for (int r = 0; r < 4; ++r) {
          int n_g = nb0 + wc * 64 + ni * 16 + g * 4 + r;          // d-dim
          int m_g = m0 + wr * 128 + mi * 16 + c16;                // s-dim
          int b = m_g >> 11, s = m_g & 2047;
          Vtb[((b * 16 + (n_g >> 6)) * 64 + (n_g & 63)) * 2048 + s] = f2bf(acc[mi][ni][r]);
        }
  }
#undef STAGE
#undef LDA
#undef LDB
}

// ---------------- 4) Flash attention (swapped-QK^T, in-register P) ----------------
// 1D grid 512. xcd = bid&7; 8 heads/XCD; 8 pair-blocks/head; pair p: {15-p, p}.
// 4 waves x 32 q-rows (mi=2 x 16). 64-key tiles. K/V double-buffered, 1 barrier/tile.
__global__ __launch_bounds__(256) void attn(const unsigned short* __restrict__ Qb,
                                            const unsigned short* __restrict__ Kb,
                                            const unsigned short* __restrict__ Vtb,
                                            float* __restrict__ out) {
  const int bid = blockIdx.x;
  const int xcd = bid & 7, slot = bid >> 3;
  const int bh = xcd * 8 + (slot >> 3);
  const int pp = slot & 7;
  const int b = bh >> 4, h = bh & 15;
  const int t = threadIdx.x, lane = t & 63, w = t >> 6;
  const int g = lane >> 4, c = lane & 15;

  __shared__ __align__(16) unsigned short Ks[2][64][72];  // [buf][key][d] padded
  __shared__ __align__(16) unsigned short Vs[2][64][72];  // [buf][d][key] padded

  for (int job = 0; job < 2; ++job) {
    const int qt = job ? pp : 15 - pp;
    const int q0 = qt * 128;
    const int ktiles = 2 * qt + 2;

    bf16x8 qf[2][2];
#pragma unroll
    for (int mi = 0; mi < 2; ++mi)
#pragma unroll
      for (int kc = 0; kc < 2; ++kc)
        qf[mi][kc] = *(const bf16x8*)(Qb + ((bh * 2048 + q0 + w * 32 + mi * 16 + c) << 6)
                                         + kc * 32 + g * 8);

    f32x4 o_acc[2][4] = {};
    float m_r[2] = {-INFINITY, -INFINITY};
    float l_r[2] = {0.f, 0.f};

    uint4 kr[2], vr[2];
#pragma unroll
    for (int i = 0; i < 2; ++i) {
      int cid = i * 256 + t;
      kr[i] = *(const uint4*)(Kb + ((bh * 2048) << 6) + cid * 8);
      vr[i] = *(const uint4*)(Vtb + ((bh * 64 + (cid >> 3)) << 11) + (cid & 7) * 8);
    }
#pragma unroll
    for (int i = 0; i < 2; ++i) {
      int cid = i * 256 + t;
      *(uint4*)&Ks[0][cid >> 3][(cid & 7) * 8] = kr[i];
      *(uint4*)&Vs[0][cid >> 3][(cid & 7) * 8] = vr[i];
    }
    __syncthreads();

    for (int kt = 0; kt < ktiles; ++kt) {
      const int cur = kt & 1;
      if (kt + 1 < ktiles) {
        const int kv0n = (kt + 1) * 64;
#pragma unroll
        for (int i = 0; i < 2; ++i) {
          int cid = i * 256 + t;
          kr[i] = *(const uint4*)(Kb + ((bh * 2048 + kv0n) << 6) + cid * 8);
          vr[i] = *(const uint4*)(Vtb + ((bh * 64 + (cid >> 3)) << 11) + kv0n + (cid & 7) * 8);
        }
      }

      f32x4 sc[2][4];
#pragma unroll
      for (int sub = 0; sub < 4; ++sub) {
        bf16x8 kf0 = *(const bf16x8*)&Ks[cur][sub * 16 + c][g * 8];
        bf16x8 kf1 = *(const bf16x8*)&Ks[cur][sub * 16 + c][32 + g * 8];
#pragma unroll
        for (int mi = 0; mi < 2; ++mi) {
          f32x4 z = {};
          z = __builtin_amdgcn_mfma_f32_16x16x32_bf16(kf0, qf[mi][0], z, 0, 0, 0);
          z = __builtin_amdgcn_mfma_f32_16x16x32_bf16(kf1, qf[mi][1], z, 0, 0, 0);
          sc[mi][sub] = z;
        }
      }

      if (kt >= 2 * qt) {
        const int koff = (kt - 2 * qt) * 64;
#pragma unroll
        for (int mi = 0; mi < 2; ++mi) {
          const int q_l = w * 32 + mi * 16 + c;
#pragma unroll
          for (int sub = 0; sub < 4; ++sub)
#pragma unroll
            for (int r = 0; r < 4; ++r)
              if (koff + sub * 16 + 4 * g + r > q_l) sc[mi][sub][r] = -INFINITY;
        }
      }

      float mx[2];
#pragma unroll
      for (int mi = 0; mi < 2; ++mi) {
        float v0 = fmaxf(fmaxf(sc[mi][0][0], sc[mi][0][1]), fmaxf(sc[mi][0][2], sc[mi][0][3]));
        float v1 = fmaxf(fmaxf(sc[mi][1][0], sc[mi][1][1]), fmaxf(sc[mi][1][2], sc[mi][1][3]));
        float v2 = fmaxf(fmaxf(sc[mi][2][0], sc[mi][2][1]), fmaxf(sc[mi][2][2], sc[mi][2][3]));
        float v3 = fmaxf(fmaxf(sc[mi][3][0], sc[mi][3][1]), fmaxf(sc[mi][3][2], sc[mi][3][3]));
        float v = fmaxf(fmaxf(v0, v1), fmaxf(v2, v3));
        v = fmaxf(v, __shfl_xor(v, 16));
        v = fmaxf(v, __shfl_xor(v, 32));
        mx[mi] = v;
      }

      bool need = (mx[0] > m_r[0] + 44.f) || (mx[1] > m_r[1] + 44.f);
      if (__any(need)) {
#pragma unroll
        for (int mi = 0; mi < 2; ++mi) {
          float mnew = fmaxf(m_r[mi], mx[mi]);
          float corr = __builtin_amdgcn_exp2f((m_r[mi] - mnew) * SCL);
          m_r[mi] = mnew;
          l_r[mi] *= corr;
#pragma unroll
          for (int ni = 0; ni < 4; ++ni) o_acc[mi][ni] *= corr;
        }
      }

      bf16x8 pb[2][2];
#pragma unroll
      for (int mi = 0; mi < 2; ++mi) {
        const float a = -m_r[mi] * SCL;
        float s = 0.f;
#pragma unroll
        for (int sub = 0; sub < 4; ++sub)
#pragma unroll
          for (int r = 0; r < 4; ++r) {
            float e = __builtin_amdgcn_exp2f(fmaf(sc[mi][sub][r], SCL, a));
            sc[mi][sub][r] = e;
            s += e;
          }
        s += __shfl_xor(s, 16);
        s += __shfl_xor(s, 32);
        l_r[mi] += s;
#pragma unroll
        for (int j = 0; j < 8; ++j) {
          pb[mi][0][j] = (short)f2bf(sc[mi][j >> 2][j & 3]);
          pb[mi][1][j] = (short)f2bf(sc[mi][2 + (j >> 2)][j & 3]);
        }
      }

#pragma unroll
      for (int ni = 0; ni < 4; ++ni)
#pragma unroll
        for (int half = 0; half < 2; ++half) {
          bf16x4 lo = *(const bf16x4*)&Vs[cur][ni * 16 + c][half * 32 + 4 * g];
          bf16x4 hi = *(const bf16x4*)&Vs[cur][ni * 16 + c][half * 32 + 16 + 4 * g];
          bf16x8 vt = __builtin_shufflevector(lo, hi, 0, 1, 2, 3, 4, 5, 6, 7);
#pragma unroll
          for (int mi = 0; mi < 2; ++mi)
            o_acc[mi][ni] = __builtin_amdgcn_mfma_f32_16x16x32_bf16(vt, pb[mi][half],
                                                                    o_acc[mi][ni], 0, 0, 0);
        }

      if (kt + 1 < ktiles) {
#pragma unroll
        for (int i = 0; i < 2; ++i) {
          int cid = i * 256 + t;
          *(uint4*)&Ks[cur ^ 1][cid >> 3][(cid & 7) * 8] = kr[i];
          *(uint4*)&Vs[cur ^ 1][cid >> 3][(cid & 7) * 8] = vr[i];
        }
      }
      __syncthreads();
    }

#pragma unroll
    for (int mi = 0; mi < 2; ++mi) {
      const float inv = 1.f / l_r[mi];
      const int q_g = q0 + w * 32 + mi * 16 + c;
      float* orow = out + (b * 2048 + q_g) * 1024 + h * 64;
#pragma unroll
      for (int ni = 0; ni < 4; ++ni) {
        f32x4 o = o_acc[mi][ni] * inv;
        *(f32x4*)(orow + ni * 16 + 4 * g) = o;
      }
    }
  }
}

// ---------------- launch ----------------
extern "C" void kernel_launch(void* const* d_in, const int* in_sizes, int n_in,
                              void* d_out, int out_size, void* d_ws, size_t ws_size,
                              hipStream_t stream) {
  const float* emb = (const float*)d_in[0];
  const float* Wq  = (const float*)d_in[1];
  const float* Wk  = (const float*)d_in[2];
  const float* Wv  = (const float*)d_in[3];
  char* ws = (char*)d_ws;
  unsigned short* Xb  = (unsigned short*)(ws + 0);          // 16,777,216
  unsigned short* Wt  = (unsigned short*)(ws + 16777216);   //  6,291,456
  unsigned short* Qb  = (unsigned short*)(ws + 23068672);   // 16,777,216
  unsigned short* Kb  = (unsigned short*)(ws + 39845888);   // 16,777,216
  unsigned short* Vtb = (unsigned short*)(ws + 56623104);   // 16,777,216
  float* out = (float*)d_out;

  conv_x<<<2048, 256, 0, stream>>>(emb, Xb, 2097152);
  conv_w<<<dim3(256, 3), 256, 0, stream>>>(Wq, Wk, Wv, Wt);
  qkv_gemm<<<384, 512, 0, stream>>>(Xb, Wt, Qb, Kb, Vtb);
  attn<<<512, 256, 0, stream>>>(Qb, Kb, Vtb, out);
}